// Round 1
// baseline (4607.100 us; speedup 1.0000x reference)
//
#include <hip/hip_runtime.h>
#include <hip/hip_bf16.h>
#include <cstddef>

// Problem constants
#define HID   2048
#define INTER 4096
#define NH    64
#define HD    64
#define NST   128
#define KCONV 4
#define CONV_DIM 4352           // INTER + 2*NST
#define PROJ  8512              // INTER + CONV_DIM + NH
#define SS    2048
#define BB    2
#define BS    (BB*SS)           // 4096 rows
#define EPS   1e-5f

// proj column layout: [0,4096)=gate  [4096,8192)=hs  [8192,8320)=B  [8320,8448)=C  [8448,8512)=dt
#define COL_HS 4096
#define COL_B  8192
#define COL_DT 8448

#define NCH   16                // conv chunks along S
#define CHUNK 128               // SS / NCH

// ---------------------------------------------------------------------------
// Generic fp32 NT GEMM: C[m,n] = sum_k A[m*lda+k] * Bw[n*ldb+k]
// 64x64 tile, BK=16, 256 threads, 4x4 microtile.
// ---------------------------------------------------------------------------
#define TILE 64
#define GBK  16

__global__ __launch_bounds__(256) void gemm_nt(
    const float* __restrict__ A, int lda,
    const float* __restrict__ Bw, int ldb,
    float* __restrict__ C, int ldc, int Kd) {
  __shared__ float As[GBK][TILE + 4];
  __shared__ float Bs[GBK][TILE + 4];
  const int tid = threadIdx.x;
  const int tx = tid & 15;        // n-frag
  const int ty = tid >> 4;        // m-frag
  const int lr = tid >> 2;        // 0..63 tile row for loads
  const int lk = (tid & 3) * 4;   // k offset for loads
  const float* Ab = A + (size_t)(blockIdx.y * TILE) * lda;
  const float* Bb = Bw + (size_t)(blockIdx.x * TILE) * ldb;
  float acc[4][4] = {};
  for (int k0 = 0; k0 < Kd; k0 += GBK) {
    float4 av = *(const float4*)(Ab + (size_t)lr * lda + k0 + lk);
    float4 bv = *(const float4*)(Bb + (size_t)lr * ldb + k0 + lk);
    __syncthreads();
    As[lk + 0][lr] = av.x; As[lk + 1][lr] = av.y;
    As[lk + 2][lr] = av.z; As[lk + 3][lr] = av.w;
    Bs[lk + 0][lr] = bv.x; Bs[lk + 1][lr] = bv.y;
    Bs[lk + 2][lr] = bv.z; Bs[lk + 3][lr] = bv.w;
    __syncthreads();
#pragma unroll
    for (int kk = 0; kk < GBK; kk++) {
      float4 a = *(const float4*)&As[kk][ty * 4];
      float4 b = *(const float4*)&Bs[kk][tx * 4];
      float ar[4] = {a.x, a.y, a.z, a.w};
      float br[4] = {b.x, b.y, b.z, b.w};
#pragma unroll
      for (int i = 0; i < 4; i++)
#pragma unroll
        for (int j = 0; j < 4; j++) acc[i][j] += ar[i] * br[j];
    }
  }
  float* Cb = C + (size_t)(blockIdx.y * TILE + ty * 4) * ldc + blockIdx.x * TILE + tx * 4;
#pragma unroll
  for (int i = 0; i < 4; i++) {
    float4 v = {acc[i][0], acc[i][1], acc[i][2], acc[i][3]};
    *(float4*)(Cb + (size_t)i * ldc) = v;
  }
}

// ---------------------------------------------------------------------------
// Conv boundary capture: for each (b, c, chunk) save x[s0-1], x[s0-2], x[s0-3]
// (original pre-conv values) so conv chunks can run in parallel + in place.
// ---------------------------------------------------------------------------
__global__ void conv_capture(const float* __restrict__ proj, float* __restrict__ side) {
  int idx = blockIdx.x * 256 + threadIdx.x;
  const int total = BB * CONV_DIM * NCH * 3;
  if (idx >= total) return;
  int c = idx % CONV_DIM;
  int t = idx / CONV_DIM;
  int j = t % 3; t /= 3;
  int chunk = t % NCH;
  int b = t / NCH;
  int s = chunk * CHUNK - 1 - j;
  float v = (s >= 0) ? proj[((size_t)b * SS + s) * PROJ + COL_HS + c] : 0.f;
  side[((size_t)(b * NCH + chunk) * 3 + j) * CONV_DIM + c] = v;
}

// ---------------------------------------------------------------------------
// Causal depthwise conv1d (K=4) + bias + SiLU, in place on proj[:, 4096:8448).
// One thread per (b, c, chunk); sequential over its 128 timesteps.
// ---------------------------------------------------------------------------
__global__ void conv_silu(float* __restrict__ proj, const float* __restrict__ side,
                          const float* __restrict__ cw, const float* __restrict__ cb) {
  int idx = blockIdx.x * 256 + threadIdx.x;
  const int total = BB * CONV_DIM * NCH;
  if (idx >= total) return;
  int c = idx % CONV_DIM;
  int t = idx / CONV_DIM;
  int chunk = t % NCH;
  int b = t / NCH;
  float w0 = cw[c * 4 + 0], w1 = cw[c * 4 + 1], w2 = cw[c * 4 + 2], w3 = cw[c * 4 + 3];
  float bias = cb[c];
  const float* sd = side + ((size_t)(b * NCH + chunk) * 3) * CONV_DIM;
  float xm1 = sd[c];                 // x[s0-1]
  float xm2 = sd[CONV_DIM + c];      // x[s0-2]
  float xm3 = sd[2 * CONV_DIM + c];  // x[s0-3]
  size_t p = ((size_t)b * SS + (size_t)chunk * CHUNK) * PROJ + COL_HS + c;
  for (int s = 0; s < CHUNK; s++) {
    float xin = proj[p];
    float o = w3 * xin + w2 * xm1 + w1 * xm2 + w0 * xm3 + bias;
    o = o / (1.f + __expf(-o));      // SiLU
    proj[p] = o;
    xm3 = xm2; xm2 = xm1; xm1 = xin;
    p += PROJ;
  }
}

// ---------------------------------------------------------------------------
// Selective SSM scan. Block = (b, h, half): owns 32 d-rows x 128 n of state.
// 256 threads: thread = (dl = tid>>3 in [0,32), n-chunk = (tid&7)*16).
// State in registers (16 f32/thread). Per step: stage B/C/x in LDS (prefetched
// into registers one step ahead), update state, reduce y over 8 lanes, write
// y (+ D*x) in place over the hs column block it alone owns.
// ---------------------------------------------------------------------------
__global__ __launch_bounds__(256) void scan_kernel(
    float* __restrict__ proj, const float* __restrict__ dt_bias,
    const float* __restrict__ A_log, const float* __restrict__ Dp) {
  const int bid = blockIdx.x;
  const int b = bid >> 7;
  const int h = (bid >> 1) & 63;
  const int half = bid & 1;
  const int tid = threadIdx.x;
  const int dl = tid >> 3;          // 0..31
  const int nc = (tid & 7) * 16;    // n-chunk start
  const int d0 = half * 32;
  const float dtb = dt_bias[h];
  const float Ah = -__expf(A_log[h]);
  const float Dh = Dp[h];
  __shared__ float sh_bc[256];
  __shared__ float sh_x[32];
  float st[16];
#pragma unroll
  for (int i = 0; i < 16; i++) st[i] = 0.f;
  const size_t base = (size_t)b * SS * PROJ;
  // prefetch s=0
  float bc_n = proj[base + COL_B + tid];
  float x_n = (tid < 32) ? proj[base + COL_HS + h * 64 + d0 + tid] : 0.f;
  float dtr_n = proj[base + COL_DT + h];
  for (int s = 0; s < SS; s++) {
    __syncthreads();
    sh_bc[tid] = bc_n;
    if (tid < 32) sh_x[tid] = x_n;
    __syncthreads();
    float dtr = dtr_n;
    if (s + 1 < SS) {
      size_t r = base + (size_t)(s + 1) * PROJ;
      bc_n = proj[r + COL_B + tid];
      if (tid < 32) x_n = proj[r + COL_HS + h * 64 + d0 + tid];
      dtr_n = proj[r + COL_DT + h];
    }
    float z = dtr + dtb;
    float dtv = (z > 20.f) ? z : log1pf(__expf(z));  // softplus
    float dAv = __expf(dtv * Ah);
    float x = sh_x[dl];
    float dtx = dtv * x;
    float ysum = 0.f;
#pragma unroll
    for (int q = 0; q < 4; q++) {
      float4 Bv = *(const float4*)&sh_bc[nc + q * 4];
      float4 Cv = *(const float4*)&sh_bc[128 + nc + q * 4];
      st[q * 4 + 0] = st[q * 4 + 0] * dAv + dtx * Bv.x; ysum += st[q * 4 + 0] * Cv.x;
      st[q * 4 + 1] = st[q * 4 + 1] * dAv + dtx * Bv.y; ysum += st[q * 4 + 1] * Cv.y;
      st[q * 4 + 2] = st[q * 4 + 2] * dAv + dtx * Bv.z; ysum += st[q * 4 + 2] * Cv.z;
      st[q * 4 + 3] = st[q * 4 + 3] * dAv + dtx * Bv.w; ysum += st[q * 4 + 3] * Cv.w;
    }
    ysum += __shfl_xor(ysum, 1);
    ysum += __shfl_xor(ysum, 2);
    ysum += __shfl_xor(ysum, 4);
    if ((tid & 7) == 0)
      proj[base + (size_t)s * PROJ + COL_HS + h * 64 + d0 + dl] = ysum + Dh * x;
  }
}

// ---------------------------------------------------------------------------
// Gated RMSNorm, in place over proj[:, 4096:8192). One block per row.
// y = y*silu(gate); y *= rsqrt(mean(y^2)+eps) * norm_weight
// ---------------------------------------------------------------------------
__global__ __launch_bounds__(256) void rmsnorm_kernel(
    float* __restrict__ proj, const float* __restrict__ nw) {
  const int row = blockIdx.x;
  const int tid = threadIdx.x;
  float* yp = proj + (size_t)row * PROJ + COL_HS;
  const float* gp = proj + (size_t)row * PROJ;
  float v[16];
  float ss = 0.f;
#pragma unroll
  for (int q = 0; q < 4; q++) {
    int col = q * 1024 + tid * 4;
    float4 y = *(const float4*)(yp + col);
    float4 g = *(const float4*)(gp + col);
    float vy[4] = {y.x, y.y, y.z, y.w};
    float vg[4] = {g.x, g.y, g.z, g.w};
#pragma unroll
    for (int j = 0; j < 4; j++) {
      float sg = vg[j] / (1.f + __expf(-vg[j]));
      float vv = vy[j] * sg;
      v[q * 4 + j] = vv;
      ss += vv * vv;
    }
  }
#pragma unroll
  for (int o = 1; o < 64; o <<= 1) ss += __shfl_xor(ss, o);
  __shared__ float red[4];
  if ((tid & 63) == 0) red[tid >> 6] = ss;
  __syncthreads();
  float tot = red[0] + red[1] + red[2] + red[3];
  float scale = rsqrtf(tot * (1.f / INTER) + EPS);
#pragma unroll
  for (int q = 0; q < 4; q++) {
    int col = q * 1024 + tid * 4;
    float4 w = *(const float4*)(nw + col);
    float4 o;
    o.x = v[q * 4 + 0] * scale * w.x;
    o.y = v[q * 4 + 1] * scale * w.y;
    o.z = v[q * 4 + 2] * scale * w.z;
    o.w = v[q * 4 + 3] * scale * w.w;
    *(float4*)(yp + col) = o;
  }
}

// ---------------------------------------------------------------------------
extern "C" void kernel_launch(void* const* d_in, const int* in_sizes, int n_in,
                              void* d_out, int out_size, void* d_ws, size_t ws_size,
                              hipStream_t stream) {
  const float* hs   = (const float*)d_in[0];
  const float* w1   = (const float*)d_in[1];
  const float* cw   = (const float*)d_in[2];
  const float* cb   = (const float*)d_in[3];
  const float* dtb  = (const float*)d_in[4];
  const float* alog = (const float*)d_in[5];
  const float* Dp   = (const float*)d_in[6];
  const float* nw   = (const float*)d_in[7];
  const float* w2   = (const float*)d_in[8];
  float* out = (float*)d_out;

  float* proj = (float*)d_ws;                       // [4096, 8512] fp32
  float* side = proj + (size_t)BS * PROJ;           // [B*NCH*3, CONV_DIM]

  // 1) in_proj GEMM: proj = hidden @ W1^T
  gemm_nt<<<dim3(PROJ / TILE, BS / TILE), 256, 0, stream>>>(
      hs, HID, w1, HID, proj, PROJ, HID);

  // 2) conv boundary capture then causal depthwise conv + SiLU (in place)
  conv_capture<<<(BB * CONV_DIM * NCH * 3 + 255) / 256, 256, 0, stream>>>(proj, side);
  conv_silu<<<(BB * CONV_DIM * NCH + 255) / 256, 256, 0, stream>>>(proj, side, cw, cb);

  // 3) selective scan (in place: y over hs columns)
  scan_kernel<<<BB * NH * 2, 256, 0, stream>>>(proj, dtb, alog, Dp);

  // 4) gated RMSNorm (in place)
  rmsnorm_kernel<<<BS, 256, 0, stream>>>(proj, nw);

  // 5) out_proj GEMM: out = ynorm @ W2^T
  gemm_nt<<<dim3(HID / TILE, BS / TILE), 256, 0, stream>>>(
      proj + COL_HS, PROJ, w2, INTER, out, HID, INTER);
}

// Round 2
// 1930.680 us; speedup vs baseline: 2.3863x; 2.3863x over previous
//
#include <hip/hip_runtime.h>
#include <hip/hip_bf16.h>
#include <cstddef>
#include <cstdint>

// Problem constants
#define HID   2048
#define INTER 4096
#define NH    64
#define HD    64
#define NST   128
#define CONV_DIM 4352           // INTER + 2*NST
#define PROJ  8512              // INTER + CONV_DIM + NH
#define PROJ_PAD 8576           // 67 * 128
#define SS    2048
#define BB    2
#define BS    (BB*SS)           // 4096 rows
#define EPS   1e-5f

// proj column layout: [0,4096)=gate  [4096,8192)=hs  [8192,8320)=B  [8320,8448)=C  [8448,8512)=dt
#define COL_HS 4096
#define COL_B  8192
#define COL_DT 8448

#define NCH   16                // conv chunks along S
#define CHUNK 128               // SS / NCH

typedef short s16x8 __attribute__((ext_vector_type(8)));
typedef float f32x4 __attribute__((ext_vector_type(4)));

// ---------------------------------------------------------------------------
// fp32 -> bf16 conversion kernels (memory-bound, vectorized 4/thread)
// ---------------------------------------------------------------------------
__global__ __launch_bounds__(256) void to_bf16(const float* __restrict__ src,
                                               ushort* __restrict__ dst, long n4) {
  long i = (long)blockIdx.x * 256 + threadIdx.x;
  if (i >= n4) return;
  float4 v = *(const float4*)(src + i * 4);
  ushort4 o;
  { __hip_bfloat16 h = __float2bfloat16(v.x); o.x = *(ushort*)&h; }
  { __hip_bfloat16 h = __float2bfloat16(v.y); o.y = *(ushort*)&h; }
  { __hip_bfloat16 h = __float2bfloat16(v.z); o.z = *(ushort*)&h; }
  { __hip_bfloat16 h = __float2bfloat16(v.w); o.w = *(ushort*)&h; }
  *(ushort4*)(dst + i * 4) = o;
}

// w1 conversion with zero-padded rows [8512, 8576)
__global__ __launch_bounds__(256) void to_bf16_pad(const float* __restrict__ src,
                                                   ushort* __restrict__ dst, long n4) {
  long i = (long)blockIdx.x * 256 + threadIdx.x;
  if (i >= n4) return;
  long e0 = i * 4;
  long row = e0 >> 11;  // / 2048
  ushort4 o;
  if (row < PROJ) {
    float4 v = *(const float4*)(src + e0);
    { __hip_bfloat16 h = __float2bfloat16(v.x); o.x = *(ushort*)&h; }
    { __hip_bfloat16 h = __float2bfloat16(v.y); o.y = *(ushort*)&h; }
    { __hip_bfloat16 h = __float2bfloat16(v.z); o.z = *(ushort*)&h; }
    { __hip_bfloat16 h = __float2bfloat16(v.w); o.w = *(ushort*)&h; }
  } else {
    o.x = o.y = o.z = o.w = 0;
  }
  *(ushort4*)(dst + e0) = o;
}

// ---------------------------------------------------------------------------
// bf16 MFMA GEMM (m97 structure): C[m,n] = sum_k A[m,k] * Bw[n,k]
// 128x128 tile, BK=32, 256 threads (4 waves, 2x2), 16x16x32 MFMA, 4x4 frags.
// A [M,lda] bf16 row-major, Bw [N,ldb] bf16 row-major, C fp32 [M,ldc].
// GUARD_N: guard stores at n >= Nmax (B rows are padded so loads are safe).
// ---------------------------------------------------------------------------
__device__ inline void gload16(const void* g, void* l) {
  __builtin_amdgcn_global_load_lds((const __attribute__((address_space(1))) void*)g,
                                   (__attribute__((address_space(3))) void*)l, 16, 0, 0);
}

template <bool GUARD_N>
__global__ __launch_bounds__(256) void gemm_bt16(
    const ushort* __restrict__ A, int lda,
    const ushort* __restrict__ Bw, int ldb,
    float* __restrict__ C, int ldc, int Kd, int Nmax) {
  __shared__ short smem[8192];          // A tile [128][32] | B tile [128][32]
  const int tid = threadIdx.x;
  const int lane = tid & 63;
  const int wid = tid >> 6;
  const int wm = wid >> 1, wn = wid & 1;
  const int r = lane & 15;
  const int kx = lane >> 4;             // 0..3 (k-chunk of 8)
  const ushort* Ab = A + (size_t)(blockIdx.y * 128) * lda;
  const ushort* Bb = Bw + (size_t)(blockIdx.x * 128) * ldb;

  f32x4 acc[4][4];
#pragma unroll
  for (int i = 0; i < 4; i++)
#pragma unroll
    for (int j = 0; j < 4; j++) acc[i][j] = (f32x4)0.f;

  const int u0 = tid, u1 = 256 + tid;
  const int row0 = u0 >> 2, kc0 = (u0 & 3) * 8;
  const int row1 = u1 >> 2, kc1 = (u1 & 3) * 8;

  const s16x8* As8 = (const s16x8*)smem;          // 512 entries
  const s16x8* Bs8 = (const s16x8*)(smem + 4096); // 512 entries

  for (int k0 = 0; k0 < Kd; k0 += 32) {
    __syncthreads();
    gload16(Ab + (size_t)row0 * lda + k0 + kc0, smem + u0 * 8);
    gload16(Ab + (size_t)row1 * lda + k0 + kc1, smem + u1 * 8);
    gload16(Bb + (size_t)row0 * ldb + k0 + kc0, smem + 4096 + u0 * 8);
    gload16(Bb + (size_t)row1 * ldb + k0 + kc1, smem + 4096 + u1 * 8);
    __syncthreads();
    s16x8 af[4], bw[4];
#pragma unroll
    for (int i = 0; i < 4; i++) af[i] = As8[(wm * 64 + i * 16 + r) * 4 + kx];
#pragma unroll
    for (int j = 0; j < 4; j++) bw[j] = Bs8[(wn * 64 + j * 16 + r) * 4 + kx];
#pragma unroll
    for (int i = 0; i < 4; i++)
#pragma unroll
      for (int j = 0; j < 4; j++)
        acc[i][j] = __builtin_amdgcn_mfma_f32_16x16x32_bf16(af[i], bw[j], acc[i][j], 0, 0, 0);
  }

  // Epilogue: lane holds D[row=(lane>>4)*4+q][col=lane&15] per fragment
  const int m0 = blockIdx.y * 128 + wm * 64 + (lane >> 4) * 4;
  const int n0 = blockIdx.x * 128 + wn * 64 + (lane & 15);
#pragma unroll
  for (int i = 0; i < 4; i++) {
#pragma unroll
    for (int j = 0; j < 4; j++) {
      int n = n0 + j * 16;
      if (GUARD_N && n >= Nmax) continue;
#pragma unroll
      for (int q = 0; q < 4; q++) {
        C[(size_t)(m0 + i * 16 + q) * ldc + n] = acc[i][j][q];
      }
    }
  }
}

// ---------------------------------------------------------------------------
// Conv boundary capture: for each (b, c, chunk) save x[s0-1..s0-3]
// ---------------------------------------------------------------------------
__global__ void conv_capture(const float* __restrict__ proj, float* __restrict__ side) {
  int idx = blockIdx.x * 256 + threadIdx.x;
  const int total = BB * CONV_DIM * NCH * 3;
  if (idx >= total) return;
  int c = idx % CONV_DIM;
  int t = idx / CONV_DIM;
  int j = t % 3; t /= 3;
  int chunk = t % NCH;
  int b = t / NCH;
  int s = chunk * CHUNK - 1 - j;
  float v = (s >= 0) ? proj[((size_t)b * SS + s) * PROJ + COL_HS + c] : 0.f;
  side[((size_t)(b * NCH + chunk) * 3 + j) * CONV_DIM + c] = v;
}

// ---------------------------------------------------------------------------
// Causal depthwise conv1d (K=4) + bias + SiLU, in place
// ---------------------------------------------------------------------------
__global__ void conv_silu(float* __restrict__ proj, const float* __restrict__ side,
                          const float* __restrict__ cw, const float* __restrict__ cb) {
  int idx = blockIdx.x * 256 + threadIdx.x;
  const int total = BB * CONV_DIM * NCH;
  if (idx >= total) return;
  int c = idx % CONV_DIM;
  int t = idx / CONV_DIM;
  int chunk = t % NCH;
  int b = t / NCH;
  float w0 = cw[c * 4 + 0], w1 = cw[c * 4 + 1], w2 = cw[c * 4 + 2], w3 = cw[c * 4 + 3];
  float bias = cb[c];
  const float* sd = side + ((size_t)(b * NCH + chunk) * 3) * CONV_DIM;
  float xm1 = sd[c];
  float xm2 = sd[CONV_DIM + c];
  float xm3 = sd[2 * CONV_DIM + c];
  size_t p = ((size_t)b * SS + (size_t)chunk * CHUNK) * PROJ + COL_HS + c;
  for (int s = 0; s < CHUNK; s++) {
    float xin = proj[p];
    float o = w3 * xin + w2 * xm1 + w1 * xm2 + w0 * xm3 + bias;
    o = o / (1.f + __expf(-o));      // SiLU
    proj[p] = o;
    xm3 = xm2; xm2 = xm1; xm1 = xin;
    p += PROJ;
  }
}

// ---------------------------------------------------------------------------
// Selective SSM scan (unchanged this round; SSD rewrite next round)
// ---------------------------------------------------------------------------
__global__ __launch_bounds__(256) void scan_kernel(
    float* __restrict__ proj, const float* __restrict__ dt_bias,
    const float* __restrict__ A_log, const float* __restrict__ Dp) {
  const int bid = blockIdx.x;
  const int b = bid >> 7;
  const int h = (bid >> 1) & 63;
  const int half = bid & 1;
  const int tid = threadIdx.x;
  const int dl = tid >> 3;          // 0..31
  const int nc = (tid & 7) * 16;    // n-chunk start
  const int d0 = half * 32;
  const float dtb = dt_bias[h];
  const float Ah = -__expf(A_log[h]);
  const float Dh = Dp[h];
  __shared__ float sh_bc[256];
  __shared__ float sh_x[32];
  float st[16];
#pragma unroll
  for (int i = 0; i < 16; i++) st[i] = 0.f;
  const size_t base = (size_t)b * SS * PROJ;
  float bc_n = proj[base + COL_B + tid];
  float x_n = (tid < 32) ? proj[base + COL_HS + h * 64 + d0 + tid] : 0.f;
  float dtr_n = proj[base + COL_DT + h];
  for (int s = 0; s < SS; s++) {
    __syncthreads();
    sh_bc[tid] = bc_n;
    if (tid < 32) sh_x[tid] = x_n;
    __syncthreads();
    float dtr = dtr_n;
    if (s + 1 < SS) {
      size_t rr = base + (size_t)(s + 1) * PROJ;
      bc_n = proj[rr + COL_B + tid];
      if (tid < 32) x_n = proj[rr + COL_HS + h * 64 + d0 + tid];
      dtr_n = proj[rr + COL_DT + h];
    }
    float z = dtr + dtb;
    float dtv = (z > 20.f) ? z : log1pf(__expf(z));  // softplus
    float dAv = __expf(dtv * Ah);
    float x = sh_x[dl];
    float dtx = dtv * x;
    float ysum = 0.f;
#pragma unroll
    for (int q = 0; q < 4; q++) {
      float4 Bv = *(const float4*)&sh_bc[nc + q * 4];
      float4 Cv = *(const float4*)&sh_bc[128 + nc + q * 4];
      st[q * 4 + 0] = st[q * 4 + 0] * dAv + dtx * Bv.x; ysum += st[q * 4 + 0] * Cv.x;
      st[q * 4 + 1] = st[q * 4 + 1] * dAv + dtx * Bv.y; ysum += st[q * 4 + 1] * Cv.y;
      st[q * 4 + 2] = st[q * 4 + 2] * dAv + dtx * Bv.z; ysum += st[q * 4 + 2] * Cv.z;
      st[q * 4 + 3] = st[q * 4 + 3] * dAv + dtx * Bv.w; ysum += st[q * 4 + 3] * Cv.w;
    }
    ysum += __shfl_xor(ysum, 1);
    ysum += __shfl_xor(ysum, 2);
    ysum += __shfl_xor(ysum, 4);
    if ((tid & 7) == 0)
      proj[base + (size_t)s * PROJ + COL_HS + h * 64 + d0 + dl] = ysum + Dh * x;
  }
}

// ---------------------------------------------------------------------------
// Gated RMSNorm: reads proj (gate + y), writes bf16 normalized y to y16.
// ---------------------------------------------------------------------------
__global__ __launch_bounds__(256) void rmsnorm_kernel(
    const float* __restrict__ proj, const float* __restrict__ nw,
    ushort* __restrict__ y16) {
  const int row = blockIdx.x;
  const int tid = threadIdx.x;
  const float* yp = proj + (size_t)row * PROJ + COL_HS;
  const float* gp = proj + (size_t)row * PROJ;
  float v[16];
  float ss = 0.f;
#pragma unroll
  for (int q = 0; q < 4; q++) {
    int col = q * 1024 + tid * 4;
    float4 y = *(const float4*)(yp + col);
    float4 g = *(const float4*)(gp + col);
    float vy[4] = {y.x, y.y, y.z, y.w};
    float vg[4] = {g.x, g.y, g.z, g.w};
#pragma unroll
    for (int j = 0; j < 4; j++) {
      float sg = vg[j] / (1.f + __expf(-vg[j]));
      float vv = vy[j] * sg;
      v[q * 4 + j] = vv;
      ss += vv * vv;
    }
  }
#pragma unroll
  for (int o = 1; o < 64; o <<= 1) ss += __shfl_xor(ss, o);
  __shared__ float red[4];
  if ((tid & 63) == 0) red[tid >> 6] = ss;
  __syncthreads();
  float tot = red[0] + red[1] + red[2] + red[3];
  float scale = rsqrtf(tot * (1.f / INTER) + EPS);
#pragma unroll
  for (int q = 0; q < 4; q++) {
    int col = q * 1024 + tid * 4;
    float4 w = *(const float4*)(nw + col);
    ushort4 o;
    { __hip_bfloat16 h = __float2bfloat16(v[q * 4 + 0] * scale * w.x); o.x = *(ushort*)&h; }
    { __hip_bfloat16 h = __float2bfloat16(v[q * 4 + 1] * scale * w.y); o.y = *(ushort*)&h; }
    { __hip_bfloat16 h = __float2bfloat16(v[q * 4 + 2] * scale * w.z); o.z = *(ushort*)&h; }
    { __hip_bfloat16 h = __float2bfloat16(v[q * 4 + 3] * scale * w.w); o.w = *(ushort*)&h; }
    *(ushort4*)(y16 + (size_t)row * INTER + col) = o;
  }
}

// ---------------------------------------------------------------------------
extern "C" void kernel_launch(void* const* d_in, const int* in_sizes, int n_in,
                              void* d_out, int out_size, void* d_ws, size_t ws_size,
                              hipStream_t stream) {
  const float* hs   = (const float*)d_in[0];
  const float* w1   = (const float*)d_in[1];
  const float* cw   = (const float*)d_in[2];
  const float* cb   = (const float*)d_in[3];
  const float* dtb  = (const float*)d_in[4];
  const float* alog = (const float*)d_in[5];
  const float* Dp   = (const float*)d_in[6];
  const float* nw   = (const float*)d_in[7];
  const float* w2   = (const float*)d_in[8];
  float* out = (float*)d_out;

  // ws layout (bytes)
  char* base = (char*)d_ws;
  size_t off = 0;
  float* proj = (float*)(base + off); off += (size_t)BS * PROJ * 4;        // 139.5 MB
  float* side = (float*)(base + off); off += (size_t)BB * NCH * 3 * CONV_DIM * 4;
  off = (off + 255) & ~(size_t)255;
  ushort* hs16 = (ushort*)(base + off); off += (size_t)BS * HID * 2;       // 16.8 MB
  off = (off + 255) & ~(size_t)255;
  ushort* w1p  = (ushort*)(base + off);                                    // 35.1 MB
  ushort* y16  = w1p;  // aliases w1p (dead after in_proj GEMM)
  off += (size_t)PROJ_PAD * HID * 2;
  off = (off + 255) & ~(size_t)255;
  ushort* w216 = (ushort*)(base + off); off += (size_t)HID * INTER * 2;    // 16.8 MB

  // 0) fp32 -> bf16 conversions
  {
    long n4 = (long)BS * HID / 4;
    to_bf16<<<(n4 + 255) / 256, 256, 0, stream>>>(hs, hs16, n4);
  }
  {
    long n4 = (long)PROJ_PAD * HID / 4;
    to_bf16_pad<<<(n4 + 255) / 256, 256, 0, stream>>>(w1, w1p, n4);
  }
  {
    long n4 = (long)HID * INTER / 4;
    to_bf16<<<(n4 + 255) / 256, 256, 0, stream>>>(w2, w216, n4);
  }

  // 1) in_proj GEMM: proj = hs @ w1^T   [4096 x 8512], K=2048
  gemm_bt16<true><<<dim3(PROJ_PAD / 128, BS / 128), 256, 0, stream>>>(
      hs16, HID, w1p, HID, proj, PROJ, HID, PROJ);

  // 2) conv boundary capture then causal depthwise conv + SiLU (in place)
  conv_capture<<<(BB * CONV_DIM * NCH * 3 + 255) / 256, 256, 0, stream>>>(proj, side);
  conv_silu<<<(BB * CONV_DIM * NCH + 255) / 256, 256, 0, stream>>>(proj, side, cw, cb);

  // 3) selective scan (in place: y over hs columns)
  scan_kernel<<<BB * NH * 2, 256, 0, stream>>>(proj, dtb, alog, Dp);

  // 4) gated RMSNorm -> bf16 y16
  rmsnorm_kernel<<<BS, 256, 0, stream>>>(proj, nw, y16);

  // 5) out_proj GEMM: out = y16 @ w2^T   [4096 x 2048], K=4096
  gemm_bt16<false><<<dim3(HID / 128, BS / 128), 256, 0, stream>>>(
      y16, INTER, w216, INTER, out, HID, INTER, HID);
}

// Round 3
// 606.004 us; speedup vs baseline: 7.6024x; 3.1859x over previous
//
#include <hip/hip_runtime.h>
#include <hip/hip_bf16.h>
#include <cstddef>
#include <cstdint>

// Problem constants
#define HID   2048
#define INTER 4096
#define NH    64
#define HD    64
#define NST   128
#define CONV_DIM 4352           // INTER + 2*NST
#define PROJ  8512              // INTER + CONV_DIM + NH
#define PROJ_PAD 8576           // 67 * 128
#define SS    2048
#define BB    2
#define BS    (BB*SS)           // 4096 rows
#define EPS   1e-5f

// proj column layout: [0,4096)=gate [4096,8192)=hs [8192,8320)=B [8320,8448)=C [8448,8512)=dt
#define COL_HS 4096
#define COL_B  8192
#define COL_C  8320
#define COL_DT 8448

#define NCH   16                // conv chunks along S
#define CHUNK 128               // SS / NCH

// SSD chunking
#define CL    128               // chunk length
#define NCHK  16                // SS / CL

typedef short s16x8 __attribute__((ext_vector_type(8)));
typedef float f32x4 __attribute__((ext_vector_type(4)));

__device__ inline ushort f2b(float x) {
  __hip_bfloat16 h = __float2bfloat16(x);
  return *(ushort*)&h;
}
__device__ inline float b2f(ushort u) {
  unsigned int v = ((unsigned int)u) << 16;
  return __uint_as_float(v);
}
// LDS tile: 256B rows (128 bf16), XOR-swizzled in 8-elem slots (T2)
__device__ inline int swz(int row, int e) { return row * 128 + (e ^ ((row & 7) << 3)); }

// ---------------------------------------------------------------------------
// fp32 -> bf16 conversion kernels
// ---------------------------------------------------------------------------
__global__ __launch_bounds__(256) void to_bf16(const float* __restrict__ src,
                                               ushort* __restrict__ dst, long n4) {
  long i = (long)blockIdx.x * 256 + threadIdx.x;
  if (i >= n4) return;
  float4 v = *(const float4*)(src + i * 4);
  ushort4 o;
  o.x = f2b(v.x); o.y = f2b(v.y); o.z = f2b(v.z); o.w = f2b(v.w);
  *(ushort4*)(dst + i * 4) = o;
}

__global__ __launch_bounds__(256) void to_bf16_pad(const float* __restrict__ src,
                                                   ushort* __restrict__ dst, long n4) {
  long i = (long)blockIdx.x * 256 + threadIdx.x;
  if (i >= n4) return;
  long e0 = i * 4;
  long row = e0 >> 11;  // / 2048
  ushort4 o;
  if (row < PROJ) {
    float4 v = *(const float4*)(src + e0);
    o.x = f2b(v.x); o.y = f2b(v.y); o.z = f2b(v.z); o.w = f2b(v.w);
  } else {
    o.x = o.y = o.z = o.w = 0;
  }
  *(ushort4*)(dst + e0) = o;
}

// ---------------------------------------------------------------------------
// bf16 MFMA GEMM (m97 structure)
// ---------------------------------------------------------------------------
__device__ inline void gload16(const void* g, void* l) {
  __builtin_amdgcn_global_load_lds((const __attribute__((address_space(1))) void*)g,
                                   (__attribute__((address_space(3))) void*)l, 16, 0, 0);
}

template <bool GUARD_N>
__global__ __launch_bounds__(256) void gemm_bt16(
    const ushort* __restrict__ A, int lda,
    const ushort* __restrict__ Bw, int ldb,
    float* __restrict__ C, int ldc, int Kd, int Nmax) {
  __shared__ short smem[8192];
  const int tid = threadIdx.x;
  const int lane = tid & 63;
  const int wid = tid >> 6;
  const int wm = wid >> 1, wn = wid & 1;
  const int r = lane & 15;
  const int kx = lane >> 4;
  const ushort* Ab = A + (size_t)(blockIdx.y * 128) * lda;
  const ushort* Bb = Bw + (size_t)(blockIdx.x * 128) * ldb;

  f32x4 acc[4][4];
#pragma unroll
  for (int i = 0; i < 4; i++)
#pragma unroll
    for (int j = 0; j < 4; j++) acc[i][j] = (f32x4)0.f;

  const int u0 = tid, u1 = 256 + tid;
  const int row0 = u0 >> 2, kc0 = (u0 & 3) * 8;
  const int row1 = u1 >> 2, kc1 = (u1 & 3) * 8;

  const s16x8* As8 = (const s16x8*)smem;
  const s16x8* Bs8 = (const s16x8*)(smem + 4096);

  for (int k0 = 0; k0 < Kd; k0 += 32) {
    __syncthreads();
    gload16(Ab + (size_t)row0 * lda + k0 + kc0, smem + u0 * 8);
    gload16(Ab + (size_t)row1 * lda + k0 + kc1, smem + u1 * 8);
    gload16(Bb + (size_t)row0 * ldb + k0 + kc0, smem + 4096 + u0 * 8);
    gload16(Bb + (size_t)row1 * ldb + k0 + kc1, smem + 4096 + u1 * 8);
    __syncthreads();
    s16x8 af[4], bw[4];
#pragma unroll
    for (int i = 0; i < 4; i++) af[i] = As8[(wm * 64 + i * 16 + r) * 4 + kx];
#pragma unroll
    for (int j = 0; j < 4; j++) bw[j] = Bs8[(wn * 64 + j * 16 + r) * 4 + kx];
#pragma unroll
    for (int i = 0; i < 4; i++)
#pragma unroll
      for (int j = 0; j < 4; j++)
        acc[i][j] = __builtin_amdgcn_mfma_f32_16x16x32_bf16(af[i], bw[j], acc[i][j], 0, 0, 0);
  }

  const int m0 = blockIdx.y * 128 + wm * 64 + (lane >> 4) * 4;
  const int n0 = blockIdx.x * 128 + wn * 64 + (lane & 15);
#pragma unroll
  for (int i = 0; i < 4; i++) {
#pragma unroll
    for (int j = 0; j < 4; j++) {
      int n = n0 + j * 16;
      if (GUARD_N && n >= Nmax) continue;
#pragma unroll
      for (int q = 0; q < 4; q++) {
        C[(size_t)(m0 + i * 16 + q) * ldc + n] = acc[i][j][q];
      }
    }
  }
}

// ---------------------------------------------------------------------------
// Conv boundary capture
// ---------------------------------------------------------------------------
__global__ void conv_capture(const float* __restrict__ proj, float* __restrict__ side) {
  int idx = blockIdx.x * 256 + threadIdx.x;
  const int total = BB * CONV_DIM * NCH * 3;
  if (idx >= total) return;
  int c = idx % CONV_DIM;
  int t = idx / CONV_DIM;
  int j = t % 3; t /= 3;
  int chunk = t % NCH;
  int b = t / NCH;
  int s = chunk * CHUNK - 1 - j;
  float v = (s >= 0) ? proj[((size_t)b * SS + s) * PROJ + COL_HS + c] : 0.f;
  side[((size_t)(b * NCH + chunk) * 3 + j) * CONV_DIM + c] = v;
}

// ---------------------------------------------------------------------------
// Causal depthwise conv1d (K=4) + bias + SiLU, in place
// ---------------------------------------------------------------------------
__global__ void conv_silu(float* __restrict__ proj, const float* __restrict__ side,
                          const float* __restrict__ cw, const float* __restrict__ cb) {
  int idx = blockIdx.x * 256 + threadIdx.x;
  const int total = BB * CONV_DIM * NCH;
  if (idx >= total) return;
  int c = idx % CONV_DIM;
  int t = idx / CONV_DIM;
  int chunk = t % NCH;
  int b = t / NCH;
  float w0 = cw[c * 4 + 0], w1 = cw[c * 4 + 1], w2 = cw[c * 4 + 2], w3 = cw[c * 4 + 3];
  float bias = cb[c];
  const float* sd = side + ((size_t)(b * NCH + chunk) * 3) * CONV_DIM;
  float xm1 = sd[c];
  float xm2 = sd[CONV_DIM + c];
  float xm3 = sd[2 * CONV_DIM + c];
  size_t p = ((size_t)b * SS + (size_t)chunk * CHUNK) * PROJ + COL_HS + c;
  for (int s = 0; s < CHUNK; s++) {
    float xin = proj[p];
    float o = w3 * xin + w2 * xm1 + w1 * xm2 + w0 * xm3 + bias;
    o = o / (1.f + __expf(-o));      // SiLU
    proj[p] = o;
    xm3 = xm2; xm2 = xm1; xm1 = xin;
    p += PROJ;
  }
}

// ---------------------------------------------------------------------------
// SSD K1: per (b,h,chunk) compute softplus(dt), cumsum, and chunk state
// S_chunk[n,d] = sum_t B[t,n] * (exp(cumL-cum[t])*dtv[t] * X[t,d])   (MFMA)
// ---------------------------------------------------------------------------
__global__ __launch_bounds__(256) void ssd_chunk_state(
    const float* __restrict__ proj, const float* __restrict__ dt_bias,
    const float* __restrict__ A_log, ushort* __restrict__ states,
    float* __restrict__ cumbuf, float* __restrict__ dtvbuf) {
  const int bid = blockIdx.x;
  const int c = bid & 15;
  const int h = (bid >> 4) & 63;
  const int b = bid >> 10;
  const int tid = threadIdx.x;
  const int lane = tid & 63;
  const int wv = tid >> 6;
  __shared__ float sdtv[CL], scum[CL], sw[CL];
  __shared__ ushort sBt[128 * 128];   // [n][t]
  __shared__ ushort sXw[64 * 128];    // [d][t] scaled
  const size_t row0 = (size_t)b * SS + (size_t)c * CL;
  const size_t bh = (size_t)(b * NH + h);

  const float Ah = -__expf(A_log[h]);
  if (tid < CL) {
    float z = proj[(row0 + tid) * PROJ + COL_DT + h] + dt_bias[h];
    float dtv = (z > 20.f) ? z : log1pf(__expf(z));
    sdtv[tid] = dtv;
    sw[tid] = dtv * Ah;
  }
  __syncthreads();
  // inclusive Hillis-Steele scan over sw
  for (int off = 1; off < CL; off <<= 1) {
    float v = 0.f;
    if (tid < CL) { v = sw[tid]; if (tid >= off) v += sw[tid - off]; }
    __syncthreads();
    if (tid < CL) sw[tid] = v;
    __syncthreads();
  }
  if (tid < CL) {
    scum[tid] = sw[tid];
    cumbuf[bh * SS + c * CL + tid] = sw[tid];
    dtvbuf[bh * SS + c * CL + tid] = sdtv[tid];
  }
  __syncthreads();
  const float cumL = scum[CL - 1];
  if (tid < CL) sw[tid] = __expf(cumL - scum[tid]) * sdtv[tid];
  __syncthreads();

  // stage B^T [n][t] (unscaled)
  {
    const int t = tid >> 1, n0 = (tid & 1) * 64;
    const float* src = proj + (row0 + t) * PROJ + COL_B + n0;
#pragma unroll
    for (int j = 0; j < 64; j += 4) {
      float4 v = *(const float4*)(src + j);
      sBt[swz(n0 + j + 0, t)] = f2b(v.x);
      sBt[swz(n0 + j + 1, t)] = f2b(v.y);
      sBt[swz(n0 + j + 2, t)] = f2b(v.z);
      sBt[swz(n0 + j + 3, t)] = f2b(v.w);
    }
  }
  // stage Xw^T [d][t] scaled by sw[t]
  {
    const int d = tid & 63;
    const int t0 = (tid >> 6) * 32;
    for (int t = t0; t < t0 + 32; t++) {
      float x = proj[(row0 + t) * PROJ + COL_HS + h * 64 + d];
      sXw[swz(d, t)] = f2b(x * sw[t]);
    }
  }
  __syncthreads();

  // MFMA: wave wv owns n rows [wv*32, +32)
  const int r = lane & 15, kx = lane >> 4;
  f32x4 acc[2][4];
#pragma unroll
  for (int i = 0; i < 2; i++)
#pragma unroll
    for (int j = 0; j < 4; j++) acc[i][j] = (f32x4)0.f;
#pragma unroll
  for (int kk = 0; kk < 4; kk++) {
    s16x8 a[2], bo[4];
#pragma unroll
    for (int i = 0; i < 2; i++)
      a[i] = *(const s16x8*)&sBt[swz(wv * 32 + i * 16 + r, kk * 32 + kx * 8)];
#pragma unroll
    for (int j = 0; j < 4; j++)
      bo[j] = *(const s16x8*)&sXw[swz(j * 16 + r, kk * 32 + kx * 8)];
#pragma unroll
    for (int i = 0; i < 2; i++)
#pragma unroll
      for (int j = 0; j < 4; j++)
        acc[i][j] = __builtin_amdgcn_mfma_f32_16x16x32_bf16(a[i], bo[j], acc[i][j], 0, 0, 0);
  }
  ushort* dst = states + (size_t)bid * (128 * 64);
#pragma unroll
  for (int i = 0; i < 2; i++) {
#pragma unroll
    for (int j = 0; j < 4; j++) {
      int n = wv * 32 + i * 16 + (lane >> 4) * 4;
      int d = (lane & 15) + j * 16;
#pragma unroll
      for (int q = 0; q < 4; q++)
        dst[(size_t)(n + q) * 64 + d] = f2b(acc[i][j][q]);
    }
  }
}

// ---------------------------------------------------------------------------
// SSD K2: inter-chunk recurrence. Block = (b,h). In place: S_chunk -> S_prev.
// ---------------------------------------------------------------------------
__global__ __launch_bounds__(256) void ssd_state_scan(
    ushort* __restrict__ states, const float* __restrict__ cumbuf) {
  const int bh = blockIdx.x;
  const int tid = threadIdx.x;
  float run[32];
#pragma unroll
  for (int i = 0; i < 32; i++) run[i] = 0.f;
  for (int c = 0; c < NCHK; c++) {
    float dec = __expf(cumbuf[(size_t)bh * SS + c * CL + (CL - 1)]);
    ushort* p = states + ((size_t)bh * NCHK + c) * 8192 + tid * 32;
    s16x8 in[4];
#pragma unroll
    for (int v = 0; v < 4; v++) in[v] = *(const s16x8*)(p + v * 8);
    s16x8 out[4];
#pragma unroll
    for (int v = 0; v < 4; v++) {
#pragma unroll
      for (int e = 0; e < 8; e++) {
        int i = v * 8 + e;
        out[v][e] = (short)f2b(run[i]);
        run[i] = dec * run[i] + b2f((ushort)in[v][e]);
      }
    }
#pragma unroll
    for (int v = 0; v < 4; v++) *(s16x8*)(p + v * 8) = out[v];
  }
}

// ---------------------------------------------------------------------------
// SSD K3: per (b,h,chunk) fused output:
//  G = C@B^T; P = mask*exp(cum[t]-cum[tau])*dtv[tau]*G (bf16);
//  y = P@X + (exp(cum[t])*C)@S_prev + D*X  -> written in place to proj hs cols
// ---------------------------------------------------------------------------
__global__ __launch_bounds__(256) void ssd_chunk_out(
    float* __restrict__ proj, const ushort* __restrict__ states,
    const float* __restrict__ cumbuf, const float* __restrict__ dtvbuf,
    const float* __restrict__ Dp) {
  const int bid = blockIdx.x;
  const int c = bid & 15;
  const int h = (bid >> 4) & 63;
  const int b = bid >> 10;
  const int tid = threadIdx.x;
  const int lane = tid & 63;
  const int wv = tid >> 6;
  __shared__ ushort sC[128 * 128];   // [t][n], later scaled -> Cs
  __shared__ ushort sB[128 * 128];   // [tau][n], later overwritten by P [t][tau]
  __shared__ ushort sX[64 * 128];    // [d][t]
  __shared__ ushort sS[64 * 128];    // [d][n] = S_prev^T
  __shared__ float scum[CL], sdtv[CL];
  const size_t row0 = (size_t)b * SS + (size_t)c * CL;
  const size_t bh = (size_t)(b * NH + h);

  if (tid < CL) {
    scum[tid] = cumbuf[bh * SS + c * CL + tid];
    sdtv[tid] = dtvbuf[bh * SS + c * CL + tid];
  }
  // stage C and B natural [t][n]
  {
    const int t = tid >> 1, n0 = (tid & 1) * 64;
    const float* srcC = proj + (row0 + t) * PROJ + COL_C + n0;
    const float* srcB = proj + (row0 + t) * PROJ + COL_B + n0;
#pragma unroll
    for (int j = 0; j < 64; j += 8) {
      float4 c0 = *(const float4*)(srcC + j);
      float4 c1 = *(const float4*)(srcC + j + 4);
      s16x8 u;
      u[0] = (short)f2b(c0.x); u[1] = (short)f2b(c0.y);
      u[2] = (short)f2b(c0.z); u[3] = (short)f2b(c0.w);
      u[4] = (short)f2b(c1.x); u[5] = (short)f2b(c1.y);
      u[6] = (short)f2b(c1.z); u[7] = (short)f2b(c1.w);
      *(s16x8*)&sC[swz(t, n0 + j)] = u;
      float4 b0 = *(const float4*)(srcB + j);
      float4 b1 = *(const float4*)(srcB + j + 4);
      s16x8 w;
      w[0] = (short)f2b(b0.x); w[1] = (short)f2b(b0.y);
      w[2] = (short)f2b(b0.z); w[3] = (short)f2b(b0.w);
      w[4] = (short)f2b(b1.x); w[5] = (short)f2b(b1.y);
      w[6] = (short)f2b(b1.z); w[7] = (short)f2b(b1.w);
      *(s16x8*)&sB[swz(t, n0 + j)] = w;
    }
  }
  // stage X^T [d][t]
  {
    const int d = tid & 63;
    const int t0 = (tid >> 6) * 32;
    for (int t = t0; t < t0 + 32; t++)
      sX[swz(d, t)] = f2b(proj[(row0 + t) * PROJ + COL_HS + h * 64 + d]);
  }
  // stage S_prev^T [d][n]
  {
    const int d = tid & 63;
    const int n0 = (tid >> 6) * 32;
    const ushort* sp = states + (size_t)bid * 8192;
    for (int n = n0; n < n0 + 32; n++)
      sS[swz(d, n)] = sp[(size_t)n * 64 + d];
  }
  __syncthreads();

  // Phase G: G = C @ B^T; wave wv owns t rows [wv*32, +32)
  const int r = lane & 15, kx = lane >> 4;
  f32x4 g[2][8];
#pragma unroll
  for (int i = 0; i < 2; i++)
#pragma unroll
    for (int j = 0; j < 8; j++) g[i][j] = (f32x4)0.f;
#pragma unroll
  for (int kk = 0; kk < 4; kk++) {
    s16x8 a[2], bo[8];
#pragma unroll
    for (int i = 0; i < 2; i++)
      a[i] = *(const s16x8*)&sC[swz(wv * 32 + i * 16 + r, kk * 32 + kx * 8)];
#pragma unroll
    for (int j = 0; j < 8; j++)
      bo[j] = *(const s16x8*)&sB[swz(j * 16 + r, kk * 32 + kx * 8)];
#pragma unroll
    for (int i = 0; i < 2; i++)
#pragma unroll
      for (int j = 0; j < 8; j++)
        g[i][j] = __builtin_amdgcn_mfma_f32_16x16x32_bf16(a[i], bo[j], g[i][j], 0, 0, 0);
  }
  __syncthreads();   // all waves done reading sB / sC

  // Phase P: write P[t][tau] over sB; scale own sC rows -> Cs
  float ct[2][4];
#pragma unroll
  for (int i = 0; i < 2; i++)
#pragma unroll
    for (int q = 0; q < 4; q++)
      ct[i][q] = scum[wv * 32 + i * 16 + ((lane >> 4) << 2) + q];
#pragma unroll
  for (int j = 0; j < 8; j++) {
    int tau = j * 16 + (lane & 15);
    float cu = scum[tau], dv = sdtv[tau];
#pragma unroll
    for (int i = 0; i < 2; i++) {
#pragma unroll
      for (int q = 0; q < 4; q++) {
        int t = wv * 32 + i * 16 + ((lane >> 4) << 2) + q;
        float val = (tau <= t) ? g[i][j][q] * __expf(ct[i][q] - cu) * dv : 0.f;
        sB[swz(t, tau)] = f2b(val);
      }
    }
  }
  {
    int t = wv * 32 + (lane >> 1);
    int n0 = (lane & 1) * 64;
    float e = __expf(scum[t]);
#pragma unroll
    for (int j = 0; j < 64; j += 8) {
      s16x8 u = *(const s16x8*)&sC[swz(t, n0 + j)];
#pragma unroll
      for (int k = 0; k < 8; k++) u[k] = (short)f2b(b2f((ushort)u[k]) * e);
      *(s16x8*)&sC[swz(t, n0 + j)] = u;
    }
  }
  __syncthreads();

  // Phase Y: y = P@X^T + Cs@Sp^T
  f32x4 y[2][4];
#pragma unroll
  for (int i = 0; i < 2; i++)
#pragma unroll
    for (int j = 0; j < 4; j++) y[i][j] = (f32x4)0.f;
#pragma unroll
  for (int kk = 0; kk < 4; kk++) {
    s16x8 a[2], bo[4];
#pragma unroll
    for (int i = 0; i < 2; i++)
      a[i] = *(const s16x8*)&sB[swz(wv * 32 + i * 16 + r, kk * 32 + kx * 8)];
#pragma unroll
    for (int j = 0; j < 4; j++)
      bo[j] = *(const s16x8*)&sX[swz(j * 16 + r, kk * 32 + kx * 8)];
#pragma unroll
    for (int i = 0; i < 2; i++)
#pragma unroll
      for (int j = 0; j < 4; j++)
        y[i][j] = __builtin_amdgcn_mfma_f32_16x16x32_bf16(a[i], bo[j], y[i][j], 0, 0, 0);
  }
#pragma unroll
  for (int kk = 0; kk < 4; kk++) {
    s16x8 a[2], bo[4];
#pragma unroll
    for (int i = 0; i < 2; i++)
      a[i] = *(const s16x8*)&sC[swz(wv * 32 + i * 16 + r, kk * 32 + kx * 8)];
#pragma unroll
    for (int j = 0; j < 4; j++)
      bo[j] = *(const s16x8*)&sS[swz(j * 16 + r, kk * 32 + kx * 8)];
#pragma unroll
    for (int i = 0; i < 2; i++)
#pragma unroll
      for (int j = 0; j < 4; j++)
        y[i][j] = __builtin_amdgcn_mfma_f32_16x16x32_bf16(a[i], bo[j], y[i][j], 0, 0, 0);
  }

  // Epilogue: add D*x, write y in place
  const float Dh = Dp[h];
#pragma unroll
  for (int i = 0; i < 2; i++) {
#pragma unroll
    for (int j = 0; j < 4; j++) {
      int t0 = wv * 32 + i * 16 + (lane >> 4) * 4;
      int d = (lane & 15) + j * 16;
#pragma unroll
      for (int q = 0; q < 4; q++) {
        float x = b2f(sX[swz(d, t0 + q)]);
        proj[(row0 + t0 + q) * PROJ + COL_HS + h * 64 + d] = y[i][j][q] + Dh * x;
      }
    }
  }
}

// ---------------------------------------------------------------------------
// Gated RMSNorm -> bf16 y16
// ---------------------------------------------------------------------------
__global__ __launch_bounds__(256) void rmsnorm_kernel(
    const float* __restrict__ proj, const float* __restrict__ nw,
    ushort* __restrict__ y16) {
  const int row = blockIdx.x;
  const int tid = threadIdx.x;
  const float* yp = proj + (size_t)row * PROJ + COL_HS;
  const float* gp = proj + (size_t)row * PROJ;
  float v[16];
  float ss = 0.f;
#pragma unroll
  for (int q = 0; q < 4; q++) {
    int col = q * 1024 + tid * 4;
    float4 y = *(const float4*)(yp + col);
    float4 g = *(const float4*)(gp + col);
    float vy[4] = {y.x, y.y, y.z, y.w};
    float vg[4] = {g.x, g.y, g.z, g.w};
#pragma unroll
    for (int j = 0; j < 4; j++) {
      float sg = vg[j] / (1.f + __expf(-vg[j]));
      float vv = vy[j] * sg;
      v[q * 4 + j] = vv;
      ss += vv * vv;
    }
  }
#pragma unroll
  for (int o = 1; o < 64; o <<= 1) ss += __shfl_xor(ss, o);
  __shared__ float red[4];
  if ((tid & 63) == 0) red[tid >> 6] = ss;
  __syncthreads();
  float tot = red[0] + red[1] + red[2] + red[3];
  float scale = rsqrtf(tot * (1.f / INTER) + EPS);
#pragma unroll
  for (int q = 0; q < 4; q++) {
    int col = q * 1024 + tid * 4;
    float4 w = *(const float4*)(nw + col);
    ushort4 o;
    o.x = f2b(v[q * 4 + 0] * scale * w.x);
    o.y = f2b(v[q * 4 + 1] * scale * w.y);
    o.z = f2b(v[q * 4 + 2] * scale * w.z);
    o.w = f2b(v[q * 4 + 3] * scale * w.w);
    *(ushort4*)(y16 + (size_t)row * INTER + col) = o;
  }
}

// ---------------------------------------------------------------------------
extern "C" void kernel_launch(void* const* d_in, const int* in_sizes, int n_in,
                              void* d_out, int out_size, void* d_ws, size_t ws_size,
                              hipStream_t stream) {
  const float* hs   = (const float*)d_in[0];
  const float* w1   = (const float*)d_in[1];
  const float* cw   = (const float*)d_in[2];
  const float* cb   = (const float*)d_in[3];
  const float* dtb  = (const float*)d_in[4];
  const float* alog = (const float*)d_in[5];
  const float* Dp   = (const float*)d_in[6];
  const float* nw   = (const float*)d_in[7];
  const float* w2   = (const float*)d_in[8];
  float* out = (float*)d_out;

  // ws layout
  char* base = (char*)d_ws;
  size_t off = 0;
  float* proj = (float*)(base + off); off += (size_t)BS * PROJ * 4;            // 139.46 MB
  float* side = (float*)(base + off); off += (size_t)BB * NCH * 3 * CONV_DIM * 4;
  off = (off + 255) & ~(size_t)255;
  char* rC = base + off;                                                       // 51.9 MB region
  // phase 1 tenants:
  ushort* hs16 = (ushort*)rC;                                 // 16.78 MB
  ushort* w1p  = (ushort*)(rC + 16777216);                    // 35.13 MB
  // phase 2 tenants (after GEMM1; hs16/w1p dead):
  ushort* states = (ushort*)rC;                               // 33.55 MB
  float*  cumbuf = (float*)(rC + 33554432);                   // 1.05 MB
  float*  dtvbuf = (float*)(rC + 33554432 + 1048576);         // 1.05 MB
  // phase 3 tenants (after K3; states/cum dead):
  ushort* w216 = (ushort*)rC;                                 // 16.78 MB
  ushort* y16  = (ushort*)(rC + 16777216);                    // 33.55 MB

  // 0) fp32 -> bf16 conversions for GEMM1
  {
    long n4 = (long)BS * HID / 4;
    to_bf16<<<(n4 + 255) / 256, 256, 0, stream>>>(hs, hs16, n4);
  }
  {
    long n4 = (long)PROJ_PAD * HID / 4;
    to_bf16_pad<<<(n4 + 255) / 256, 256, 0, stream>>>(w1, w1p, n4);
  }

  // 1) in_proj GEMM: proj = hs @ w1^T
  gemm_bt16<true><<<dim3(PROJ_PAD / 128, BS / 128), 256, 0, stream>>>(
      hs16, HID, w1p, HID, proj, PROJ, HID, PROJ);

  // 2) causal depthwise conv + SiLU (in place)
  conv_capture<<<(BB * CONV_DIM * NCH * 3 + 255) / 256, 256, 0, stream>>>(proj, side);
  conv_silu<<<(BB * CONV_DIM * NCH + 255) / 256, 256, 0, stream>>>(proj, side, cw, cb);

  // 3) SSD chunked scan
  ssd_chunk_state<<<BB * NH * NCHK, 256, 0, stream>>>(proj, dtb, alog, states, cumbuf, dtvbuf);
  ssd_state_scan<<<BB * NH, 256, 0, stream>>>(states, cumbuf);
  ssd_chunk_out<<<BB * NH * NCHK, 256, 0, stream>>>(proj, states, cumbuf, dtvbuf, Dp);

  // 4) w2 conversion (after SSD so it can reuse region C)
  {
    long n4 = (long)HID * INTER / 4;
    to_bf16<<<(n4 + 255) / 256, 256, 0, stream>>>(w2, w216, n4);
  }

  // 5) gated RMSNorm -> bf16 y16
  rmsnorm_kernel<<<BS, 256, 0, stream>>>(proj, nw, y16);

  // 6) out_proj GEMM: out = y16 @ w2^T
  gemm_bt16<false><<<dim3(HID / 128, BS / 128), 256, 0, stream>>>(
      y16, INTER, w216, INTER, out, HID, INTER, HID);
}

// Round 4
// 531.217 us; speedup vs baseline: 8.6727x; 1.1408x over previous
//
#include <hip/hip_runtime.h>
#include <hip/hip_bf16.h>
#include <cstddef>
#include <cstdint>

// Problem constants
#define HID   2048
#define INTER 4096
#define NH    64
#define HD    64
#define NST   128
#define CONV_DIM 4352           // INTER + 2*NST
#define PROJ  8512              // INTER + CONV_DIM + NH
#define PROJ_PAD 8576           // 67 * 128
#define SS    2048
#define BB    2
#define BS    (BB*SS)           // 4096 rows
#define EPS   1e-5f

// proj column layout: [0,4096)=gate [4096,8192)=hs [8192,8320)=B [8320,8448)=C [8448,8512)=dt
#define COL_HS 4096
#define COL_B  8192
#define COL_C  8320
#define COL_DT 8448

#define NCH   16                // conv chunks along S
#define CHUNK 128               // SS / NCH

// SSD chunking
#define CL    128               // chunk length
#define NCHK  16                // SS / CL

typedef short s16x8 __attribute__((ext_vector_type(8)));
typedef float f32x4 __attribute__((ext_vector_type(4)));

__device__ inline ushort f2b(float x) {
  __hip_bfloat16 h = __float2bfloat16(x);
  return *(ushort*)&h;
}
__device__ inline float b2f(ushort u) {
  unsigned int v = ((unsigned int)u) << 16;
  return __uint_as_float(v);
}
// LDS tile: 256B rows (128 bf16), XOR-swizzled in 8-elem slots (T2)
__device__ inline int swz(int row, int e) { return row * 128 + (e ^ ((row & 7) << 3)); }

// ---------------------------------------------------------------------------
// fp32 -> bf16 conversion kernels
// ---------------------------------------------------------------------------
__global__ __launch_bounds__(256) void to_bf16(const float* __restrict__ src,
                                               ushort* __restrict__ dst, long n4) {
  long i = (long)blockIdx.x * 256 + threadIdx.x;
  if (i >= n4) return;
  float4 v = *(const float4*)(src + i * 4);
  ushort4 o;
  o.x = f2b(v.x); o.y = f2b(v.y); o.z = f2b(v.z); o.w = f2b(v.w);
  *(ushort4*)(dst + i * 4) = o;
}

__global__ __launch_bounds__(256) void to_bf16_pad(const float* __restrict__ src,
                                                   ushort* __restrict__ dst, long n4) {
  long i = (long)blockIdx.x * 256 + threadIdx.x;
  if (i >= n4) return;
  long e0 = i * 4;
  long row = e0 >> 11;  // / 2048
  ushort4 o;
  if (row < PROJ) {
    float4 v = *(const float4*)(src + e0);
    o.x = f2b(v.x); o.y = f2b(v.y); o.z = f2b(v.z); o.w = f2b(v.w);
  } else {
    o.x = o.y = o.z = o.w = 0;
  }
  *(ushort4*)(dst + e0) = o;
}

// ---------------------------------------------------------------------------
// bf16 MFMA GEMM (m97 structure) with L2-locality grid remap:
// fid -> column-group-of-8 traversal; requires gridDim.y == 32.
// ---------------------------------------------------------------------------
__device__ inline void gload16(const void* g, void* l) {
  __builtin_amdgcn_global_load_lds((const __attribute__((address_space(1))) void*)g,
                                   (__attribute__((address_space(3))) void*)l, 16, 0, 0);
}

template <bool GUARD_N>
__global__ __launch_bounds__(256) void gemm_bt16(
    const ushort* __restrict__ A, int lda,
    const ushort* __restrict__ Bw, int ldb,
    float* __restrict__ C, int ldc, int Kd, int Nmax) {
  __shared__ short smem[8192];
  const int tid = threadIdx.x;
  const int lane = tid & 63;
  const int wid = tid >> 6;
  const int wm = wid >> 1, wn = wid & 1;
  const int r = lane & 15;
  const int kx = lane >> 4;

  // grid remap: process columns in groups of 8 (all 32 rows per group)
  const int fid = blockIdx.y * gridDim.x + blockIdx.x;
  const int bcol = ((fid >> 8) << 3) | ((fid & 255) >> 5);
  const int brow = fid & 31;

  const ushort* Ab = A + (size_t)(brow * 128) * lda;
  const ushort* Bb = Bw + (size_t)(bcol * 128) * ldb;

  f32x4 acc[4][4];
#pragma unroll
  for (int i = 0; i < 4; i++)
#pragma unroll
    for (int j = 0; j < 4; j++) acc[i][j] = (f32x4)0.f;

  const int u0 = tid, u1 = 256 + tid;
  const int row0 = u0 >> 2, kc0 = (u0 & 3) * 8;
  const int row1 = u1 >> 2, kc1 = (u1 & 3) * 8;

  const s16x8* As8 = (const s16x8*)smem;
  const s16x8* Bs8 = (const s16x8*)(smem + 4096);

  for (int k0 = 0; k0 < Kd; k0 += 32) {
    __syncthreads();
    gload16(Ab + (size_t)row0 * lda + k0 + kc0, smem + u0 * 8);
    gload16(Ab + (size_t)row1 * lda + k0 + kc1, smem + u1 * 8);
    gload16(Bb + (size_t)row0 * ldb + k0 + kc0, smem + 4096 + u0 * 8);
    gload16(Bb + (size_t)row1 * ldb + k0 + kc1, smem + 4096 + u1 * 8);
    __syncthreads();
    s16x8 af[4], bw[4];
#pragma unroll
    for (int i = 0; i < 4; i++) af[i] = As8[(wm * 64 + i * 16 + r) * 4 + kx];
#pragma unroll
    for (int j = 0; j < 4; j++) bw[j] = Bs8[(wn * 64 + j * 16 + r) * 4 + kx];
#pragma unroll
    for (int i = 0; i < 4; i++)
#pragma unroll
      for (int j = 0; j < 4; j++)
        acc[i][j] = __builtin_amdgcn_mfma_f32_16x16x32_bf16(af[i], bw[j], acc[i][j], 0, 0, 0);
  }

  const int m0 = brow * 128 + wm * 64 + (lane >> 4) * 4;
  const int n0 = bcol * 128 + wn * 64 + (lane & 15);
#pragma unroll
  for (int i = 0; i < 4; i++) {
#pragma unroll
    for (int j = 0; j < 4; j++) {
      int n = n0 + j * 16;
      if (GUARD_N && n >= Nmax) continue;
#pragma unroll
      for (int q = 0; q < 4; q++) {
        C[(size_t)(m0 + i * 16 + q) * ldc + n] = acc[i][j][q];
      }
    }
  }
}

// ---------------------------------------------------------------------------
// Conv boundary capture
// ---------------------------------------------------------------------------
__global__ void conv_capture(const float* __restrict__ proj, float* __restrict__ side) {
  int idx = blockIdx.x * 256 + threadIdx.x;
  const int total = BB * CONV_DIM * NCH * 3;
  if (idx >= total) return;
  int c = idx % CONV_DIM;
  int t = idx / CONV_DIM;
  int j = t % 3; t /= 3;
  int chunk = t % NCH;
  int b = t / NCH;
  int s = chunk * CHUNK - 1 - j;
  float v = (s >= 0) ? proj[((size_t)b * SS + s) * PROJ + COL_HS + c] : 0.f;
  side[((size_t)(b * NCH + chunk) * 3 + j) * CONV_DIM + c] = v;
}

// ---------------------------------------------------------------------------
// Causal depthwise conv1d (K=4) + bias + SiLU, in place
// ---------------------------------------------------------------------------
__global__ void conv_silu(float* __restrict__ proj, const float* __restrict__ side,
                          const float* __restrict__ cw, const float* __restrict__ cb) {
  int idx = blockIdx.x * 256 + threadIdx.x;
  const int total = BB * CONV_DIM * NCH;
  if (idx >= total) return;
  int c = idx % CONV_DIM;
  int t = idx / CONV_DIM;
  int chunk = t % NCH;
  int b = t / NCH;
  float w0 = cw[c * 4 + 0], w1 = cw[c * 4 + 1], w2 = cw[c * 4 + 2], w3 = cw[c * 4 + 3];
  float bias = cb[c];
  const float* sd = side + ((size_t)(b * NCH + chunk) * 3) * CONV_DIM;
  float xm1 = sd[c];
  float xm2 = sd[CONV_DIM + c];
  float xm3 = sd[2 * CONV_DIM + c];
  size_t p = ((size_t)b * SS + (size_t)chunk * CHUNK) * PROJ + COL_HS + c;
  for (int s = 0; s < CHUNK; s++) {
    float xin = proj[p];
    float o = w3 * xin + w2 * xm1 + w1 * xm2 + w0 * xm3 + bias;
    o = o / (1.f + __expf(-o));      // SiLU
    proj[p] = o;
    xm3 = xm2; xm2 = xm1; xm1 = xin;
    p += PROJ;
  }
}

// ---------------------------------------------------------------------------
// SSD K1: per (b,h,chunk): softplus(dt), cumsum, chunk state (MFMA).
// states written TRANSPOSED: [d=64][n=128]  (so K3 can read Sp^T fragments
// as contiguous 16B from global).
// ---------------------------------------------------------------------------
__global__ __launch_bounds__(256) void ssd_chunk_state(
    const float* __restrict__ proj, const float* __restrict__ dt_bias,
    const float* __restrict__ A_log, ushort* __restrict__ states,
    float* __restrict__ cumbuf, float* __restrict__ dtvbuf) {
  const int bid = blockIdx.x;
  const int c = bid & 15;
  const int h = (bid >> 4) & 63;
  const int b = bid >> 10;
  const int tid = threadIdx.x;
  const int lane = tid & 63;
  const int wv = tid >> 6;
  __shared__ float sdtv[CL], scum[CL], sw[CL];
  __shared__ ushort sBt[128 * 128];   // [n][t]
  __shared__ ushort sXw[64 * 128];    // [d][t] scaled
  const size_t row0 = (size_t)b * SS + (size_t)c * CL;
  const size_t bh = (size_t)(b * NH + h);

  const float Ah = -__expf(A_log[h]);
  if (tid < CL) {
    float z = proj[(row0 + tid) * PROJ + COL_DT + h] + dt_bias[h];
    float dtv = (z > 20.f) ? z : log1pf(__expf(z));
    sdtv[tid] = dtv;
    sw[tid] = dtv * Ah;
  }
  __syncthreads();
  // inclusive Hillis-Steele scan over sw
  for (int off = 1; off < CL; off <<= 1) {
    float v = 0.f;
    if (tid < CL) { v = sw[tid]; if (tid >= off) v += sw[tid - off]; }
    __syncthreads();
    if (tid < CL) sw[tid] = v;
    __syncthreads();
  }
  if (tid < CL) {
    scum[tid] = sw[tid];
    cumbuf[bh * SS + c * CL + tid] = sw[tid];
    dtvbuf[bh * SS + c * CL + tid] = sdtv[tid];
  }
  __syncthreads();
  const float cumL = scum[CL - 1];
  if (tid < CL) sw[tid] = __expf(cumL - scum[tid]) * sdtv[tid];
  __syncthreads();

  // stage B^T [n][t] (unscaled)
  {
    const int t = tid >> 1, n0 = (tid & 1) * 64;
    const float* src = proj + (row0 + t) * PROJ + COL_B + n0;
#pragma unroll
    for (int j = 0; j < 64; j += 4) {
      float4 v = *(const float4*)(src + j);
      sBt[swz(n0 + j + 0, t)] = f2b(v.x);
      sBt[swz(n0 + j + 1, t)] = f2b(v.y);
      sBt[swz(n0 + j + 2, t)] = f2b(v.z);
      sBt[swz(n0 + j + 3, t)] = f2b(v.w);
    }
  }
  // stage Xw^T [d][t] scaled by sw[t]
  {
    const int d = tid & 63;
    const int t0 = (tid >> 6) * 32;
    for (int t = t0; t < t0 + 32; t++) {
      float x = proj[(row0 + t) * PROJ + COL_HS + h * 64 + d];
      sXw[swz(d, t)] = f2b(x * sw[t]);
    }
  }
  __syncthreads();

  // MFMA: wave wv owns n rows [wv*32, +32)
  const int r = lane & 15, kx = lane >> 4;
  f32x4 acc[2][4];
#pragma unroll
  for (int i = 0; i < 2; i++)
#pragma unroll
    for (int j = 0; j < 4; j++) acc[i][j] = (f32x4)0.f;
#pragma unroll
  for (int kk = 0; kk < 4; kk++) {
    s16x8 a[2], bo[4];
#pragma unroll
    for (int i = 0; i < 2; i++)
      a[i] = *(const s16x8*)&sBt[swz(wv * 32 + i * 16 + r, kk * 32 + kx * 8)];
#pragma unroll
    for (int j = 0; j < 4; j++)
      bo[j] = *(const s16x8*)&sXw[swz(j * 16 + r, kk * 32 + kx * 8)];
#pragma unroll
    for (int i = 0; i < 2; i++)
#pragma unroll
      for (int j = 0; j < 4; j++)
        acc[i][j] = __builtin_amdgcn_mfma_f32_16x16x32_bf16(a[i], bo[j], acc[i][j], 0, 0, 0);
  }
  // write transposed [d][n], 8B vector stores
  ushort* dst = states + (size_t)bid * (128 * 64);
#pragma unroll
  for (int i = 0; i < 2; i++) {
#pragma unroll
    for (int j = 0; j < 4; j++) {
      int n = wv * 32 + i * 16 + (lane >> 4) * 4;
      int d = (lane & 15) + j * 16;
      ushort4 o;
      o.x = f2b(acc[i][j][0]);
      o.y = f2b(acc[i][j][1]);
      o.z = f2b(acc[i][j][2]);
      o.w = f2b(acc[i][j][3]);
      *(ushort4*)(dst + (size_t)d * 128 + n) = o;
    }
  }
}

// ---------------------------------------------------------------------------
// SSD K2: inter-chunk recurrence. Block = (b,h). In place: S_chunk -> S_prev.
// (layout-agnostic elementwise over the 8192-elem state)
// ---------------------------------------------------------------------------
__global__ __launch_bounds__(256) void ssd_state_scan(
    ushort* __restrict__ states, const float* __restrict__ cumbuf) {
  const int bh = blockIdx.x;
  const int tid = threadIdx.x;
  float run[32];
#pragma unroll
  for (int i = 0; i < 32; i++) run[i] = 0.f;
  for (int c = 0; c < NCHK; c++) {
    float dec = __expf(cumbuf[(size_t)bh * SS + c * CL + (CL - 1)]);
    ushort* p = states + ((size_t)bh * NCHK + c) * 8192 + tid * 32;
    s16x8 in[4];
#pragma unroll
    for (int v = 0; v < 4; v++) in[v] = *(const s16x8*)(p + v * 8);
    s16x8 out[4];
#pragma unroll
    for (int v = 0; v < 4; v++) {
#pragma unroll
      for (int e = 0; e < 8; e++) {
        int i = v * 8 + e;
        out[v][e] = (short)f2b(run[i]);
        run[i] = dec * run[i] + b2f((ushort)in[v][e]);
      }
    }
#pragma unroll
    for (int v = 0; v < 4; v++) *(s16x8*)(p + v * 8) = out[v];
  }
}

// ---------------------------------------------------------------------------
// SSD K3: per (b,h,chunk) fused output. LDS = 80KB exactly -> 2 blocks/CU.
//  G = C@B^T; P = mask*exp(cum[t]-cum[tau])*dtv[tau]*G (bf16, over sB);
//  y = P@X + (exp(cum[t])*C)@S_prev^T + D*X  -> written in place to proj
// S_prev^T fragments read directly from global (states [d][n]).
// cum/dtv read directly from global into registers (no LDS copy).
// ---------------------------------------------------------------------------
__global__ __launch_bounds__(256, 2) void ssd_chunk_out(
    float* __restrict__ proj, const ushort* __restrict__ states,
    const float* __restrict__ cumbuf, const float* __restrict__ dtvbuf,
    const float* __restrict__ Dp) {
  const int bid = blockIdx.x;
  const int c = bid & 15;
  const int h = (bid >> 4) & 63;
  const int b = bid >> 10;
  const int tid = threadIdx.x;
  const int lane = tid & 63;
  const int wv = tid >> 6;
  __shared__ ushort sC[128 * 128];   // [t][n], later scaled -> Cs
  __shared__ ushort sB[128 * 128];   // [tau][n], later overwritten by P [t][tau]
  __shared__ ushort sX[64 * 128];    // [d][t]
  const size_t row0 = (size_t)b * SS + (size_t)c * CL;
  const size_t bh = (size_t)(b * NH + h);
  const float* cumb = cumbuf + bh * SS + c * CL;
  const float* dtvb = dtvbuf + bh * SS + c * CL;
  const int r = lane & 15, kx = lane >> 4;

  // per-thread cum/dtv register loads (L2-hot, issued early)
  float ct[2][4];        // own t rows
#pragma unroll
  for (int i = 0; i < 2; i++)
#pragma unroll
    for (int q = 0; q < 4; q++)
      ct[i][q] = cumb[wv * 32 + i * 16 + ((lane >> 4) << 2) + q];
  float cumt[8], dvt[8]; // tau side
#pragma unroll
  for (int j = 0; j < 8; j++) {
    int tau = j * 16 + (lane & 15);
    cumt[j] = cumb[tau];
    dvt[j] = dtvb[tau];
  }
  const float eC = __expf(cumb[wv * 32 + (lane >> 1)]);  // Cs row scale

  // stage C and B natural [t][n]
  {
    const int t = tid >> 1, n0 = (tid & 1) * 64;
    const float* srcC = proj + (row0 + t) * PROJ + COL_C + n0;
    const float* srcB = proj + (row0 + t) * PROJ + COL_B + n0;
#pragma unroll
    for (int j = 0; j < 64; j += 8) {
      float4 c0 = *(const float4*)(srcC + j);
      float4 c1 = *(const float4*)(srcC + j + 4);
      s16x8 u;
      u[0] = (short)f2b(c0.x); u[1] = (short)f2b(c0.y);
      u[2] = (short)f2b(c0.z); u[3] = (short)f2b(c0.w);
      u[4] = (short)f2b(c1.x); u[5] = (short)f2b(c1.y);
      u[6] = (short)f2b(c1.z); u[7] = (short)f2b(c1.w);
      *(s16x8*)&sC[swz(t, n0 + j)] = u;
      float4 b0 = *(const float4*)(srcB + j);
      float4 b1 = *(const float4*)(srcB + j + 4);
      s16x8 w;
      w[0] = (short)f2b(b0.x); w[1] = (short)f2b(b0.y);
      w[2] = (short)f2b(b0.z); w[3] = (short)f2b(b0.w);
      w[4] = (short)f2b(b1.x); w[5] = (short)f2b(b1.y);
      w[6] = (short)f2b(b1.z); w[7] = (short)f2b(b1.w);
      *(s16x8*)&sB[swz(t, n0 + j)] = w;
    }
  }
  // stage X^T [d][t]
  {
    const int d = tid & 63;
    const int t0 = (tid >> 6) * 32;
    for (int t = t0; t < t0 + 32; t++)
      sX[swz(d, t)] = f2b(proj[(row0 + t) * PROJ + COL_HS + h * 64 + d]);
  }
  __syncthreads();

  // Phase G: G = C @ B^T; wave wv owns t rows [wv*32, +32)
  f32x4 g[2][8];
#pragma unroll
  for (int i = 0; i < 2; i++)
#pragma unroll
    for (int j = 0; j < 8; j++) g[i][j] = (f32x4)0.f;
#pragma unroll
  for (int kk = 0; kk < 4; kk++) {
    s16x8 a[2], bo[8];
#pragma unroll
    for (int i = 0; i < 2; i++)
      a[i] = *(const s16x8*)&sC[swz(wv * 32 + i * 16 + r, kk * 32 + kx * 8)];
#pragma unroll
    for (int j = 0; j < 8; j++)
      bo[j] = *(const s16x8*)&sB[swz(j * 16 + r, kk * 32 + kx * 8)];
#pragma unroll
    for (int i = 0; i < 2; i++)
#pragma unroll
      for (int j = 0; j < 8; j++)
        g[i][j] = __builtin_amdgcn_mfma_f32_16x16x32_bf16(a[i], bo[j], g[i][j], 0, 0, 0);
  }

  // prefetch S_prev^T fragments from global (states [d][n]; contiguous 16B)
  s16x8 spf[4][4];  // [kk][j]
  {
    const ushort* sp = states + (size_t)bid * 8192;
#pragma unroll
    for (int kk = 0; kk < 4; kk++)
#pragma unroll
      for (int j = 0; j < 4; j++)
        spf[kk][j] = *(const s16x8*)(sp + (size_t)(j * 16 + r) * 128 + kk * 32 + kx * 8);
  }
  __syncthreads();   // all waves done reading sB / sC

  // Phase P: write P[t][tau] over sB; scale own sC rows -> Cs
#pragma unroll
  for (int j = 0; j < 8; j++) {
    float cu = cumt[j], dv = dvt[j];
    int tau = j * 16 + (lane & 15);
#pragma unroll
    for (int i = 0; i < 2; i++) {
#pragma unroll
      for (int q = 0; q < 4; q++) {
        int t = wv * 32 + i * 16 + ((lane >> 4) << 2) + q;
        float val = (tau <= t) ? g[i][j][q] * __expf(ct[i][q] - cu) * dv : 0.f;
        sB[swz(t, tau)] = f2b(val);
      }
    }
  }
  {
    int t = wv * 32 + (lane >> 1);
    int n0 = (lane & 1) * 64;
#pragma unroll
    for (int j = 0; j < 64; j += 8) {
      s16x8 u = *(const s16x8*)&sC[swz(t, n0 + j)];
#pragma unroll
      for (int k = 0; k < 8; k++) u[k] = (short)f2b(b2f((ushort)u[k]) * eC);
      *(s16x8*)&sC[swz(t, n0 + j)] = u;
    }
  }
  __syncthreads();

  // Phase Y: y = P@X^T + Cs@Sp^T
  f32x4 y[2][4];
#pragma unroll
  for (int i = 0; i < 2; i++)
#pragma unroll
    for (int j = 0; j < 4; j++) y[i][j] = (f32x4)0.f;
#pragma unroll
  for (int kk = 0; kk < 4; kk++) {
    s16x8 a[2], bo[4];
#pragma unroll
    for (int i = 0; i < 2; i++)
      a[i] = *(const s16x8*)&sB[swz(wv * 32 + i * 16 + r, kk * 32 + kx * 8)];
#pragma unroll
    for (int j = 0; j < 4; j++)
      bo[j] = *(const s16x8*)&sX[swz(j * 16 + r, kk * 32 + kx * 8)];
#pragma unroll
    for (int i = 0; i < 2; i++)
#pragma unroll
      for (int j = 0; j < 4; j++)
        y[i][j] = __builtin_amdgcn_mfma_f32_16x16x32_bf16(a[i], bo[j], y[i][j], 0, 0, 0);
  }
#pragma unroll
  for (int kk = 0; kk < 4; kk++) {
    s16x8 a[2];
#pragma unroll
    for (int i = 0; i < 2; i++)
      a[i] = *(const s16x8*)&sC[swz(wv * 32 + i * 16 + r, kk * 32 + kx * 8)];
#pragma unroll
    for (int i = 0; i < 2; i++)
#pragma unroll
      for (int j = 0; j < 4; j++)
        y[i][j] = __builtin_amdgcn_mfma_f32_16x16x32_bf16(a[i], spf[kk][j], y[i][j], 0, 0, 0);
  }

  // Epilogue: add D*x, write y in place
  const float Dh = Dp[h];
#pragma unroll
  for (int i = 0; i < 2; i++) {
#pragma unroll
    for (int j = 0; j < 4; j++) {
      int t0 = wv * 32 + i * 16 + (lane >> 4) * 4;
      int d = (lane & 15) + j * 16;
#pragma unroll
      for (int q = 0; q < 4; q++) {
        float x = b2f(sX[swz(d, t0 + q)]);
        proj[(row0 + t0 + q) * PROJ + COL_HS + h * 64 + d] = y[i][j][q] + Dh * x;
      }
    }
  }
}

// ---------------------------------------------------------------------------
// Gated RMSNorm -> bf16 y16
// ---------------------------------------------------------------------------
__global__ __launch_bounds__(256) void rmsnorm_kernel(
    const float* __restrict__ proj, const float* __restrict__ nw,
    ushort* __restrict__ y16) {
  const int row = blockIdx.x;
  const int tid = threadIdx.x;
  const float* yp = proj + (size_t)row * PROJ + COL_HS;
  const float* gp = proj + (size_t)row * PROJ;
  float v[16];
  float ss = 0.f;
#pragma unroll
  for (int q = 0; q < 4; q++) {
    int col = q * 1024 + tid * 4;
    float4 y = *(const float4*)(yp + col);
    float4 g = *(const float4*)(gp + col);
    float vy[4] = {y.x, y.y, y.z, y.w};
    float vg[4] = {g.x, g.y, g.z, g.w};
#pragma unroll
    for (int j = 0; j < 4; j++) {
      float sg = vg[j] / (1.f + __expf(-vg[j]));
      float vv = vy[j] * sg;
      v[q * 4 + j] = vv;
      ss += vv * vv;
    }
  }
#pragma unroll
  for (int o = 1; o < 64; o <<= 1) ss += __shfl_xor(ss, o);
  __shared__ float red[4];
  if ((tid & 63) == 0) red[tid >> 6] = ss;
  __syncthreads();
  float tot = red[0] + red[1] + red[2] + red[3];
  float scale = rsqrtf(tot * (1.f / INTER) + EPS);
#pragma unroll
  for (int q = 0; q < 4; q++) {
    int col = q * 1024 + tid * 4;
    float4 w = *(const float4*)(nw + col);
    ushort4 o;
    o.x = f2b(v[q * 4 + 0] * scale * w.x);
    o.y = f2b(v[q * 4 + 1] * scale * w.y);
    o.z = f2b(v[q * 4 + 2] * scale * w.z);
    o.w = f2b(v[q * 4 + 3] * scale * w.w);
    *(ushort4*)(y16 + (size_t)row * INTER + col) = o;
  }
}

// ---------------------------------------------------------------------------
extern "C" void kernel_launch(void* const* d_in, const int* in_sizes, int n_in,
                              void* d_out, int out_size, void* d_ws, size_t ws_size,
                              hipStream_t stream) {
  const float* hs   = (const float*)d_in[0];
  const float* w1   = (const float*)d_in[1];
  const float* cw   = (const float*)d_in[2];
  const float* cb   = (const float*)d_in[3];
  const float* dtb  = (const float*)d_in[4];
  const float* alog = (const float*)d_in[5];
  const float* Dp   = (const float*)d_in[6];
  const float* nw   = (const float*)d_in[7];
  const float* w2   = (const float*)d_in[8];
  float* out = (float*)d_out;

  // ws layout
  char* base = (char*)d_ws;
  size_t off = 0;
  float* proj = (float*)(base + off); off += (size_t)BS * PROJ * 4;            // 139.46 MB
  float* side = (float*)(base + off); off += (size_t)BB * NCH * 3 * CONV_DIM * 4;
  off = (off + 255) & ~(size_t)255;
  char* rC = base + off;                                                       // 51.9 MB region
  // phase 1 tenants:
  ushort* hs16 = (ushort*)rC;                                 // 16.78 MB
  ushort* w1p  = (ushort*)(rC + 16777216);                    // 35.13 MB
  // phase 2 tenants (after GEMM1; hs16/w1p dead):
  ushort* states = (ushort*)rC;                               // 33.55 MB
  float*  cumbuf = (float*)(rC + 33554432);                   // 1.05 MB
  float*  dtvbuf = (float*)(rC + 33554432 + 1048576);         // 1.05 MB
  // phase 3 tenants (after K3; states/cum dead):
  ushort* w216 = (ushort*)rC;                                 // 16.78 MB
  ushort* y16  = (ushort*)(rC + 16777216);                    // 33.55 MB

  // 0) fp32 -> bf16 conversions for GEMM1
  {
    long n4 = (long)BS * HID / 4;
    to_bf16<<<(n4 + 255) / 256, 256, 0, stream>>>(hs, hs16, n4);
  }
  {
    long n4 = (long)PROJ_PAD * HID / 4;
    to_bf16_pad<<<(n4 + 255) / 256, 256, 0, stream>>>(w1, w1p, n4);
  }

  // 1) in_proj GEMM: proj = hs @ w1^T
  gemm_bt16<true><<<dim3(PROJ_PAD / 128, BS / 128), 256, 0, stream>>>(
      hs16, HID, w1p, HID, proj, PROJ, HID, PROJ);

  // 2) causal depthwise conv + SiLU (in place)
  conv_capture<<<(BB * CONV_DIM * NCH * 3 + 255) / 256, 256, 0, stream>>>(proj, side);
  conv_silu<<<(BB * CONV_DIM * NCH + 255) / 256, 256, 0, stream>>>(proj, side, cw, cb);

  // 3) SSD chunked scan
  ssd_chunk_state<<<BB * NH * NCHK, 256, 0, stream>>>(proj, dtb, alog, states, cumbuf, dtvbuf);
  ssd_state_scan<<<BB * NH, 256, 0, stream>>>(states, cumbuf);
  ssd_chunk_out<<<BB * NH * NCHK, 256, 0, stream>>>(proj, states, cumbuf, dtvbuf, Dp);

  // 4) w2 conversion (after SSD so it can reuse region C)
  {
    long n4 = (long)HID * INTER / 4;
    to_bf16<<<(n4 + 255) / 256, 256, 0, stream>>>(w2, w216, n4);
  }

  // 5) gated RMSNorm -> bf16 y16
  rmsnorm_kernel<<<BS, 256, 0, stream>>>(proj, nw, y16);

  // 6) out_proj GEMM: out = y16 @ w2^T
  gemm_bt16<false><<<dim3(HID / 128, BS / 128), 256, 0, stream>>>(
      y16, INTER, w216, INTER, out, HID, INTER, HID);
}

// Round 5
// 497.337 us; speedup vs baseline: 9.2635x; 1.0681x over previous
//
#include <hip/hip_runtime.h>
#include <hip/hip_bf16.h>
#include <cstddef>
#include <cstdint>

// Problem constants
#define HID   2048
#define INTER 4096
#define NH    64
#define HD    64
#define NST   128
#define CONV_DIM 4352           // INTER + 2*NST
#define PROJ  8512              // INTER + CONV_DIM + NH
#define PROJ_PAD 8704           // 34 * 256 (pad for 256-col tiles)
#define SS    2048
#define BB    2
#define BS    (BB*SS)           // 4096 rows
#define EPS   1e-5f

// proj column layout: [0,4096)=gate [4096,8192)=hs [8192,8320)=B [8320,8448)=C [8448,8512)=dt
#define COL_HS 4096
#define COL_B  8192
#define COL_C  8320
#define COL_DT 8448

#define NCH   16                // conv chunks along S
#define CHUNK 128               // SS / NCH

// SSD chunking
#define CL    128               // chunk length
#define NCHK  16                // SS / CL

typedef short s16x8 __attribute__((ext_vector_type(8)));
typedef float f32x4 __attribute__((ext_vector_type(4)));

__device__ inline ushort f2b(float x) {
  __hip_bfloat16 h = __float2bfloat16(x);
  return *(ushort*)&h;
}
__device__ inline float b2f(ushort u) {
  unsigned int v = ((unsigned int)u) << 16;
  return __uint_as_float(v);
}
// LDS tile: 256B rows (128 bf16), XOR-swizzled in 8-elem slots (T2)
__device__ inline int swz(int row, int e) { return row * 128 + (e ^ ((row & 7) << 3)); }

__device__ inline void gload16(const void* g, void* l) {
  __builtin_amdgcn_global_load_lds((const __attribute__((address_space(1))) void*)g,
                                   (__attribute__((address_space(3))) void*)l, 16, 0, 0);
}

// ---------------------------------------------------------------------------
// fp32 -> bf16 conversion kernels
// ---------------------------------------------------------------------------
__global__ __launch_bounds__(256) void to_bf16(const float* __restrict__ src,
                                               ushort* __restrict__ dst, long n4) {
  long i = (long)blockIdx.x * 256 + threadIdx.x;
  if (i >= n4) return;
  float4 v = *(const float4*)(src + i * 4);
  ushort4 o;
  o.x = f2b(v.x); o.y = f2b(v.y); o.z = f2b(v.z); o.w = f2b(v.w);
  *(ushort4*)(dst + i * 4) = o;
}

__global__ __launch_bounds__(256) void to_bf16_pad(const float* __restrict__ src,
                                                   ushort* __restrict__ dst, long n4) {
  long i = (long)blockIdx.x * 256 + threadIdx.x;
  if (i >= n4) return;
  long e0 = i * 4;
  long row = e0 >> 11;  // / 2048
  ushort4 o;
  if (row < PROJ) {
    float4 v = *(const float4*)(src + e0);
    o.x = f2b(v.x); o.y = f2b(v.y); o.z = f2b(v.z); o.w = f2b(v.w);
  } else {
    o.x = o.y = o.z = o.w = 0;
  }
  *(ushort4*)(dst + e0) = o;
}

// ---------------------------------------------------------------------------
// GEMM1: 256x256 8-phase pipelined bf16 MFMA GEMM (T2+T3+T4+T5).
// A [4096][2048] bf16, Bw [8704][2048] bf16, C fp32 [4096][8512] (guard n<8512).
// 512 threads = 8 waves (2M x 4N), per-wave 128x64 out, BK=64, LDS 128KB dbuf.
// LDS swizzle: byte ^= (row&7)<<4 ; gload_lds dest linear, source pre-swizzled.
// Counted vmcnt(4) once per K-tile; B(t+1) staged ph1/ph2, A(t+2) staged ph4.
// ---------------------------------------------------------------------------
__global__ __launch_bounds__(512, 2) void gemm256_8ph(
    const ushort* __restrict__ A, const ushort* __restrict__ Bw,
    float* __restrict__ C) {
  __shared__ ushort smem[65536];   // [A: buf0 16K, buf1 16K][B: buf0, buf1] (ushorts)
  const int tid = threadIdx.x;
  const int lane = tid & 63;
  const int wid = tid >> 6;
  const int wm = wid >> 2;         // 0..1
  const int wn = wid & 3;          // 0..3
  const int r = lane & 15;
  const int kx = lane >> 4;        // 0..3

  // grid remap: column-groups of 8 (16 row-tiles), bijective over 544 blocks
  const int fid = blockIdx.x;
  const int bcol = ((fid >> 7) << 3) + ((fid & 127) >> 4);   // 0..33
  const int brow = fid & 15;                                  // 0..15

  const ushort* Ag = A + (size_t)(brow * 256) * HID;
  const ushort* Bg = Bw + (size_t)(bcol * 256) * HID;

  // staging precompute: thread covers row srow(+64), 16B slot (tid&7)
  const int srow = tid >> 3;                 // 0..63
  const int scole = (((tid & 7) * 16) ^ ((srow & 7) << 4)) >> 1;  // elem offset in row

  auto stageA = [&](int buf, int kt, int half) {
    const ushort* g = Ag + (size_t)(half * 128 + srow) * HID + kt * 64 + scole;
    ushort* l = smem + buf * 16384 + half * 8192 + tid * 8;
    gload16(g, l);
    gload16(g + (size_t)64 * HID, l + 4096);
  };
  auto stageB = [&](int buf, int kt, int half) {
    const ushort* g = Bg + (size_t)(half * 128 + srow) * HID + kt * 64 + scole;
    ushort* l = smem + 32768 + buf * 16384 + half * 8192 + tid * 8;
    gload16(g, l);
    gload16(g + (size_t)64 * HID, l + 4096);
  };
  auto ldA = [&](int buf, int mf, int ks) -> s16x8 {
    int row = wm * 128 + mf * 16 + r;
    int cb = (ks * 64 + kx * 16) ^ ((row & 7) << 4);
    return *(const s16x8*)(smem + buf * 16384 + row * 64 + (cb >> 1));
  };
  auto ldB = [&](int buf, int nf, int ks) -> s16x8 {
    int row = wn * 64 + nf * 16 + r;
    int cb = (ks * 64 + kx * 16) ^ ((row & 7) << 4);
    return *(const s16x8*)(smem + 32768 + buf * 16384 + row * 64 + (cb >> 1));
  };

  f32x4 acc[8][4];
#pragma unroll
  for (int i = 0; i < 8; i++)
#pragma unroll
    for (int j = 0; j < 4; j++) acc[i][j] = (f32x4)0.f;

  constexpr int NT = HID / 64;   // 32 K-tiles

  // prologue: A(0), B(0), A(1) ; wait tile0 arrived (A(1) in flight)
  stageA(0, 0, 0); stageA(0, 0, 1);
  stageB(0, 0, 0); stageB(0, 0, 1);
  stageA(1, 1, 0); stageA(1, 1, 1);
  asm volatile("s_waitcnt vmcnt(4)" ::: "memory");
  __builtin_amdgcn_s_barrier();

  int cur = 0;
  for (int t = 0; t < NT; t++) {
    s16x8 a[4][2], b[2][2], b2[2][2];
    // ---------- phase 1: read a(mf0-3), b(nf0-1); stage B-lo(t+1); Q00
#pragma unroll
    for (int mf = 0; mf < 4; mf++)
#pragma unroll
      for (int ks = 0; ks < 2; ks++) a[mf][ks] = ldA(cur, mf, ks);
#pragma unroll
    for (int nf = 0; nf < 2; nf++)
#pragma unroll
      for (int ks = 0; ks < 2; ks++) b[nf][ks] = ldB(cur, nf, ks);
    if (t + 1 < NT) stageB(cur ^ 1, t + 1, 0);
    __builtin_amdgcn_s_barrier();
    asm volatile("s_waitcnt lgkmcnt(0)" ::: "memory");
    __builtin_amdgcn_sched_barrier(0);
    __builtin_amdgcn_s_setprio(1);
#pragma unroll
    for (int mf = 0; mf < 4; mf++)
#pragma unroll
      for (int nf = 0; nf < 2; nf++)
#pragma unroll
        for (int ks = 0; ks < 2; ks++)
          acc[mf][nf] = __builtin_amdgcn_mfma_f32_16x16x32_bf16(a[mf][ks], b[nf][ks], acc[mf][nf], 0, 0, 0);
    __builtin_amdgcn_s_setprio(0);
    __builtin_amdgcn_s_barrier();
    // ---------- phase 2: read b2(nf2-3); stage B-hi(t+1); Q01
#pragma unroll
    for (int nf = 0; nf < 2; nf++)
#pragma unroll
      for (int ks = 0; ks < 2; ks++) b2[nf][ks] = ldB(cur, nf + 2, ks);
    if (t + 1 < NT) stageB(cur ^ 1, t + 1, 1);
    __builtin_amdgcn_s_barrier();
    asm volatile("s_waitcnt lgkmcnt(0)" ::: "memory");
    __builtin_amdgcn_sched_barrier(0);
    __builtin_amdgcn_s_setprio(1);
#pragma unroll
    for (int mf = 0; mf < 4; mf++)
#pragma unroll
      for (int nf = 0; nf < 2; nf++)
#pragma unroll
        for (int ks = 0; ks < 2; ks++)
          acc[mf][nf + 2] = __builtin_amdgcn_mfma_f32_16x16x32_bf16(a[mf][ks], b2[nf][ks], acc[mf][nf + 2], 0, 0, 0);
    __builtin_amdgcn_s_setprio(0);
    __builtin_amdgcn_s_barrier();
    // ---------- phase 3: read a(mf4-7) (reuse regs); Q10
#pragma unroll
    for (int mf = 0; mf < 4; mf++)
#pragma unroll
      for (int ks = 0; ks < 2; ks++) a[mf][ks] = ldA(cur, mf + 4, ks);
    __builtin_amdgcn_s_barrier();
    asm volatile("s_waitcnt lgkmcnt(0)" ::: "memory");
    __builtin_amdgcn_sched_barrier(0);
    __builtin_amdgcn_s_setprio(1);
#pragma unroll
    for (int mf = 0; mf < 4; mf++)
#pragma unroll
      for (int nf = 0; nf < 2; nf++)
#pragma unroll
        for (int ks = 0; ks < 2; ks++)
          acc[mf + 4][nf] = __builtin_amdgcn_mfma_f32_16x16x32_bf16(a[mf][ks], b[nf][ks], acc[mf + 4][nf], 0, 0, 0);
    __builtin_amdgcn_s_setprio(0);
    __builtin_amdgcn_s_barrier();
    // ---------- phase 4: stage A(t+2) into cur (its reads finished ph3); Q11
    if (t + 2 < NT) { stageA(cur, t + 2, 0); stageA(cur, t + 2, 1); }
    __builtin_amdgcn_s_setprio(1);
#pragma unroll
    for (int mf = 0; mf < 4; mf++)
#pragma unroll
      for (int nf = 0; nf < 2; nf++)
#pragma unroll
        for (int ks = 0; ks < 2; ks++)
          acc[mf + 4][nf + 2] = __builtin_amdgcn_mfma_f32_16x16x32_bf16(a[mf][ks], b2[nf][ks], acc[mf + 4][nf + 2], 0, 0, 0);
    __builtin_amdgcn_s_setprio(0);
    if (t + 2 < NT) {
      asm volatile("s_waitcnt vmcnt(4)" ::: "memory");
    } else {
      asm volatile("s_waitcnt vmcnt(0)" ::: "memory");
    }
    __builtin_amdgcn_s_barrier();
    cur ^= 1;
  }

  // epilogue
  const int m0 = brow * 256 + wm * 128 + (lane >> 4) * 4;
  const int n0 = bcol * 256 + wn * 64 + r;
#pragma unroll
  for (int mf = 0; mf < 8; mf++) {
#pragma unroll
    for (int nf = 0; nf < 4; nf++) {
      int n = n0 + nf * 16;
      if (n >= PROJ) continue;
#pragma unroll
      for (int q = 0; q < 4; q++)
        C[(size_t)(m0 + mf * 16 + q) * PROJ + n] = acc[mf][nf][q];
    }
  }
}

// ---------------------------------------------------------------------------
// GEMM2: bf16 MFMA GEMM (m97 structure) with L2-locality grid remap
// (requires gridDim.y == 32)
// ---------------------------------------------------------------------------
template <bool GUARD_N>
__global__ __launch_bounds__(256) void gemm_bt16(
    const ushort* __restrict__ A, int lda,
    const ushort* __restrict__ Bw, int ldb,
    float* __restrict__ C, int ldc, int Kd, int Nmax) {
  __shared__ short smem[8192];
  const int tid = threadIdx.x;
  const int lane = tid & 63;
  const int wid = tid >> 6;
  const int wm = wid >> 1, wn = wid & 1;
  const int r = lane & 15;
  const int kx = lane >> 4;

  const int fid = blockIdx.y * gridDim.x + blockIdx.x;
  const int bcol = ((fid >> 8) << 3) | ((fid & 255) >> 5);
  const int brow = fid & 31;

  const ushort* Ab = A + (size_t)(brow * 128) * lda;
  const ushort* Bb = Bw + (size_t)(bcol * 128) * ldb;

  f32x4 acc[4][4];
#pragma unroll
  for (int i = 0; i < 4; i++)
#pragma unroll
    for (int j = 0; j < 4; j++) acc[i][j] = (f32x4)0.f;

  const int u0 = tid, u1 = 256 + tid;
  const int row0 = u0 >> 2, kc0 = (u0 & 3) * 8;
  const int row1 = u1 >> 2, kc1 = (u1 & 3) * 8;

  const s16x8* As8 = (const s16x8*)smem;
  const s16x8* Bs8 = (const s16x8*)(smem + 4096);

  for (int k0 = 0; k0 < Kd; k0 += 32) {
    __syncthreads();
    gload16(Ab + (size_t)row0 * lda + k0 + kc0, smem + u0 * 8);
    gload16(Ab + (size_t)row1 * lda + k0 + kc1, smem + u1 * 8);
    gload16(Bb + (size_t)row0 * ldb + k0 + kc0, smem + 4096 + u0 * 8);
    gload16(Bb + (size_t)row1 * ldb + k0 + kc1, smem + 4096 + u1 * 8);
    __syncthreads();
    s16x8 af[4], bw[4];
#pragma unroll
    for (int i = 0; i < 4; i++) af[i] = As8[(wm * 64 + i * 16 + r) * 4 + kx];
#pragma unroll
    for (int j = 0; j < 4; j++) bw[j] = Bs8[(wn * 64 + j * 16 + r) * 4 + kx];
#pragma unroll
    for (int i = 0; i < 4; i++)
#pragma unroll
      for (int j = 0; j < 4; j++)
        acc[i][j] = __builtin_amdgcn_mfma_f32_16x16x32_bf16(af[i], bw[j], acc[i][j], 0, 0, 0);
  }

  const int m0 = brow * 128 + wm * 64 + (lane >> 4) * 4;
  const int n0 = bcol * 128 + wn * 64 + (lane & 15);
#pragma unroll
  for (int i = 0; i < 4; i++) {
#pragma unroll
    for (int j = 0; j < 4; j++) {
      int n = n0 + j * 16;
      if (GUARD_N && n >= Nmax) continue;
#pragma unroll
      for (int q = 0; q < 4; q++) {
        C[(size_t)(m0 + i * 16 + q) * ldc + n] = acc[i][j][q];
      }
    }
  }
}

// ---------------------------------------------------------------------------
// Conv boundary capture
// ---------------------------------------------------------------------------
__global__ void conv_capture(const float* __restrict__ proj, float* __restrict__ side) {
  int idx = blockIdx.x * 256 + threadIdx.x;
  const int total = BB * CONV_DIM * NCH * 3;
  if (idx >= total) return;
  int c = idx % CONV_DIM;
  int t = idx / CONV_DIM;
  int j = t % 3; t /= 3;
  int chunk = t % NCH;
  int b = t / NCH;
  int s = chunk * CHUNK - 1 - j;
  float v = (s >= 0) ? proj[((size_t)b * SS + s) * PROJ + COL_HS + c] : 0.f;
  side[((size_t)(b * NCH + chunk) * 3 + j) * CONV_DIM + c] = v;
}

// ---------------------------------------------------------------------------
// Causal depthwise conv1d (K=4) + bias + SiLU, in place
// ---------------------------------------------------------------------------
__global__ void conv_silu(float* __restrict__ proj, const float* __restrict__ side,
                          const float* __restrict__ cw, const float* __restrict__ cb) {
  int idx = blockIdx.x * 256 + threadIdx.x;
  const int total = BB * CONV_DIM * NCH;
  if (idx >= total) return;
  int c = idx % CONV_DIM;
  int t = idx / CONV_DIM;
  int chunk = t % NCH;
  int b = t / NCH;
  float w0 = cw[c * 4 + 0], w1 = cw[c * 4 + 1], w2 = cw[c * 4 + 2], w3 = cw[c * 4 + 3];
  float bias = cb[c];
  const float* sd = side + ((size_t)(b * NCH + chunk) * 3) * CONV_DIM;
  float xm1 = sd[c];
  float xm2 = sd[CONV_DIM + c];
  float xm3 = sd[2 * CONV_DIM + c];
  size_t p = ((size_t)b * SS + (size_t)chunk * CHUNK) * PROJ + COL_HS + c;
  for (int s = 0; s < CHUNK; s++) {
    float xin = proj[p];
    float o = w3 * xin + w2 * xm1 + w1 * xm2 + w0 * xm3 + bias;
    o = o / (1.f + __expf(-o));      // SiLU
    proj[p] = o;
    xm3 = xm2; xm2 = xm1; xm1 = xin;
    p += PROJ;
  }
}

// ---------------------------------------------------------------------------
// SSD K1: per (b,h,chunk): softplus(dt), cumsum, chunk state (MFMA).
// states written TRANSPOSED: [d=64][n=128]
// ---------------------------------------------------------------------------
__global__ __launch_bounds__(256) void ssd_chunk_state(
    const float* __restrict__ proj, const float* __restrict__ dt_bias,
    const float* __restrict__ A_log, ushort* __restrict__ states,
    float* __restrict__ cumbuf, float* __restrict__ dtvbuf) {
  const int bid = blockIdx.x;
  const int c = bid & 15;
  const int h = (bid >> 4) & 63;
  const int b = bid >> 10;
  const int tid = threadIdx.x;
  const int lane = tid & 63;
  const int wv = tid >> 6;
  __shared__ float sdtv[CL], scum[CL], sw[CL];
  __shared__ ushort sBt[128 * 128];   // [n][t]
  __shared__ ushort sXw[64 * 128];    // [d][t] scaled
  const size_t row0 = (size_t)b * SS + (size_t)c * CL;
  const size_t bh = (size_t)(b * NH + h);

  const float Ah = -__expf(A_log[h]);
  if (tid < CL) {
    float z = proj[(row0 + tid) * PROJ + COL_DT + h] + dt_bias[h];
    float dtv = (z > 20.f) ? z : log1pf(__expf(z));
    sdtv[tid] = dtv;
    sw[tid] = dtv * Ah;
  }
  __syncthreads();
  for (int off = 1; off < CL; off <<= 1) {
    float v = 0.f;
    if (tid < CL) { v = sw[tid]; if (tid >= off) v += sw[tid - off]; }
    __syncthreads();
    if (tid < CL) sw[tid] = v;
    __syncthreads();
  }
  if (tid < CL) {
    scum[tid] = sw[tid];
    cumbuf[bh * SS + c * CL + tid] = sw[tid];
    dtvbuf[bh * SS + c * CL + tid] = sdtv[tid];
  }
  __syncthreads();
  const float cumL = scum[CL - 1];
  if (tid < CL) sw[tid] = __expf(cumL - scum[tid]) * sdtv[tid];
  __syncthreads();

  {
    const int t = tid >> 1, n0 = (tid & 1) * 64;
    const float* src = proj + (row0 + t) * PROJ + COL_B + n0;
#pragma unroll
    for (int j = 0; j < 64; j += 4) {
      float4 v = *(const float4*)(src + j);
      sBt[swz(n0 + j + 0, t)] = f2b(v.x);
      sBt[swz(n0 + j + 1, t)] = f2b(v.y);
      sBt[swz(n0 + j + 2, t)] = f2b(v.z);
      sBt[swz(n0 + j + 3, t)] = f2b(v.w);
    }
  }
  {
    const int d = tid & 63;
    const int t0 = (tid >> 6) * 32;
    for (int t = t0; t < t0 + 32; t++) {
      float x = proj[(row0 + t) * PROJ + COL_HS + h * 64 + d];
      sXw[swz(d, t)] = f2b(x * sw[t]);
    }
  }
  __syncthreads();

  const int r = lane & 15, kx = lane >> 4;
  f32x4 acc[2][4];
#pragma unroll
  for (int i = 0; i < 2; i++)
#pragma unroll
    for (int j = 0; j < 4; j++) acc[i][j] = (f32x4)0.f;
#pragma unroll
  for (int kk = 0; kk < 4; kk++) {
    s16x8 a[2], bo[4];
#pragma unroll
    for (int i = 0; i < 2; i++)
      a[i] = *(const s16x8*)&sBt[swz(wv * 32 + i * 16 + r, kk * 32 + kx * 8)];
#pragma unroll
    for (int j = 0; j < 4; j++)
      bo[j] = *(const s16x8*)&sXw[swz(j * 16 + r, kk * 32 + kx * 8)];
#pragma unroll
    for (int i = 0; i < 2; i++)
#pragma unroll
      for (int j = 0; j < 4; j++)
        acc[i][j] = __builtin_amdgcn_mfma_f32_16x16x32_bf16(a[i], bo[j], acc[i][j], 0, 0, 0);
  }
  ushort* dst = states + (size_t)bid * (128 * 64);
#pragma unroll
  for (int i = 0; i < 2; i++) {
#pragma unroll
    for (int j = 0; j < 4; j++) {
      int n = wv * 32 + i * 16 + (lane >> 4) * 4;
      int d = (lane & 15) + j * 16;
      ushort4 o;
      o.x = f2b(acc[i][j][0]);
      o.y = f2b(acc[i][j][1]);
      o.z = f2b(acc[i][j][2]);
      o.w = f2b(acc[i][j][3]);
      *(ushort4*)(dst + (size_t)d * 128 + n) = o;
    }
  }
}

// ---------------------------------------------------------------------------
// SSD K2: inter-chunk recurrence
// ---------------------------------------------------------------------------
__global__ __launch_bounds__(256) void ssd_state_scan(
    ushort* __restrict__ states, const float* __restrict__ cumbuf) {
  const int bh = blockIdx.x;
  const int tid = threadIdx.x;
  float run[32];
#pragma unroll
  for (int i = 0; i < 32; i++) run[i] = 0.f;
  for (int c = 0; c < NCHK; c++) {
    float dec = __expf(cumbuf[(size_t)bh * SS + c * CL + (CL - 1)]);
    ushort* p = states + ((size_t)bh * NCHK + c) * 8192 + tid * 32;
    s16x8 in[4];
#pragma unroll
    for (int v = 0; v < 4; v++) in[v] = *(const s16x8*)(p + v * 8);
    s16x8 out[4];
#pragma unroll
    for (int v = 0; v < 4; v++) {
#pragma unroll
      for (int e = 0; e < 8; e++) {
        int i = v * 8 + e;
        out[v][e] = (short)f2b(run[i]);
        run[i] = dec * run[i] + b2f((ushort)in[v][e]);
      }
    }
#pragma unroll
    for (int v = 0; v < 4; v++) *(s16x8*)(p + v * 8) = out[v];
  }
}

// ---------------------------------------------------------------------------
// SSD K3: per (b,h,chunk) fused output. LDS = 80KB -> 2 blocks/CU.
// ---------------------------------------------------------------------------
__global__ __launch_bounds__(256, 2) void ssd_chunk_out(
    float* __restrict__ proj, const ushort* __restrict__ states,
    const float* __restrict__ cumbuf, const float* __restrict__ dtvbuf,
    const float* __restrict__ Dp) {
  const int bid = blockIdx.x;
  const int c = bid & 15;
  const int h = (bid >> 4) & 63;
  const int b = bid >> 10;
  const int tid = threadIdx.x;
  const int lane = tid & 63;
  const int wv = tid >> 6;
  __shared__ ushort sC[128 * 128];
  __shared__ ushort sB[128 * 128];
  __shared__ ushort sX[64 * 128];
  const size_t row0 = (size_t)b * SS + (size_t)c * CL;
  const size_t bh = (size_t)(b * NH + h);
  const float* cumb = cumbuf + bh * SS + c * CL;
  const float* dtvb = dtvbuf + bh * SS + c * CL;
  const int r = lane & 15, kx = lane >> 4;

  float ct[2][4];
#pragma unroll
  for (int i = 0; i < 2; i++)
#pragma unroll
    for (int q = 0; q < 4; q++)
      ct[i][q] = cumb[wv * 32 + i * 16 + ((lane >> 4) << 2) + q];
  float cumt[8], dvt[8];
#pragma unroll
  for (int j = 0; j < 8; j++) {
    int tau = j * 16 + (lane & 15);
    cumt[j] = cumb[tau];
    dvt[j] = dtvb[tau];
  }
  const float eC = __expf(cumb[wv * 32 + (lane >> 1)]);

  {
    const int t = tid >> 1, n0 = (tid & 1) * 64;
    const float* srcC = proj + (row0 + t) * PROJ + COL_C + n0;
    const float* srcB = proj + (row0 + t) * PROJ + COL_B + n0;
#pragma unroll
    for (int j = 0; j < 64; j += 8) {
      float4 c0 = *(const float4*)(srcC + j);
      float4 c1 = *(const float4*)(srcC + j + 4);
      s16x8 u;
      u[0] = (short)f2b(c0.x); u[1] = (short)f2b(c0.y);
      u[2] = (short)f2b(c0.z); u[3] = (short)f2b(c0.w);
      u[4] = (short)f2b(c1.x); u[5] = (short)f2b(c1.y);
      u[6] = (short)f2b(c1.z); u[7] = (short)f2b(c1.w);
      *(s16x8*)&sC[swz(t, n0 + j)] = u;
      float4 b0 = *(const float4*)(srcB + j);
      float4 b1 = *(const float4*)(srcB + j + 4);
      s16x8 w;
      w[0] = (short)f2b(b0.x); w[1] = (short)f2b(b0.y);
      w[2] = (short)f2b(b0.z); w[3] = (short)f2b(b0.w);
      w[4] = (short)f2b(b1.x); w[5] = (short)f2b(b1.y);
      w[6] = (short)f2b(b1.z); w[7] = (short)f2b(b1.w);
      *(s16x8*)&sB[swz(t, n0 + j)] = w;
    }
  }
  {
    const int d = tid & 63;
    const int t0 = (tid >> 6) * 32;
    for (int t = t0; t < t0 + 32; t++)
      sX[swz(d, t)] = f2b(proj[(row0 + t) * PROJ + COL_HS + h * 64 + d]);
  }
  __syncthreads();

  f32x4 g[2][8];
#pragma unroll
  for (int i = 0; i < 2; i++)
#pragma unroll
    for (int j = 0; j < 8; j++) g[i][j] = (f32x4)0.f;
#pragma unroll
  for (int kk = 0; kk < 4; kk++) {
    s16x8 a[2], bo[8];
#pragma unroll
    for (int i = 0; i < 2; i++)
      a[i] = *(const s16x8*)&sC[swz(wv * 32 + i * 16 + r, kk * 32 + kx * 8)];
#pragma unroll
    for (int j = 0; j < 8; j++)
      bo[j] = *(const s16x8*)&sB[swz(j * 16 + r, kk * 32 + kx * 8)];
#pragma unroll
    for (int i = 0; i < 2; i++)
#pragma unroll
      for (int j = 0; j < 8; j++)
        g[i][j] = __builtin_amdgcn_mfma_f32_16x16x32_bf16(a[i], bo[j], g[i][j], 0, 0, 0);
  }

  s16x8 spf[4][4];
  {
    const ushort* sp = states + (size_t)bid * 8192;
#pragma unroll
    for (int kk = 0; kk < 4; kk++)
#pragma unroll
      for (int j = 0; j < 4; j++)
        spf[kk][j] = *(const s16x8*)(sp + (size_t)(j * 16 + r) * 128 + kk * 32 + kx * 8);
  }
  __syncthreads();

#pragma unroll
  for (int j = 0; j < 8; j++) {
    float cu = cumt[j], dv = dvt[j];
    int tau = j * 16 + (lane & 15);
#pragma unroll
    for (int i = 0; i < 2; i++) {
#pragma unroll
      for (int q = 0; q < 4; q++) {
        int t = wv * 32 + i * 16 + ((lane >> 4) << 2) + q;
        float val = (tau <= t) ? g[i][j][q] * __expf(ct[i][q] - cu) * dv : 0.f;
        sB[swz(t, tau)] = f2b(val);
      }
    }
  }
  {
    int t = wv * 32 + (lane >> 1);
    int n0 = (lane & 1) * 64;
#pragma unroll
    for (int j = 0; j < 64; j += 8) {
      s16x8 u = *(const s16x8*)&sC[swz(t, n0 + j)];
#pragma unroll
      for (int k = 0; k < 8; k++) u[k] = (short)f2b(b2f((ushort)u[k]) * eC);
      *(s16x8*)&sC[swz(t, n0 + j)] = u;
    }
  }
  __syncthreads();

  f32x4 y[2][4];
#pragma unroll
  for (int i = 0; i < 2; i++)
#pragma unroll
    for (int j = 0; j < 4; j++) y[i][j] = (f32x4)0.f;
#pragma unroll
  for (int kk = 0; kk < 4; kk++) {
    s16x8 a[2], bo[4];
#pragma unroll
    for (int i = 0; i < 2; i++)
      a[i] = *(const s16x8*)&sB[swz(wv * 32 + i * 16 + r, kk * 32 + kx * 8)];
#pragma unroll
    for (int j = 0; j < 4; j++)
      bo[j] = *(const s16x8*)&sX[swz(j * 16 + r, kk * 32 + kx * 8)];
#pragma unroll
    for (int i = 0; i < 2; i++)
#pragma unroll
      for (int j = 0; j < 4; j++)
        y[i][j] = __builtin_amdgcn_mfma_f32_16x16x32_bf16(a[i], bo[j], y[i][j], 0, 0, 0);
  }
#pragma unroll
  for (int kk = 0; kk < 4; kk++) {
    s16x8 a[2];
#pragma unroll
    for (int i = 0; i < 2; i++)
      a[i] = *(const s16x8*)&sC[swz(wv * 32 + i * 16 + r, kk * 32 + kx * 8)];
#pragma unroll
    for (int i = 0; i < 2; i++)
#pragma unroll
      for (int j = 0; j < 4; j++)
        y[i][j] = __builtin_amdgcn_mfma_f32_16x16x32_bf16(a[i], spf[kk][j], y[i][j], 0, 0, 0);
  }

  const float Dh = Dp[h];
#pragma unroll
  for (int i = 0; i < 2; i++) {
#pragma unroll
    for (int j = 0; j < 4; j++) {
      int t0 = wv * 32 + i * 16 + (lane >> 4) * 4;
      int d = (lane & 15) + j * 16;
#pragma unroll
      for (int q = 0; q < 4; q++) {
        float x = b2f(sX[swz(d, t0 + q)]);
        proj[(row0 + t0 + q) * PROJ + COL_HS + h * 64 + d] = y[i][j][q] + Dh * x;
      }
    }
  }
}

// ---------------------------------------------------------------------------
// Gated RMSNorm -> bf16 y16
// ---------------------------------------------------------------------------
__global__ __launch_bounds__(256) void rmsnorm_kernel(
    const float* __restrict__ proj, const float* __restrict__ nw,
    ushort* __restrict__ y16) {
  const int row = blockIdx.x;
  const int tid = threadIdx.x;
  const float* yp = proj + (size_t)row * PROJ + COL_HS;
  const float* gp = proj + (size_t)row * PROJ;
  float v[16];
  float ss = 0.f;
#pragma unroll
  for (int q = 0; q < 4; q++) {
    int col = q * 1024 + tid * 4;
    float4 y = *(const float4*)(yp + col);
    float4 g = *(const float4*)(gp + col);
    float vy[4] = {y.x, y.y, y.z, y.w};
    float vg[4] = {g.x, g.y, g.z, g.w};
#pragma unroll
    for (int j = 0; j < 4; j++) {
      float sg = vg[j] / (1.f + __expf(-vg[j]));
      float vv = vy[j] * sg;
      v[q * 4 + j] = vv;
      ss += vv * vv;
    }
  }
#pragma unroll
  for (int o = 1; o < 64; o <<= 1) ss += __shfl_xor(ss, o);
  __shared__ float red[4];
  if ((tid & 63) == 0) red[tid >> 6] = ss;
  __syncthreads();
  float tot = red[0] + red[1] + red[2] + red[3];
  float scale = rsqrtf(tot * (1.f / INTER) + EPS);
#pragma unroll
  for (int q = 0; q < 4; q++) {
    int col = q * 1024 + tid * 4;
    float4 w = *(const float4*)(nw + col);
    ushort4 o;
    o.x = f2b(v[q * 4 + 0] * scale * w.x);
    o.y = f2b(v[q * 4 + 1] * scale * w.y);
    o.z = f2b(v[q * 4 + 2] * scale * w.z);
    o.w = f2b(v[q * 4 + 3] * scale * w.w);
    *(ushort4*)(y16 + (size_t)row * INTER + col) = o;
  }
}

// ---------------------------------------------------------------------------
extern "C" void kernel_launch(void* const* d_in, const int* in_sizes, int n_in,
                              void* d_out, int out_size, void* d_ws, size_t ws_size,
                              hipStream_t stream) {
  const float* hs   = (const float*)d_in[0];
  const float* w1   = (const float*)d_in[1];
  const float* cw   = (const float*)d_in[2];
  const float* cb   = (const float*)d_in[3];
  const float* dtb  = (const float*)d_in[4];
  const float* alog = (const float*)d_in[5];
  const float* Dp   = (const float*)d_in[6];
  const float* nw   = (const float*)d_in[7];
  const float* w2   = (const float*)d_in[8];
  float* out = (float*)d_out;

  // ws layout
  char* base = (char*)d_ws;
  size_t off = 0;
  float* proj = (float*)(base + off); off += (size_t)BS * PROJ * 4;            // 139.46 MB
  float* side = (float*)(base + off); off += (size_t)BB * NCH * 3 * CONV_DIM * 4;
  off = (off + 255) & ~(size_t)255;
  char* rC = base + off;
  // phase 1 tenants:
  ushort* hs16 = (ushort*)rC;                                 // 16.78 MB
  ushort* w1p  = (ushort*)(rC + 16777216);                    // 35.65 MB (8704x2048)
  // phase 2 tenants (after GEMM1; hs16/w1p dead):
  ushort* states = (ushort*)rC;                               // 33.55 MB
  float*  cumbuf = (float*)(rC + 33554432);                   // 1.05 MB
  float*  dtvbuf = (float*)(rC + 33554432 + 1048576);         // 1.05 MB
  // phase 3 tenants (after K3; states/cum dead):
  ushort* w216 = (ushort*)rC;                                 // 16.78 MB
  ushort* y16  = (ushort*)(rC + 16777216);                    // 33.55 MB

  // 0) fp32 -> bf16 conversions for GEMM1
  {
    long n4 = (long)BS * HID / 4;
    to_bf16<<<(n4 + 255) / 256, 256, 0, stream>>>(hs, hs16, n4);
  }
  {
    long n4 = (long)PROJ_PAD * HID / 4;
    to_bf16_pad<<<(n4 + 255) / 256, 256, 0, stream>>>(w1, w1p, n4);
  }

  // 1) in_proj GEMM (8-phase 256^2): proj = hs @ w1^T
  gemm256_8ph<<<(BS / 256) * (PROJ_PAD / 256), 512, 0, stream>>>(hs16, w1p, proj);

  // 2) causal depthwise conv + SiLU (in place)
  conv_capture<<<(BB * CONV_DIM * NCH * 3 + 255) / 256, 256, 0, stream>>>(proj, side);
  conv_silu<<<(BB * CONV_DIM * NCH + 255) / 256, 256, 0, stream>>>(proj, side, cw, cb);

  // 3) SSD chunked scan
  ssd_chunk_state<<<BB * NH * NCHK, 256, 0, stream>>>(proj, dtb, alog, states, cumbuf, dtvbuf);
  ssd_state_scan<<<BB * NH, 256, 0, stream>>>(states, cumbuf);
  ssd_chunk_out<<<BB * NH * NCHK, 256, 0, stream>>>(proj, states, cumbuf, dtvbuf, Dp);

  // 4) w2 conversion (after SSD so it can reuse region C)
  {
    long n4 = (long)HID * INTER / 4;
    to_bf16<<<(n4 + 255) / 256, 256, 0, stream>>>(w2, w216, n4);
  }

  // 5) gated RMSNorm -> bf16 y16
  rmsnorm_kernel<<<BS, 256, 0, stream>>>(proj, nw, y16);

  // 6) out_proj GEMM: out = y16 @ w2^T
  gemm_bt16<false><<<dim3(HID / 128, BS / 128), 256, 0, stream>>>(
      y16, INTER, w216, INTER, out, HID, INTER, HID);
}

// Round 6
// 477.964 us; speedup vs baseline: 9.6390x; 1.0405x over previous
//
#include <hip/hip_runtime.h>
#include <hip/hip_bf16.h>
#include <cstddef>
#include <cstdint>

// Problem constants
#define HID   2048
#define INTER 4096
#define NH    64
#define HD    64
#define NST   128
#define CONV_DIM 4352           // INTER + 2*NST
#define PROJ  8512              // INTER + CONV_DIM + NH
#define PROJ_PAD 8704           // 34 * 256 (pad for 256-col tiles)
#define SS    2048
#define BB    2
#define BS    (BB*SS)           // 4096 rows
#define EPS   1e-5f

// proj column layout: [0,4096)=gate [4096,8192)=hs [8192,8320)=B [8320,8448)=C [8448,8512)=dt
#define COL_HS 4096
#define COL_B  8192
#define COL_C  8320
#define COL_DT 8448

#define NCH   16                // conv chunks along S
#define CHUNK 128               // SS / NCH

// SSD chunking
#define CL    128               // chunk length
#define NCHK  16                // SS / CL

typedef short s16x8 __attribute__((ext_vector_type(8)));
typedef float f32x4 __attribute__((ext_vector_type(4)));

__device__ inline ushort f2b(float x) {
  __hip_bfloat16 h = __float2bfloat16(x);
  return *(ushort*)&h;
}
__device__ inline float b2f(ushort u) {
  unsigned int v = ((unsigned int)u) << 16;
  return __uint_as_float(v);
}
// LDS tile: 256B rows (128 bf16), XOR-swizzled in 8-elem slots (T2)
__device__ inline int swz(int row, int e) { return row * 128 + (e ^ ((row & 7) << 3)); }

__device__ inline void gload16(const void* g, void* l) {
  __builtin_amdgcn_global_load_lds((const __attribute__((address_space(1))) void*)g,
                                   (__attribute__((address_space(3))) void*)l, 16, 0, 0);
}

// ---------------------------------------------------------------------------
// fp32 -> bf16 conversion kernels
// ---------------------------------------------------------------------------
__global__ __launch_bounds__(256) void to_bf16(const float* __restrict__ src,
                                               ushort* __restrict__ dst, long n4) {
  long i = (long)blockIdx.x * 256 + threadIdx.x;
  if (i >= n4) return;
  float4 v = *(const float4*)(src + i * 4);
  ushort4 o;
  o.x = f2b(v.x); o.y = f2b(v.y); o.z = f2b(v.z); o.w = f2b(v.w);
  *(ushort4*)(dst + i * 4) = o;
}

__global__ __launch_bounds__(256) void to_bf16_pad(const float* __restrict__ src,
                                                   ushort* __restrict__ dst, long n4) {
  long i = (long)blockIdx.x * 256 + threadIdx.x;
  if (i >= n4) return;
  long e0 = i * 4;
  long row = e0 >> 11;  // / 2048
  ushort4 o;
  if (row < PROJ) {
    float4 v = *(const float4*)(src + e0);
    o.x = f2b(v.x); o.y = f2b(v.y); o.z = f2b(v.z); o.w = f2b(v.w);
  } else {
    o.x = o.y = o.z = o.w = 0;
  }
  *(ushort4*)(dst + e0) = o;
}

// ---------------------------------------------------------------------------
// GEMM1: 256x256 8-phase pipelined bf16 MFMA GEMM (T2+T3+T4+T5).
// A [4096][2048] bf16, Bw [8704][2048] bf16 -> proj bf16 [4096][8512]
// (+ fp32 sidecar for the 64 dt columns).
// All 8 staging loads of tile t+2 issued in phase 4; counted vmcnt(8).
// ---------------------------------------------------------------------------
__global__ __launch_bounds__(512, 2) void gemm256_8ph(
    const ushort* __restrict__ A, const ushort* __restrict__ Bw,
    ushort* __restrict__ C, float* __restrict__ dtbuf) {
  __shared__ ushort smem[65536];   // [A: buf0 16K, buf1 16K][B: buf0, buf1] (ushorts)
  const int tid = threadIdx.x;
  const int lane = tid & 63;
  const int wid = tid >> 6;
  const int wm = wid >> 2;         // 0..1
  const int wn = wid & 3;          // 0..3
  const int r = lane & 15;
  const int kx = lane >> 4;        // 0..3

  // grid remap: column-groups of 8 (16 row-tiles), bijective over 544 blocks
  const int fid = blockIdx.x;
  const int bcol = ((fid >> 7) << 3) + ((fid & 127) >> 4);   // 0..33
  const int brow = fid & 15;                                  // 0..15

  const ushort* Ag = A + (size_t)(brow * 256) * HID;
  const ushort* Bg = Bw + (size_t)(bcol * 256) * HID;

  const int srow = tid >> 3;                 // 0..63
  const int scole = (((tid & 7) * 16) ^ ((srow & 7) << 4)) >> 1;  // elem offset in row

  auto stageA = [&](int buf, int kt, int half) {
    const ushort* g = Ag + (size_t)(half * 128 + srow) * HID + kt * 64 + scole;
    ushort* l = smem + buf * 16384 + half * 8192 + tid * 8;
    gload16(g, l);
    gload16(g + (size_t)64 * HID, l + 4096);
  };
  auto stageB = [&](int buf, int kt, int half) {
    const ushort* g = Bg + (size_t)(half * 128 + srow) * HID + kt * 64 + scole;
    ushort* l = smem + 32768 + buf * 16384 + half * 8192 + tid * 8;
    gload16(g, l);
    gload16(g + (size_t)64 * HID, l + 4096);
  };
  auto ldA = [&](int buf, int mf, int ks) -> s16x8 {
    int row = wm * 128 + mf * 16 + r;
    int cb = (ks * 64 + kx * 16) ^ ((row & 7) << 4);
    return *(const s16x8*)(smem + buf * 16384 + row * 64 + (cb >> 1));
  };
  auto ldB = [&](int buf, int nf, int ks) -> s16x8 {
    int row = wn * 64 + nf * 16 + r;
    int cb = (ks * 64 + kx * 16) ^ ((row & 7) << 4);
    return *(const s16x8*)(smem + 32768 + buf * 16384 + row * 64 + (cb >> 1));
  };

  f32x4 acc[8][4];
#pragma unroll
  for (int i = 0; i < 8; i++)
#pragma unroll
    for (int j = 0; j < 4; j++) acc[i][j] = (f32x4)0.f;

  constexpr int NT = HID / 64;   // 32 K-tiles

  // prologue: tile0 -> buf0, tile1 -> buf1; wait tile0 (tile1's 8 in flight)
  stageA(0, 0, 0); stageA(0, 0, 1);
  stageB(0, 0, 0); stageB(0, 0, 1);
  stageA(1, 1, 0); stageA(1, 1, 1);
  stageB(1, 1, 0); stageB(1, 1, 1);
  asm volatile("s_waitcnt vmcnt(8)" ::: "memory");
  __builtin_amdgcn_s_barrier();

  int cur = 0;
  for (int t = 0; t < NT; t++) {
    s16x8 a[4][2], b[2][2], b2[2][2];
    // ---------- phase 1: read a(mf0-3), b(nf0-1); Q00
#pragma unroll
    for (int mf = 0; mf < 4; mf++)
#pragma unroll
      for (int ks = 0; ks < 2; ks++) a[mf][ks] = ldA(cur, mf, ks);
#pragma unroll
    for (int nf = 0; nf < 2; nf++)
#pragma unroll
      for (int ks = 0; ks < 2; ks++) b[nf][ks] = ldB(cur, nf, ks);
    __builtin_amdgcn_s_barrier();
    asm volatile("s_waitcnt lgkmcnt(0)" ::: "memory");
    __builtin_amdgcn_sched_barrier(0);
    __builtin_amdgcn_s_setprio(1);
#pragma unroll
    for (int mf = 0; mf < 4; mf++)
#pragma unroll
      for (int nf = 0; nf < 2; nf++)
#pragma unroll
        for (int ks = 0; ks < 2; ks++)
          acc[mf][nf] = __builtin_amdgcn_mfma_f32_16x16x32_bf16(a[mf][ks], b[nf][ks], acc[mf][nf], 0, 0, 0);
    __builtin_amdgcn_s_setprio(0);
    __builtin_amdgcn_s_barrier();
    // ---------- phase 2: read b2(nf2-3); Q01
#pragma unroll
    for (int nf = 0; nf < 2; nf++)
#pragma unroll
      for (int ks = 0; ks < 2; ks++) b2[nf][ks] = ldB(cur, nf + 2, ks);
    __builtin_amdgcn_s_barrier();
    asm volatile("s_waitcnt lgkmcnt(0)" ::: "memory");
    __builtin_amdgcn_sched_barrier(0);
    __builtin_amdgcn_s_setprio(1);
#pragma unroll
    for (int mf = 0; mf < 4; mf++)
#pragma unroll
      for (int nf = 0; nf < 2; nf++)
#pragma unroll
        for (int ks = 0; ks < 2; ks++)
          acc[mf][nf + 2] = __builtin_amdgcn_mfma_f32_16x16x32_bf16(a[mf][ks], b2[nf][ks], acc[mf][nf + 2], 0, 0, 0);
    __builtin_amdgcn_s_setprio(0);
    __builtin_amdgcn_s_barrier();
    // ---------- phase 3: read a(mf4-7) (reuse regs); Q10
#pragma unroll
    for (int mf = 0; mf < 4; mf++)
#pragma unroll
      for (int ks = 0; ks < 2; ks++) a[mf][ks] = ldA(cur, mf + 4, ks);
    __builtin_amdgcn_s_barrier();
    asm volatile("s_waitcnt lgkmcnt(0)" ::: "memory");
    __builtin_amdgcn_sched_barrier(0);
    __builtin_amdgcn_s_setprio(1);
#pragma unroll
    for (int mf = 0; mf < 4; mf++)
#pragma unroll
      for (int nf = 0; nf < 2; nf++)
#pragma unroll
        for (int ks = 0; ks < 2; ks++)
          acc[mf + 4][nf] = __builtin_amdgcn_mfma_f32_16x16x32_bf16(a[mf][ks], b[nf][ks], acc[mf + 4][nf], 0, 0, 0);
    __builtin_amdgcn_s_setprio(0);
    __builtin_amdgcn_s_barrier();
    // ---------- phase 4: stage A(t+2)+B(t+2) into cur (tile t dead); Q11
    if (t + 2 < NT) {
      stageA(cur, t + 2, 0); stageA(cur, t + 2, 1);
      stageB(cur, t + 2, 0); stageB(cur, t + 2, 1);
    }
    __builtin_amdgcn_s_setprio(1);
#pragma unroll
    for (int mf = 0; mf < 4; mf++)
#pragma unroll
      for (int nf = 0; nf < 2; nf++)
#pragma unroll
        for (int ks = 0; ks < 2; ks++)
          acc[mf + 4][nf + 2] = __builtin_amdgcn_mfma_f32_16x16x32_bf16(a[mf][ks], b2[nf][ks], acc[mf + 4][nf + 2], 0, 0, 0);
    __builtin_amdgcn_s_setprio(0);
    if (t + 2 < NT) {
      asm volatile("s_waitcnt vmcnt(8)" ::: "memory");
    } else {
      asm volatile("s_waitcnt vmcnt(0)" ::: "memory");
    }
    __builtin_amdgcn_s_barrier();
    cur ^= 1;
  }

  // epilogue: bf16 store; dt columns also stored fp32 to sidecar
  const int m0 = brow * 256 + wm * 128 + (lane >> 4) * 4;
  const int n0 = bcol * 256 + wn * 64 + r;
#pragma unroll
  for (int mf = 0; mf < 8; mf++) {
#pragma unroll
    for (int nf = 0; nf < 4; nf++) {
      int n = n0 + nf * 16;
      if (n >= PROJ) continue;
#pragma unroll
      for (int q = 0; q < 4; q++) {
        float v = acc[mf][nf][q];
        int m = m0 + mf * 16 + q;
        C[(size_t)m * PROJ + n] = f2b(v);
        if (n >= COL_DT) dtbuf[(size_t)m * 64 + (n - COL_DT)] = v;
      }
    }
  }
}

// ---------------------------------------------------------------------------
// GEMM2: bf16 MFMA GEMM (m97 structure) with L2-locality grid remap
// (requires gridDim.y == 32). C output fp32.
// ---------------------------------------------------------------------------
__global__ __launch_bounds__(256) void gemm_bt16(
    const ushort* __restrict__ A, int lda,
    const ushort* __restrict__ Bw, int ldb,
    float* __restrict__ C, int ldc, int Kd) {
  __shared__ short smem[8192];
  const int tid = threadIdx.x;
  const int lane = tid & 63;
  const int wid = tid >> 6;
  const int wm = wid >> 1, wn = wid & 1;
  const int r = lane & 15;
  const int kx = lane >> 4;

  const int fid = blockIdx.y * gridDim.x + blockIdx.x;
  const int bcol = ((fid >> 8) << 3) | ((fid & 255) >> 5);
  const int brow = fid & 31;

  const ushort* Ab = A + (size_t)(brow * 128) * lda;
  const ushort* Bb = Bw + (size_t)(bcol * 128) * ldb;

  f32x4 acc[4][4];
#pragma unroll
  for (int i = 0; i < 4; i++)
#pragma unroll
    for (int j = 0; j < 4; j++) acc[i][j] = (f32x4)0.f;

  const int u0 = tid, u1 = 256 + tid;
  const int row0 = u0 >> 2, kc0 = (u0 & 3) * 8;
  const int row1 = u1 >> 2, kc1 = (u1 & 3) * 8;

  const s16x8* As8 = (const s16x8*)smem;
  const s16x8* Bs8 = (const s16x8*)(smem + 4096);

  for (int k0 = 0; k0 < Kd; k0 += 32) {
    __syncthreads();
    gload16(Ab + (size_t)row0 * lda + k0 + kc0, smem + u0 * 8);
    gload16(Ab + (size_t)row1 * lda + k0 + kc1, smem + u1 * 8);
    gload16(Bb + (size_t)row0 * ldb + k0 + kc0, smem + 4096 + u0 * 8);
    gload16(Bb + (size_t)row1 * ldb + k0 + kc1, smem + 4096 + u1 * 8);
    __syncthreads();
    s16x8 af[4], bw[4];
#pragma unroll
    for (int i = 0; i < 4; i++) af[i] = As8[(wm * 64 + i * 16 + r) * 4 + kx];
#pragma unroll
    for (int j = 0; j < 4; j++) bw[j] = Bs8[(wn * 64 + j * 16 + r) * 4 + kx];
#pragma unroll
    for (int i = 0; i < 4; i++)
#pragma unroll
      for (int j = 0; j < 4; j++)
        acc[i][j] = __builtin_amdgcn_mfma_f32_16x16x32_bf16(af[i], bw[j], acc[i][j], 0, 0, 0);
  }

  const int m0 = brow * 128 + wm * 64 + (lane >> 4) * 4;
  const int n0 = bcol * 128 + wn * 64 + (lane & 15);
#pragma unroll
  for (int i = 0; i < 4; i++) {
#pragma unroll
    for (int j = 0; j < 4; j++) {
      int n = n0 + j * 16;
#pragma unroll
      for (int q = 0; q < 4; q++) {
        C[(size_t)(m0 + i * 16 + q) * ldc + n] = acc[i][j][q];
      }
    }
  }
}

// ---------------------------------------------------------------------------
// Conv boundary capture (bf16)
// ---------------------------------------------------------------------------
__global__ void conv_capture(const ushort* __restrict__ proj, ushort* __restrict__ side) {
  int idx = blockIdx.x * 256 + threadIdx.x;
  const int total = BB * CONV_DIM * NCH * 3;
  if (idx >= total) return;
  int c = idx % CONV_DIM;
  int t = idx / CONV_DIM;
  int j = t % 3; t /= 3;
  int chunk = t % NCH;
  int b = t / NCH;
  int s = chunk * CHUNK - 1 - j;
  ushort v = (s >= 0) ? proj[((size_t)b * SS + s) * PROJ + COL_HS + c] : (ushort)0;
  side[((size_t)(b * NCH + chunk) * 3 + j) * CONV_DIM + c] = v;
}

// ---------------------------------------------------------------------------
// Causal depthwise conv1d (K=4) + bias + SiLU, in place (bf16)
// ---------------------------------------------------------------------------
__global__ void conv_silu(ushort* __restrict__ proj, const ushort* __restrict__ side,
                          const float* __restrict__ cw, const float* __restrict__ cb) {
  int idx = blockIdx.x * 256 + threadIdx.x;
  const int total = BB * CONV_DIM * NCH;
  if (idx >= total) return;
  int c = idx % CONV_DIM;
  int t = idx / CONV_DIM;
  int chunk = t % NCH;
  int b = t / NCH;
  float w0 = cw[c * 4 + 0], w1 = cw[c * 4 + 1], w2 = cw[c * 4 + 2], w3 = cw[c * 4 + 3];
  float bias = cb[c];
  const ushort* sd = side + ((size_t)(b * NCH + chunk) * 3) * CONV_DIM;
  float xm1 = b2f(sd[c]);
  float xm2 = b2f(sd[CONV_DIM + c]);
  float xm3 = b2f(sd[2 * CONV_DIM + c]);
  size_t p = ((size_t)b * SS + (size_t)chunk * CHUNK) * PROJ + COL_HS + c;
  for (int s = 0; s < CHUNK; s++) {
    float xin = b2f(proj[p]);
    float o = w3 * xin + w2 * xm1 + w1 * xm2 + w0 * xm3 + bias;
    o = o / (1.f + __expf(-o));      // SiLU
    proj[p] = f2b(o);
    xm3 = xm2; xm2 = xm1; xm1 = xin;
    p += PROJ;
  }
}

// ---------------------------------------------------------------------------
// SSD K1: per (b,h,chunk): softplus(dt) [fp32 sidecar], cumsum, chunk state.
// states written TRANSPOSED: [d=64][n=128]
// ---------------------------------------------------------------------------
__global__ __launch_bounds__(256) void ssd_chunk_state(
    const ushort* __restrict__ proj, const float* __restrict__ dtf,
    const float* __restrict__ dt_bias, const float* __restrict__ A_log,
    ushort* __restrict__ states, float* __restrict__ cumbuf,
    float* __restrict__ dtvbuf) {
  const int bid = blockIdx.x;
  const int c = bid & 15;
  const int h = (bid >> 4) & 63;
  const int b = bid >> 10;
  const int tid = threadIdx.x;
  const int lane = tid & 63;
  const int wv = tid >> 6;
  __shared__ float sdtv[CL], scum[CL], sw[CL];
  __shared__ ushort sBt[128 * 128];   // [n][t]
  __shared__ ushort sXw[64 * 128];    // [d][t] scaled
  const size_t row0 = (size_t)b * SS + (size_t)c * CL;
  const size_t bh = (size_t)(b * NH + h);

  const float Ah = -__expf(A_log[h]);
  if (tid < CL) {
    float z = dtf[(row0 + tid) * 64 + h] + dt_bias[h];
    float dtv = (z > 20.f) ? z : log1pf(__expf(z));
    sdtv[tid] = dtv;
    sw[tid] = dtv * Ah;
  }
  __syncthreads();
  for (int off = 1; off < CL; off <<= 1) {
    float v = 0.f;
    if (tid < CL) { v = sw[tid]; if (tid >= off) v += sw[tid - off]; }
    __syncthreads();
    if (tid < CL) sw[tid] = v;
    __syncthreads();
  }
  if (tid < CL) {
    scum[tid] = sw[tid];
    cumbuf[bh * SS + c * CL + tid] = sw[tid];
    dtvbuf[bh * SS + c * CL + tid] = sdtv[tid];
  }
  __syncthreads();
  const float cumL = scum[CL - 1];
  if (tid < CL) sw[tid] = __expf(cumL - scum[tid]) * sdtv[tid];
  __syncthreads();

  // stage B^T [n][t]
  {
    const int t = tid >> 1, n0 = (tid & 1) * 64;
    const ushort* src = proj + (row0 + t) * PROJ + COL_B + n0;
#pragma unroll
    for (int j = 0; j < 64; j += 8) {
      s16x8 v = *(const s16x8*)(src + j);
#pragma unroll
      for (int e = 0; e < 8; e++) sBt[swz(n0 + j + e, t)] = (ushort)v[e];
    }
  }
  // stage Xw^T [d][t] scaled by sw[t]
  {
    const int d = tid & 63;
    const int t0 = (tid >> 6) * 32;
    for (int t = t0; t < t0 + 32; t++) {
      float x = b2f(proj[(row0 + t) * PROJ + COL_HS + h * 64 + d]);
      sXw[swz(d, t)] = f2b(x * sw[t]);
    }
  }
  __syncthreads();

  const int r = lane & 15, kx = lane >> 4;
  f32x4 acc[2][4];
#pragma unroll
  for (int i = 0; i < 2; i++)
#pragma unroll
    for (int j = 0; j < 4; j++) acc[i][j] = (f32x4)0.f;
#pragma unroll
  for (int kk = 0; kk < 4; kk++) {
    s16x8 a[2], bo[4];
#pragma unroll
    for (int i = 0; i < 2; i++)
      a[i] = *(const s16x8*)&sBt[swz(wv * 32 + i * 16 + r, kk * 32 + kx * 8)];
#pragma unroll
    for (int j = 0; j < 4; j++)
      bo[j] = *(const s16x8*)&sXw[swz(j * 16 + r, kk * 32 + kx * 8)];
#pragma unroll
    for (int i = 0; i < 2; i++)
#pragma unroll
      for (int j = 0; j < 4; j++)
        acc[i][j] = __builtin_amdgcn_mfma_f32_16x16x32_bf16(a[i], bo[j], acc[i][j], 0, 0, 0);
  }
  ushort* dst = states + (size_t)bid * (128 * 64);
#pragma unroll
  for (int i = 0; i < 2; i++) {
#pragma unroll
    for (int j = 0; j < 4; j++) {
      int n = wv * 32 + i * 16 + (lane >> 4) * 4;
      int d = (lane & 15) + j * 16;
      ushort4 o;
      o.x = f2b(acc[i][j][0]);
      o.y = f2b(acc[i][j][1]);
      o.z = f2b(acc[i][j][2]);
      o.w = f2b(acc[i][j][3]);
      *(ushort4*)(dst + (size_t)d * 128 + n) = o;
    }
  }
}

// ---------------------------------------------------------------------------
// SSD K2: inter-chunk recurrence
// ---------------------------------------------------------------------------
__global__ __launch_bounds__(256) void ssd_state_scan(
    ushort* __restrict__ states, const float* __restrict__ cumbuf) {
  const int bh = blockIdx.x;
  const int tid = threadIdx.x;
  float run[32];
#pragma unroll
  for (int i = 0; i < 32; i++) run[i] = 0.f;
  for (int c = 0; c < NCHK; c++) {
    float dec = __expf(cumbuf[(size_t)bh * SS + c * CL + (CL - 1)]);
    ushort* p = states + ((size_t)bh * NCHK + c) * 8192 + tid * 32;
    s16x8 in[4];
#pragma unroll
    for (int v = 0; v < 4; v++) in[v] = *(const s16x8*)(p + v * 8);
    s16x8 out[4];
#pragma unroll
    for (int v = 0; v < 4; v++) {
#pragma unroll
      for (int e = 0; e < 8; e++) {
        int i = v * 8 + e;
        out[v][e] = (short)f2b(run[i]);
        run[i] = dec * run[i] + b2f((ushort)in[v][e]);
      }
    }
#pragma unroll
    for (int v = 0; v < 4; v++) *(s16x8*)(p + v * 8) = out[v];
  }
}

// ---------------------------------------------------------------------------
// SSD K3: per (b,h,chunk) fused output. LDS = 80KB -> 2 blocks/CU.
// ---------------------------------------------------------------------------
__global__ __launch_bounds__(256, 2) void ssd_chunk_out(
    ushort* __restrict__ proj, const ushort* __restrict__ states,
    const float* __restrict__ cumbuf, const float* __restrict__ dtvbuf,
    const float* __restrict__ Dp) {
  const int bid = blockIdx.x;
  const int c = bid & 15;
  const int h = (bid >> 4) & 63;
  const int b = bid >> 10;
  const int tid = threadIdx.x;
  const int lane = tid & 63;
  const int wv = tid >> 6;
  __shared__ ushort sC[128 * 128];
  __shared__ ushort sB[128 * 128];
  __shared__ ushort sX[64 * 128];
  const size_t row0 = (size_t)b * SS + (size_t)c * CL;
  const size_t bh = (size_t)(b * NH + h);
  const float* cumb = cumbuf + bh * SS + c * CL;
  const float* dtvb = dtvbuf + bh * SS + c * CL;
  const int r = lane & 15, kx = lane >> 4;

  float ct[2][4];
#pragma unroll
  for (int i = 0; i < 2; i++)
#pragma unroll
    for (int q = 0; q < 4; q++)
      ct[i][q] = cumb[wv * 32 + i * 16 + ((lane >> 4) << 2) + q];
  float cumt[8], dvt[8];
#pragma unroll
  for (int j = 0; j < 8; j++) {
    int tau = j * 16 + (lane & 15);
    cumt[j] = cumb[tau];
    dvt[j] = dtvb[tau];
  }
  const float eC = __expf(cumb[wv * 32 + (lane >> 1)]);

  // stage C and B natural [t][n]  (pure bf16 copies)
  {
    const int t = tid >> 1, n0 = (tid & 1) * 64;
    const ushort* srcC = proj + (row0 + t) * PROJ + COL_C + n0;
    const ushort* srcB = proj + (row0 + t) * PROJ + COL_B + n0;
#pragma unroll
    for (int j = 0; j < 64; j += 8) {
      *(s16x8*)&sC[swz(t, n0 + j)] = *(const s16x8*)(srcC + j);
      *(s16x8*)&sB[swz(t, n0 + j)] = *(const s16x8*)(srcB + j);
    }
  }
  // stage X^T [d][t]
  {
    const int d = tid & 63;
    const int t0 = (tid >> 6) * 32;
    for (int t = t0; t < t0 + 32; t++)
      sX[swz(d, t)] = proj[(row0 + t) * PROJ + COL_HS + h * 64 + d];
  }
  __syncthreads();

  f32x4 g[2][8];
#pragma unroll
  for (int i = 0; i < 2; i++)
#pragma unroll
    for (int j = 0; j < 8; j++) g[i][j] = (f32x4)0.f;
#pragma unroll
  for (int kk = 0; kk < 4; kk++) {
    s16x8 a[2], bo[8];
#pragma unroll
    for (int i = 0; i < 2; i++)
      a[i] = *(const s16x8*)&sC[swz(wv * 32 + i * 16 + r, kk * 32 + kx * 8)];
#pragma unroll
    for (int j = 0; j < 8; j++)
      bo[j] = *(const s16x8*)&sB[swz(j * 16 + r, kk * 32 + kx * 8)];
#pragma unroll
    for (int i = 0; i < 2; i++)
#pragma unroll
      for (int j = 0; j < 8; j++)
        g[i][j] = __builtin_amdgcn_mfma_f32_16x16x32_bf16(a[i], bo[j], g[i][j], 0, 0, 0);
  }

  s16x8 spf[4][4];
  {
    const ushort* sp = states + (size_t)bid * 8192;
#pragma unroll
    for (int kk = 0; kk < 4; kk++)
#pragma unroll
      for (int j = 0; j < 4; j++)
        spf[kk][j] = *(const s16x8*)(sp + (size_t)(j * 16 + r) * 128 + kk * 32 + kx * 8);
  }
  __syncthreads();

#pragma unroll
  for (int j = 0; j < 8; j++) {
    float cu = cumt[j], dv = dvt[j];
    int tau = j * 16 + (lane & 15);
#pragma unroll
    for (int i = 0; i < 2; i++) {
#pragma unroll
      for (int q = 0; q < 4; q++) {
        int t = wv * 32 + i * 16 + ((lane >> 4) << 2) + q;
        float val = (tau <= t) ? g[i][j][q] * __expf(ct[i][q] - cu) * dv : 0.f;
        sB[swz(t, tau)] = f2b(val);
      }
    }
  }
  {
    int t = wv * 32 + (lane >> 1);
    int n0 = (lane & 1) * 64;
#pragma unroll
    for (int j = 0; j < 64; j += 8) {
      s16x8 u = *(const s16x8*)&sC[swz(t, n0 + j)];
#pragma unroll
      for (int k = 0; k < 8; k++) u[k] = (short)f2b(b2f((ushort)u[k]) * eC);
      *(s16x8*)&sC[swz(t, n0 + j)] = u;
    }
  }
  __syncthreads();

  f32x4 y[2][4];
#pragma unroll
  for (int i = 0; i < 2; i++)
#pragma unroll
    for (int j = 0; j < 4; j++) y[i][j] = (f32x4)0.f;
#pragma unroll
  for (int kk = 0; kk < 4; kk++) {
    s16x8 a[2], bo[4];
#pragma unroll
    for (int i = 0; i < 2; i++)
      a[i] = *(const s16x8*)&sB[swz(wv * 32 + i * 16 + r, kk * 32 + kx * 8)];
#pragma unroll
    for (int j = 0; j < 4; j++)
      bo[j] = *(const s16x8*)&sX[swz(j * 16 + r, kk * 32 + kx * 8)];
#pragma unroll
    for (int i = 0; i < 2; i++)
#pragma unroll
      for (int j = 0; j < 4; j++)
        y[i][j] = __builtin_amdgcn_mfma_f32_16x16x32_bf16(a[i], bo[j], y[i][j], 0, 0, 0);
  }
#pragma unroll
  for (int kk = 0; kk < 4; kk++) {
    s16x8 a[2];
#pragma unroll
    for (int i = 0; i < 2; i++)
      a[i] = *(const s16x8*)&sC[swz(wv * 32 + i * 16 + r, kk * 32 + kx * 8)];
#pragma unroll
    for (int i = 0; i < 2; i++)
#pragma unroll
      for (int j = 0; j < 4; j++)
        y[i][j] = __builtin_amdgcn_mfma_f32_16x16x32_bf16(a[i], spf[kk][j], y[i][j], 0, 0, 0);
  }

  const float Dh = Dp[h];
#pragma unroll
  for (int i = 0; i < 2; i++) {
#pragma unroll
    for (int j = 0; j < 4; j++) {
      int t0 = wv * 32 + i * 16 + (lane >> 4) * 4;
      int d = (lane & 15) + j * 16;
#pragma unroll
      for (int q = 0; q < 4; q++) {
        float x = b2f(sX[swz(d, t0 + q)]);
        proj[(row0 + t0 + q) * PROJ + COL_HS + h * 64 + d] = f2b(y[i][j][q] + Dh * x);
      }
    }
  }
}

// ---------------------------------------------------------------------------
// Gated RMSNorm, bf16 in / bf16 in-place out over proj hs columns
// ---------------------------------------------------------------------------
__global__ __launch_bounds__(256) void rmsnorm_kernel(
    ushort* __restrict__ proj, const float* __restrict__ nw) {
  const int row = blockIdx.x;
  const int tid = threadIdx.x;
  ushort* yp = proj + (size_t)row * PROJ + COL_HS;
  const ushort* gp = proj + (size_t)row * PROJ;
  float v[16];
  float ss = 0.f;
#pragma unroll
  for (int q = 0; q < 4; q++) {
    int col = q * 1024 + tid * 4;
    ushort4 yv = *(const ushort4*)(yp + col);
    ushort4 gv = *(const ushort4*)(gp + col);
    float vy[4] = {b2f(yv.x), b2f(yv.y), b2f(yv.z), b2f(yv.w)};
    float vg[4] = {b2f(gv.x), b2f(gv.y), b2f(gv.z), b2f(gv.w)};
#pragma unroll
    for (int j = 0; j < 4; j++) {
      float sg = vg[j] / (1.f + __expf(-vg[j]));
      float vv = vy[j] * sg;
      v[q * 4 + j] = vv;
      ss += vv * vv;
    }
  }
#pragma unroll
  for (int o = 1; o < 64; o <<= 1) ss += __shfl_xor(ss, o);
  __shared__ float red[4];
  if ((tid & 63) == 0) red[tid >> 6] = ss;
  __syncthreads();
  float tot = red[0] + red[1] + red[2] + red[3];
  float scale = rsqrtf(tot * (1.f / INTER) + EPS);
#pragma unroll
  for (int q = 0; q < 4; q++) {
    int col = q * 1024 + tid * 4;
    float4 w = *(const float4*)(nw + col);
    ushort4 o;
    o.x = f2b(v[q * 4 + 0] * scale * w.x);
    o.y = f2b(v[q * 4 + 1] * scale * w.y);
    o.z = f2b(v[q * 4 + 2] * scale * w.z);
    o.w = f2b(v[q * 4 + 3] * scale * w.w);
    *(ushort4*)(yp + col) = o;
  }
}

// ---------------------------------------------------------------------------
extern "C" void kernel_launch(void* const* d_in, const int* in_sizes, int n_in,
                              void* d_out, int out_size, void* d_ws, size_t ws_size,
                              hipStream_t stream) {
  const float* hs   = (const float*)d_in[0];
  const float* w1   = (const float*)d_in[1];
  const float* cw   = (const float*)d_in[2];
  const float* cb   = (const float*)d_in[3];
  const float* dtb  = (const float*)d_in[4];
  const float* alog = (const float*)d_in[5];
  const float* Dp   = (const float*)d_in[6];
  const float* nw   = (const float*)d_in[7];
  const float* w2   = (const float*)d_in[8];
  float* out = (float*)d_out;

  // ws layout
  char* base = (char*)d_ws;
  size_t off = 0;
  ushort* proj = (ushort*)(base + off); off += (size_t)BS * PROJ * 2;          // 69.7 MB
  ushort* side = (ushort*)(base + off); off += (size_t)BB * NCH * 3 * CONV_DIM * 2;
  off = (off + 255) & ~(size_t)255;
  float* dtbuf = (float*)(base + off); off += (size_t)BS * 64 * 4;             // 1.05 MB
  off = (off + 255) & ~(size_t)255;
  char* rC = base + off;
  // phase 1 tenants:
  ushort* hs16 = (ushort*)rC;                                 // 16.78 MB
  ushort* w1p  = (ushort*)(rC + 16777216);                    // 35.65 MB (8704x2048)
  // phase 2 tenants (after GEMM1; hs16/w1p dead):
  ushort* states = (ushort*)rC;                               // 33.55 MB
  float*  cumbuf = (float*)(rC + 33554432);                   // 1.05 MB
  float*  dtvbuf = (float*)(rC + 33554432 + 1048576);         // 1.05 MB
  // phase 3 tenants (after K3; states/cum dead):
  ushort* w216 = (ushort*)rC;                                 // 16.78 MB

  // 0) fp32 -> bf16 conversions for GEMM1
  {
    long n4 = (long)BS * HID / 4;
    to_bf16<<<(n4 + 255) / 256, 256, 0, stream>>>(hs, hs16, n4);
  }
  {
    long n4 = (long)PROJ_PAD * HID / 4;
    to_bf16_pad<<<(n4 + 255) / 256, 256, 0, stream>>>(w1, w1p, n4);
  }

  // 1) in_proj GEMM (8-phase 256^2): proj(bf16) = hs @ w1^T ; dt fp32 sidecar
  gemm256_8ph<<<(BS / 256) * (PROJ_PAD / 256), 512, 0, stream>>>(hs16, w1p, proj, dtbuf);

  // 2) causal depthwise conv + SiLU (in place, bf16)
  conv_capture<<<(BB * CONV_DIM * NCH * 3 + 255) / 256, 256, 0, stream>>>(proj, side);
  conv_silu<<<(BB * CONV_DIM * NCH + 255) / 256, 256, 0, stream>>>(proj, side, cw, cb);

  // 3) SSD chunked scan
  ssd_chunk_state<<<BB * NH * NCHK, 256, 0, stream>>>(proj, dtbuf, dtb, alog, states, cumbuf, dtvbuf);
  ssd_state_scan<<<BB * NH, 256, 0, stream>>>(states, cumbuf);
  ssd_chunk_out<<<BB * NH * NCHK, 256, 0, stream>>>(proj, states, cumbuf, dtvbuf, Dp);

  // 4) w2 conversion (after SSD so it can reuse region C)
  {
    long n4 = (long)HID * INTER / 4;
    to_bf16<<<(n4 + 255) / 256, 256, 0, stream>>>(w2, w216, n4);
  }

  // 5) gated RMSNorm (in place over proj hs columns)
  rmsnorm_kernel<<<BS, 256, 0, stream>>>(proj, nw);

  // 6) out_proj GEMM: out = ynorm @ w2^T  (A read directly from proj, lda=PROJ)
  gemm_bt16<<<dim3(HID / 128, BS / 128), 256, 0, stream>>>(
      (const ushort*)(proj + COL_HS), PROJ, w216, INTER, out, HID, INTER);
}

// Round 8
// 441.356 us; speedup vs baseline: 10.4385x; 1.0829x over previous
//
#include <hip/hip_runtime.h>
#include <hip/hip_bf16.h>
#include <cstddef>
#include <cstdint>

// Problem constants
#define HID   2048
#define INTER 4096
#define NH    64
#define HD    64
#define NST   128
#define CONV_DIM 4352           // INTER + 2*NST
#define PROJ  8512              // INTER + CONV_DIM + NH
#define PROJ_PAD 8704           // 34 * 256 (pad for 256-col tiles)
#define SS    2048
#define BB    2
#define BS    (BB*SS)           // 4096 rows
#define EPS   1e-5f

// proj column layout: [0,4096)=gate [4096,8192)=hs [8192,8320)=B [8320,8448)=C [8448,8512)=dt
#define COL_HS 4096
#define COL_B  8192
#define COL_C  8320
#define COL_DT 8448

#define NCH   16                // conv chunks along S
#define CHUNK 128               // SS / NCH

// SSD chunking
#define CL    128               // chunk length
#define NCHK  16                // SS / CL

typedef short s16x8 __attribute__((ext_vector_type(8)));
typedef float f32x4 __attribute__((ext_vector_type(4)));

__device__ inline ushort f2b(float x) {
  __hip_bfloat16 h = __float2bfloat16(x);
  return *(ushort*)&h;
}
__device__ inline float b2f(ushort u) {
  unsigned int v = ((unsigned int)u) << 16;
  return __uint_as_float(v);
}
// LDS tile: 256B rows (128 bf16), XOR-swizzled in 8-elem slots (T2)
__device__ inline int swz(int row, int e) { return row * 128 + (e ^ ((row & 7) << 3)); }

__device__ inline void gload16(const void* g, void* l) {
  __builtin_amdgcn_global_load_lds((const __attribute__((address_space(1))) void*)g,
                                   (__attribute__((address_space(3))) void*)l, 16, 0, 0);
}

// ---------------------------------------------------------------------------
// fp32 -> bf16 conversion kernels
// ---------------------------------------------------------------------------
__global__ __launch_bounds__(256) void to_bf16(const float* __restrict__ src,
                                               ushort* __restrict__ dst, long n4) {
  long i = (long)blockIdx.x * 256 + threadIdx.x;
  if (i >= n4) return;
  float4 v = *(const float4*)(src + i * 4);
  ushort4 o;
  o.x = f2b(v.x); o.y = f2b(v.y); o.z = f2b(v.z); o.w = f2b(v.w);
  *(ushort4*)(dst + i * 4) = o;
}

__global__ __launch_bounds__(256) void to_bf16_pad(const float* __restrict__ src,
                                                   ushort* __restrict__ dst, long n4) {
  long i = (long)blockIdx.x * 256 + threadIdx.x;
  if (i >= n4) return;
  long e0 = i * 4;
  long row = e0 >> 11;  // / 2048
  ushort4 o;
  if (row < PROJ) {
    float4 v = *(const float4*)(src + e0);
    o.x = f2b(v.x); o.y = f2b(v.y); o.z = f2b(v.z); o.w = f2b(v.w);
  } else {
    o.x = o.y = o.z = o.w = 0;
  }
  *(ushort4*)(dst + e0) = o;
}

// ---------------------------------------------------------------------------
// GEMM1: 256x256 8-phase pipelined bf16 MFMA GEMM (T2+T3+T4+T5).
// Round-5 schedule: B(t+1) staged halves in ph1/ph2 (other buf), A(t+2)
// staged in ph4 (same buf, reads drained by ph3), vmcnt(4).
// Epilogue: bf16 proj store + fp32 dt sidecar.
// ---------------------------------------------------------------------------
__global__ __launch_bounds__(512, 2) void gemm256_8ph(
    const ushort* __restrict__ A, const ushort* __restrict__ Bw,
    ushort* __restrict__ C, float* __restrict__ dtbuf) {
  __shared__ ushort smem[65536];   // [A: buf0 16K, buf1 16K][B: buf0, buf1] (ushorts)
  const int tid = threadIdx.x;
  const int lane = tid & 63;
  const int wid = tid >> 6;
  const int wm = wid >> 2;         // 0..1
  const int wn = wid & 3;          // 0..3
  const int r = lane & 15;
  const int kx = lane >> 4;        // 0..3

  // grid remap: column-groups of 8 (16 row-tiles), bijective over 544 blocks
  const int fid = blockIdx.x;
  const int bcol = ((fid >> 7) << 3) + ((fid & 127) >> 4);   // 0..33
  const int brow = fid & 15;                                  // 0..15

  const ushort* Ag = A + (size_t)(brow * 256) * HID;
  const ushort* Bg = Bw + (size_t)(bcol * 256) * HID;

  const int srow = tid >> 3;                 // 0..63
  const int scole = (((tid & 7) * 16) ^ ((srow & 7) << 4)) >> 1;  // elem offset in row

  auto stageA = [&](int buf, int kt, int half) {
    const ushort* g = Ag + (size_t)(half * 128 + srow) * HID + kt * 64 + scole;
    ushort* l = smem + buf * 16384 + half * 8192 + tid * 8;
    gload16(g, l);
    gload16(g + (size_t)64 * HID, l + 4096);
  };
  auto stageB = [&](int buf, int kt, int half) {
    const ushort* g = Bg + (size_t)(half * 128 + srow) * HID + kt * 64 + scole;
    ushort* l = smem + 32768 + buf * 16384 + half * 8192 + tid * 8;
    gload16(g, l);
    gload16(g + (size_t)64 * HID, l + 4096);
  };
  auto ldA = [&](int buf, int mf, int ks) -> s16x8 {
    int row = wm * 128 + mf * 16 + r;
    int cb = (ks * 64 + kx * 16) ^ ((row & 7) << 4);
    return *(const s16x8*)(smem + buf * 16384 + row * 64 + (cb >> 1));
  };
  auto ldB = [&](int buf, int nf, int ks) -> s16x8 {
    int row = wn * 64 + nf * 16 + r;
    int cb = (ks * 64 + kx * 16) ^ ((row & 7) << 4);
    return *(const s16x8*)(smem + 32768 + buf * 16384 + row * 64 + (cb >> 1));
  };

  f32x4 acc[8][4];
#pragma unroll
  for (int i = 0; i < 8; i++)
#pragma unroll
    for (int j = 0; j < 4; j++) acc[i][j] = (f32x4)0.f;

  constexpr int NT = HID / 64;   // 32 K-tiles

  // prologue: A(0), B(0), A(1) ; wait tile0 arrived (A(1) in flight)
  stageA(0, 0, 0); stageA(0, 0, 1);
  stageB(0, 0, 0); stageB(0, 0, 1);
  stageA(1, 1, 0); stageA(1, 1, 1);
  asm volatile("s_waitcnt vmcnt(4)" ::: "memory");
  __builtin_amdgcn_s_barrier();

  int cur = 0;
  for (int t = 0; t < NT; t++) {
    s16x8 a[4][2], b[2][2], b2[2][2];
    // ---------- phase 1: read a(mf0-3), b(nf0-1); stage B-lo(t+1); Q00
#pragma unroll
    for (int mf = 0; mf < 4; mf++)
#pragma unroll
      for (int ks = 0; ks < 2; ks++) a[mf][ks] = ldA(cur, mf, ks);
#pragma unroll
    for (int nf = 0; nf < 2; nf++)
#pragma unroll
      for (int ks = 0; ks < 2; ks++) b[nf][ks] = ldB(cur, nf, ks);
    if (t + 1 < NT) stageB(cur ^ 1, t + 1, 0);
    __builtin_amdgcn_s_barrier();
    asm volatile("s_waitcnt lgkmcnt(0)" ::: "memory");
    __builtin_amdgcn_sched_barrier(0);
    __builtin_amdgcn_s_setprio(1);
#pragma unroll
    for (int mf = 0; mf < 4; mf++)
#pragma unroll
      for (int nf = 0; nf < 2; nf++)
#pragma unroll
        for (int ks = 0; ks < 2; ks++)
          acc[mf][nf] = __builtin_amdgcn_mfma_f32_16x16x32_bf16(a[mf][ks], b[nf][ks], acc[mf][nf], 0, 0, 0);
    __builtin_amdgcn_s_setprio(0);
    __builtin_amdgcn_s_barrier();
    // ---------- phase 2: read b2(nf2-3); stage B-hi(t+1); Q01
#pragma unroll
    for (int nf = 0; nf < 2; nf++)
#pragma unroll
      for (int ks = 0; ks < 2; ks++) b2[nf][ks] = ldB(cur, nf + 2, ks);
    if (t + 1 < NT) stageB(cur ^ 1, t + 1, 1);
    __builtin_amdgcn_s_barrier();
    asm volatile("s_waitcnt lgkmcnt(0)" ::: "memory");
    __builtin_amdgcn_sched_barrier(0);
    __builtin_amdgcn_s_setprio(1);
#pragma unroll
    for (int mf = 0; mf < 4; mf++)
#pragma unroll
      for (int nf = 0; nf < 2; nf++)
#pragma unroll
        for (int ks = 0; ks < 2; ks++)
          acc[mf][nf + 2] = __builtin_amdgcn_mfma_f32_16x16x32_bf16(a[mf][ks], b2[nf][ks], acc[mf][nf + 2], 0, 0, 0);
    __builtin_amdgcn_s_setprio(0);
    __builtin_amdgcn_s_barrier();
    // ---------- phase 3: read a(mf4-7) (reuse regs); Q10
#pragma unroll
    for (int mf = 0; mf < 4; mf++)
#pragma unroll
      for (int ks = 0; ks < 2; ks++) a[mf][ks] = ldA(cur, mf + 4, ks);
    __builtin_amdgcn_s_barrier();
    asm volatile("s_waitcnt lgkmcnt(0)" ::: "memory");
    __builtin_amdgcn_sched_barrier(0);
    __builtin_amdgcn_s_setprio(1);
#pragma unroll
    for (int mf = 0; mf < 4; mf++)
#pragma unroll
      for (int nf = 0; nf < 2; nf++)
#pragma unroll
        for (int ks = 0; ks < 2; ks++)
          acc[mf + 4][nf] = __builtin_amdgcn_mfma_f32_16x16x32_bf16(a[mf][ks], b[nf][ks], acc[mf + 4][nf], 0, 0, 0);
    __builtin_amdgcn_s_setprio(0);
    __builtin_amdgcn_s_barrier();
    // ---------- phase 4: stage A(t+2) into cur (its reads finished ph3); Q11
    if (t + 2 < NT) { stageA(cur, t + 2, 0); stageA(cur, t + 2, 1); }
    __builtin_amdgcn_s_setprio(1);
#pragma unroll
    for (int mf = 0; mf < 4; mf++)
#pragma unroll
      for (int nf = 0; nf < 2; nf++)
#pragma unroll
        for (int ks = 0; ks < 2; ks++)
          acc[mf + 4][nf + 2] = __builtin_amdgcn_mfma_f32_16x16x32_bf16(a[mf][ks], b2[nf][ks], acc[mf + 4][nf + 2], 0, 0, 0);
    __builtin_amdgcn_s_setprio(0);
    if (t + 2 < NT) {
      asm volatile("s_waitcnt vmcnt(4)" ::: "memory");
    } else {
      asm volatile("s_waitcnt vmcnt(0)" ::: "memory");
    }
    __builtin_amdgcn_s_barrier();
    cur ^= 1;
  }

  // epilogue: bf16 store; dt columns also stored fp32 to sidecar
  const int m0 = brow * 256 + wm * 128 + (lane >> 4) * 4;
  const int n0 = bcol * 256 + wn * 64 + r;
#pragma unroll
  for (int mf = 0; mf < 8; mf++) {
#pragma unroll
    for (int nf = 0; nf < 4; nf++) {
      int n = n0 + nf * 16;
      if (n >= PROJ) continue;
#pragma unroll
      for (int q = 0; q < 4; q++) {
        float v = acc[mf][nf][q];
        int m = m0 + mf * 16 + q;
        C[(size_t)m * PROJ + n] = f2b(v);
        if (n >= COL_DT) dtbuf[(size_t)m * 64 + (n - COL_DT)] = v;
      }
    }
  }
}

// ---------------------------------------------------------------------------
// GEMM2: 256x128-tile pipelined bf16 MFMA GEMM. Grid = 256 blocks.
// 512 thr = 8 waves (4M x 2N, 64x64/wave), BK=64, NT=64, LDS 96KB dbuf.
// STAGING FIX (rule 21): each thread writes exactly one 16B slot at
// lds + tid*16 per batch (gload_lds is wave-uniform-base + lane*16);
// batches of 64 rows: A = 4 batches, B = 2 batches. Global source
// pre-swizzled; readers use the matching XOR.
// ---------------------------------------------------------------------------
__global__ __launch_bounds__(512, 2) void gemm2_256x128(
    const ushort* __restrict__ A, const ushort* __restrict__ Bw,
    float* __restrict__ C) {
  __shared__ ushort smem[49152];   // A: 2x16384, B (at 32768): 2x8192
  const int tid = threadIdx.x;
  const int lane = tid & 63;
  const int wid = tid >> 6;
  const int wm = wid >> 1;         // 0..3
  const int wn = wid & 1;          // 0..1
  const int r = lane & 15;
  const int kx = lane >> 4;        // 0..3

  const int fid = blockIdx.x;      // 256 blocks
  const int bcol = fid >> 4;       // 0..15
  const int brow = fid & 15;       // 0..15

  const ushort* Ag = A + (size_t)(brow * 256) * PROJ;
  const ushort* Bg = Bw + (size_t)(bcol * 128) * INTER;

  // contiguous staging map: thread -> (row srow in batch, 16B slot tid&7)
  const int srow = tid >> 3;                 // 0..63
  const int scole = (((tid & 7) * 16) ^ ((srow & 7) << 4)) >> 1;  // elem off in row

  auto stageA2 = [&](int buf, int kt) {
#pragma unroll
    for (int i = 0; i < 4; i++) {
      gload16(Ag + (size_t)(i * 64 + srow) * PROJ + kt * 64 + scole,
              smem + buf * 16384 + i * 4096 + tid * 8);
    }
  };
  auto stageB2 = [&](int buf, int kt) {
#pragma unroll
    for (int i = 0; i < 2; i++) {
      gload16(Bg + (size_t)(i * 64 + srow) * INTER + kt * 64 + scole,
              smem + 32768 + buf * 8192 + i * 4096 + tid * 8);
    }
  };
  auto ldA2 = [&](int buf, int mf, int ks) -> s16x8 {
    int row = wm * 64 + mf * 16 + r;
    int cb = (ks * 64 + kx * 16) ^ ((row & 7) << 4);
    return *(const s16x8*)(smem + buf * 16384 + row * 64 + (cb >> 1));
  };
  auto ldB2 = [&](int buf, int nf, int ks) -> s16x8 {
    int row = wn * 64 + nf * 16 + r;
    int cb = (ks * 64 + kx * 16) ^ ((row & 7) << 4);
    return *(const s16x8*)(smem + 32768 + buf * 8192 + row * 64 + (cb >> 1));
  };

  f32x4 acc[4][4];
#pragma unroll
  for (int i = 0; i < 4; i++)
#pragma unroll
    for (int j = 0; j < 4; j++) acc[i][j] = (f32x4)0.f;

  constexpr int NT = INTER / 64;   // 64 K-tiles

  // prologue: tile0 -> buf0, tile1 -> buf1 (6 loads each); wait tile0
  stageA2(0, 0); stageB2(0, 0);
  stageA2(1, 1); stageB2(1, 1);
  asm volatile("s_waitcnt vmcnt(6)" ::: "memory");
  __builtin_amdgcn_s_barrier();

  int cur = 0;
  for (int t = 0; t < NT; t++) {
    s16x8 a[4][2], b[4][2];
    // ---------- phase 1: read ALL frags; MFMA nf0-1
#pragma unroll
    for (int mf = 0; mf < 4; mf++)
#pragma unroll
      for (int ks = 0; ks < 2; ks++) a[mf][ks] = ldA2(cur, mf, ks);
#pragma unroll
    for (int nf = 0; nf < 4; nf++)
#pragma unroll
      for (int ks = 0; ks < 2; ks++) b[nf][ks] = ldB2(cur, nf, ks);
    __builtin_amdgcn_s_barrier();
    asm volatile("s_waitcnt lgkmcnt(0)" ::: "memory");
    __builtin_amdgcn_sched_barrier(0);
    __builtin_amdgcn_s_setprio(1);
#pragma unroll
    for (int mf = 0; mf < 4; mf++)
#pragma unroll
      for (int nf = 0; nf < 2; nf++)
#pragma unroll
        for (int ks = 0; ks < 2; ks++)
          acc[mf][nf] = __builtin_amdgcn_mfma_f32_16x16x32_bf16(a[mf][ks], b[nf][ks], acc[mf][nf], 0, 0, 0);
    __builtin_amdgcn_s_setprio(0);
    __builtin_amdgcn_s_barrier();
    // ---------- phase 2: stage t+2 into cur (all reads drained); MFMA nf2-3
    if (t + 2 < NT) { stageA2(cur, t + 2); stageB2(cur, t + 2); }
    __builtin_amdgcn_s_setprio(1);
#pragma unroll
    for (int mf = 0; mf < 4; mf++)
#pragma unroll
      for (int nf = 2; nf < 4; nf++)
#pragma unroll
        for (int ks = 0; ks < 2; ks++)
          acc[mf][nf] = __builtin_amdgcn_mfma_f32_16x16x32_bf16(a[mf][ks], b[nf][ks], acc[mf][nf], 0, 0, 0);
    __builtin_amdgcn_s_setprio(0);
    if (t + 2 < NT) {
      asm volatile("s_waitcnt vmcnt(6)" ::: "memory");
    } else {
      asm volatile("s_waitcnt vmcnt(0)" ::: "memory");
    }
    __builtin_amdgcn_s_barrier();
    cur ^= 1;
  }

  // epilogue: fp32 out
  const int m0 = brow * 256 + wm * 64 + (lane >> 4) * 4;
  const int n0 = bcol * 128 + wn * 64 + r;
#pragma unroll
  for (int mf = 0; mf < 4; mf++) {
#pragma unroll
    for (int nf = 0; nf < 4; nf++) {
      int n = n0 + nf * 16;
#pragma unroll
      for (int q = 0; q < 4; q++)
        C[(size_t)(m0 + mf * 16 + q) * HID + n] = acc[mf][nf][q];
    }
  }
}

// ---------------------------------------------------------------------------
// Conv boundary capture (bf16)
// ---------------------------------------------------------------------------
__global__ void conv_capture(const ushort* __restrict__ proj, ushort* __restrict__ side) {
  int idx = blockIdx.x * 256 + threadIdx.x;
  const int total = BB * CONV_DIM * NCH * 3;
  if (idx >= total) return;
  int c = idx % CONV_DIM;
  int t = idx / CONV_DIM;
  int j = t % 3; t /= 3;
  int chunk = t % NCH;
  int b = t / NCH;
  int s = chunk * CHUNK - 1 - j;
  ushort v = (s >= 0) ? proj[((size_t)b * SS + s) * PROJ + COL_HS + c] : (ushort)0;
  side[((size_t)(b * NCH + chunk) * 3 + j) * CONV_DIM + c] = v;
}

// ---------------------------------------------------------------------------
// Causal depthwise conv1d (K=4) + bias + SiLU, in place (bf16)
// ---------------------------------------------------------------------------
__global__ void conv_silu(ushort* __restrict__ proj, const ushort* __restrict__ side,
                          const float* __restrict__ cw, const float* __restrict__ cb) {
  int idx = blockIdx.x * 256 + threadIdx.x;
  const int total = BB * CONV_DIM * NCH;
  if (idx >= total) return;
  int c = idx % CONV_DIM;
  int t = idx / CONV_DIM;
  int chunk = t % NCH;
  int b = t / NCH;
  float w0 = cw[c * 4 + 0], w1 = cw[c * 4 + 1], w2 = cw[c * 4 + 2], w3 = cw[c * 4 + 3];
  float bias = cb[c];
  const ushort* sd = side + ((size_t)(b * NCH + chunk) * 3) * CONV_DIM;
  float xm1 = b2f(sd[c]);
  float xm2 = b2f(sd[CONV_DIM + c]);
  float xm3 = b2f(sd[2 * CONV_DIM + c]);
  size_t p = ((size_t)b * SS + (size_t)chunk * CHUNK) * PROJ + COL_HS + c;
  for (int s = 0; s < CHUNK; s++) {
    float xin = b2f(proj[p]);
    float o = w3 * xin + w2 * xm1 + w1 * xm2 + w0 * xm3 + bias;
    o = o / (1.f + __expf(-o));      // SiLU
    proj[p] = f2b(o);
    xm3 = xm2; xm2 = xm1; xm1 = xin;
    p += PROJ;
  }
}

// ---------------------------------------------------------------------------
// SSD K1: per (b,h,chunk): softplus(dt) [fp32 sidecar], cumsum, chunk state.
// states written TRANSPOSED: [d=64][n=128]
// ---------------------------------------------------------------------------
__global__ __launch_bounds__(256) void ssd_chunk_state(
    const ushort* __restrict__ proj, const float* __restrict__ dtf,
    const float* __restrict__ dt_bias, const float* __restrict__ A_log,
    ushort* __restrict__ states, float* __restrict__ cumbuf,
    float* __restrict__ dtvbuf) {
  const int bid = blockIdx.x;
  const int c = bid & 15;
  const int h = (bid >> 4) & 63;
  const int b = bid >> 10;
  const int tid = threadIdx.x;
  const int lane = tid & 63;
  const int wv = tid >> 6;
  __shared__ float sdtv[CL], scum[CL], sw[CL];
  __shared__ ushort sBt[128 * 128];   // [n][t]
  __shared__ ushort sXw[64 * 128];    // [d][t] scaled
  const size_t row0 = (size_t)b * SS + (size_t)c * CL;
  const size_t bh = (size_t)(b * NH + h);

  const float Ah = -__expf(A_log[h]);
  if (tid < CL) {
    float z = dtf[(row0 + tid) * 64 + h] + dt_bias[h];
    float dtv = (z > 20.f) ? z : log1pf(__expf(z));
    sdtv[tid] = dtv;
    sw[tid] = dtv * Ah;
  }
  __syncthreads();
  for (int off = 1; off < CL; off <<= 1) {
    float v = 0.f;
    if (tid < CL) { v = sw[tid]; if (tid >= off) v += sw[tid - off]; }
    __syncthreads();
    if (tid < CL) sw[tid] = v;
    __syncthreads();
  }
  if (tid < CL) {
    scum[tid] = sw[tid];
    cumbuf[bh * SS + c * CL + tid] = sw[tid];
    dtvbuf[bh * SS + c * CL + tid] = sdtv[tid];
  }
  __syncthreads();
  const float cumL = scum[CL - 1];
  if (tid < CL) sw[tid] = __expf(cumL - scum[tid]) * sdtv[tid];
  __syncthreads();

  // stage B^T [n][t]
  {
    const int t = tid >> 1, n0 = (tid & 1) * 64;
    const ushort* src = proj + (row0 + t) * PROJ + COL_B + n0;
#pragma unroll
    for (int j = 0; j < 64; j += 8) {
      s16x8 v = *(const s16x8*)(src + j);
#pragma unroll
      for (int e = 0; e < 8; e++) sBt[swz(n0 + j + e, t)] = (ushort)v[e];
    }
  }
  // stage Xw^T [d][t] scaled by sw[t]
  {
    const int d = tid & 63;
    const int t0 = (tid >> 6) * 32;
    for (int t = t0; t < t0 + 32; t++) {
      float x = b2f(proj[(row0 + t) * PROJ + COL_HS + h * 64 + d]);
      sXw[swz(d, t)] = f2b(x * sw[t]);
    }
  }
  __syncthreads();

  const int r = lane & 15, kx = lane >> 4;
  f32x4 acc[2][4];
#pragma unroll
  for (int i = 0; i < 2; i++)
#pragma unroll
    for (int j = 0; j < 4; j++) acc[i][j] = (f32x4)0.f;
#pragma unroll
  for (int kk = 0; kk < 4; kk++) {
    s16x8 a[2], bo[4];
#pragma unroll
    for (int i = 0; i < 2; i++)
      a[i] = *(const s16x8*)&sBt[swz(wv * 32 + i * 16 + r, kk * 32 + kx * 8)];
#pragma unroll
    for (int j = 0; j < 4; j++)
      bo[j] = *(const s16x8*)&sXw[swz(j * 16 + r, kk * 32 + kx * 8)];
#pragma unroll
    for (int i = 0; i < 2; i++)
#pragma unroll
      for (int j = 0; j < 4; j++)
        acc[i][j] = __builtin_amdgcn_mfma_f32_16x16x32_bf16(a[i], bo[j], acc[i][j], 0, 0, 0);
  }
  ushort* dst = states + (size_t)bid * (128 * 64);
#pragma unroll
  for (int i = 0; i < 2; i++) {
#pragma unroll
    for (int j = 0; j < 4; j++) {
      int n = wv * 32 + i * 16 + (lane >> 4) * 4;
      int d = (lane & 15) + j * 16;
      ushort4 o;
      o.x = f2b(acc[i][j][0]);
      o.y = f2b(acc[i][j][1]);
      o.z = f2b(acc[i][j][2]);
      o.w = f2b(acc[i][j][3]);
      *(ushort4*)(dst + (size_t)d * 128 + n) = o;
    }
  }
}

// ---------------------------------------------------------------------------
// SSD K2: inter-chunk recurrence
// ---------------------------------------------------------------------------
__global__ __launch_bounds__(256) void ssd_state_scan(
    ushort* __restrict__ states, const float* __restrict__ cumbuf) {
  const int bh = blockIdx.x;
  const int tid = threadIdx.x;
  float run[32];
#pragma unroll
  for (int i = 0; i < 32; i++) run[i] = 0.f;
  for (int c = 0; c < NCHK; c++) {
    float dec = __expf(cumbuf[(size_t)bh * SS + c * CL + (CL - 1)]);
    ushort* p = states + ((size_t)bh * NCHK + c) * 8192 + tid * 32;
    s16x8 in[4];
#pragma unroll
    for (int v = 0; v < 4; v++) in[v] = *(const s16x8*)(p + v * 8);
    s16x8 out[4];
#pragma unroll
    for (int v = 0; v < 4; v++) {
#pragma unroll
      for (int e = 0; e < 8; e++) {
        int i = v * 8 + e;
        out[v][e] = (short)f2b(run[i]);
        run[i] = dec * run[i] + b2f((ushort)in[v][e]);
      }
    }
#pragma unroll
    for (int v = 0; v < 4; v++) *(s16x8*)(p + v * 8) = out[v];
  }
}

// ---------------------------------------------------------------------------
// SSD K3: per (b,h,chunk) fused output. LDS = 80KB -> 2 blocks/CU.
// ---------------------------------------------------------------------------
__global__ __launch_bounds__(256, 2) void ssd_chunk_out(
    ushort* __restrict__ proj, const ushort* __restrict__ states,
    const float* __restrict__ cumbuf, const float* __restrict__ dtvbuf,
    const float* __restrict__ Dp) {
  const int bid = blockIdx.x;
  const int c = bid & 15;
  const int h = (bid >> 4) & 63;
  const int b = bid >> 10;
  const int tid = threadIdx.x;
  const int lane = tid & 63;
  const int wv = tid >> 6;
  __shared__ ushort sC[128 * 128];
  __shared__ ushort sB[128 * 128];
  __shared__ ushort sX[64 * 128];
  const size_t row0 = (size_t)b * SS + (size_t)c * CL;
  const size_t bh = (size_t)(b * NH + h);
  const float* cumb = cumbuf + bh * SS + c * CL;
  const float* dtvb = dtvbuf + bh * SS + c * CL;
  const int r = lane & 15, kx = lane >> 4;

  float ct[2][4];
#pragma unroll
  for (int i = 0; i < 2; i++)
#pragma unroll
    for (int q = 0; q < 4; q++)
      ct[i][q] = cumb[wv * 32 + i * 16 + ((lane >> 4) << 2) + q];
  float cumt[8], dvt[8];
#pragma unroll
  for (int j = 0; j < 8; j++) {
    int tau = j * 16 + (lane & 15);
    cumt[j] = cumb[tau];
    dvt[j] = dtvb[tau];
  }
  const float eC = __expf(cumb[wv * 32 + (lane >> 1)]);

  // stage C and B natural [t][n]  (pure bf16 copies)
  {
    const int t = tid >> 1, n0 = (tid & 1) * 64;
    const ushort* srcC = proj + (row0 + t) * PROJ + COL_C + n0;
    const ushort* srcB = proj + (row0 + t) * PROJ + COL_B + n0;
#pragma unroll
    for (int j = 0; j < 64; j += 8) {
      *(s16x8*)&sC[swz(t, n0 + j)] = *(const s16x8*)(srcC + j);
      *(s16x8*)&sB[swz(t, n0 + j)] = *(const s16x8*)(srcB + j);
    }
  }
  // stage X^T [d][t]
  {
    const int d = tid & 63;
    const int t0 = (tid >> 6) * 32;
    for (int t = t0; t < t0 + 32; t++)
      sX[swz(d, t)] = proj[(row0 + t) * PROJ + COL_HS + h * 64 + d];
  }
  __syncthreads();

  f32x4 g[2][8];
#pragma unroll
  for (int i = 0; i < 2; i++)
#pragma unroll
    for (int j = 0; j < 8; j++) g[i][j] = (f32x4)0.f;
#pragma unroll
  for (int kk = 0; kk < 4; kk++) {
    s16x8 a[2], bo[8];
#pragma unroll
    for (int i = 0; i < 2; i++)
      a[i] = *(const s16x8*)&sC[swz(wv * 32 + i * 16 + r, kk * 32 + kx * 8)];
#pragma unroll
    for (int j = 0; j < 8; j++)
      bo[j] = *(const s16x8*)&sB[swz(j * 16 + r, kk * 32 + kx * 8)];
#pragma unroll
    for (int i = 0; i < 2; i++)
#pragma unroll
      for (int j = 0; j < 8; j++)
        g[i][j] = __builtin_amdgcn_mfma_f32_16x16x32_bf16(a[i], bo[j], g[i][j], 0, 0, 0);
  }

  s16x8 spf[4][4];
  {
    const ushort* sp = states + (size_t)bid * 8192;
#pragma unroll
    for (int kk = 0; kk < 4; kk++)
#pragma unroll
      for (int j = 0; j < 4; j++)
        spf[kk][j] = *(const s16x8*)(sp + (size_t)(j * 16 + r) * 128 + kk * 32 + kx * 8);
  }
  __syncthreads();

#pragma unroll
  for (int j = 0; j < 8; j++) {
    float cu = cumt[j], dv = dvt[j];
    int tau = j * 16 + (lane & 15);
#pragma unroll
    for (int i = 0; i < 2; i++) {
#pragma unroll
      for (int q = 0; q < 4; q++) {
        int t = wv * 32 + i * 16 + ((lane >> 4) << 2) + q;
        float val = (tau <= t) ? g[i][j][q] * __expf(ct[i][q] - cu) * dv : 0.f;
        sB[swz(t, tau)] = f2b(val);
      }
    }
  }
  {
    int t = wv * 32 + (lane >> 1);
    int n0 = (lane & 1) * 64;
#pragma unroll
    for (int j = 0; j < 64; j += 8) {
      s16x8 u = *(const s16x8*)&sC[swz(t, n0 + j)];
#pragma unroll
      for (int k = 0; k < 8; k++) u[k] = (short)f2b(b2f((ushort)u[k]) * eC);
      *(s16x8*)&sC[swz(t, n0 + j)] = u;
    }
  }
  __syncthreads();

  f32x4 y[2][4];
#pragma unroll
  for (int i = 0; i < 2; i++)
#pragma unroll
    for (int j = 0; j < 4; j++) y[i][j] = (f32x4)0.f;
#pragma unroll
  for (int kk = 0; kk < 4; kk++) {
    s16x8 a[2], bo[4];
#pragma unroll
    for (int i = 0; i < 2; i++)
      a[i] = *(const s16x8*)&sB[swz(wv * 32 + i * 16 + r, kk * 32 + kx * 8)];
#pragma unroll
    for (int j = 0; j < 4; j++)
      bo[j] = *(const s16x8*)&sX[swz(j * 16 + r, kk * 32 + kx * 8)];
#pragma unroll
    for (int i = 0; i < 2; i++)
#pragma unroll
      for (int j = 0; j < 4; j++)
        y[i][j] = __builtin_amdgcn_mfma_f32_16x16x32_bf16(a[i], bo[j], y[i][j], 0, 0, 0);
  }
#pragma unroll
  for (int kk = 0; kk < 4; kk++) {
    s16x8 a[2];
#pragma unroll
    for (int i = 0; i < 2; i++)
      a[i] = *(const s16x8*)&sC[swz(wv * 32 + i * 16 + r, kk * 32 + kx * 8)];
#pragma unroll
    for (int i = 0; i < 2; i++)
#pragma unroll
      for (int j = 0; j < 4; j++)
        y[i][j] = __builtin_amdgcn_mfma_f32_16x16x32_bf16(a[i], spf[kk][j], y[i][j], 0, 0, 0);
  }

  const float Dh = Dp[h];
#pragma unroll
  for (int i = 0; i < 2; i++) {
#pragma unroll
    for (int j = 0; j < 4; j++) {
      int t0 = wv * 32 + i * 16 + (lane >> 4) * 4;
      int d = (lane & 15) + j * 16;
#pragma unroll
      for (int q = 0; q < 4; q++) {
        float x = b2f(sX[swz(d, t0 + q)]);
        proj[(row0 + t0 + q) * PROJ + COL_HS + h * 64 + d] = f2b(y[i][j][q] + Dh * x);
      }
    }
  }
}

// ---------------------------------------------------------------------------
// Gated RMSNorm, bf16 in / bf16 in-place out over proj hs columns
// ---------------------------------------------------------------------------
__global__ __launch_bounds__(256) void rmsnorm_kernel(
    ushort* __restrict__ proj, const float* __restrict__ nw) {
  const int row = blockIdx.x;
  const int tid = threadIdx.x;
  ushort* yp = proj + (size_t)row * PROJ + COL_HS;
  const ushort* gp = proj + (size_t)row * PROJ;
  float v[16];
  float ss = 0.f;
#pragma unroll
  for (int q = 0; q < 4; q++) {
    int col = q * 1024 + tid * 4;
    ushort4 yv = *(const ushort4*)(yp + col);
    ushort4 gv = *(const ushort4*)(gp + col);
    float vy[4] = {b2f(yv.x), b2f(yv.y), b2f(yv.z), b2f(yv.w)};
    float vg[4] = {b2f(gv.x), b2f(gv.y), b2f(gv.z), b2f(gv.w)};
#pragma unroll
    for (int j = 0; j < 4; j++) {
      float sg = vg[j] / (1.f + __expf(-vg[j]));
      float vv = vy[j] * sg;
      v[q * 4 + j] = vv;
      ss += vv * vv;
    }
  }
#pragma unroll
  for (int o = 1; o < 64; o <<= 1) ss += __shfl_xor(ss, o);
  __shared__ float red[4];
  if ((tid & 63) == 0) red[tid >> 6] = ss;
  __syncthreads();
  float tot = red[0] + red[1] + red[2] + red[3];
  float scale = rsqrtf(tot * (1.f / INTER) + EPS);
#pragma unroll
  for (int q = 0; q < 4; q++) {
    int col = q * 1024 + tid * 4;
    float4 w = *(const float4*)(nw + col);
    ushort4 o;
    o.x = f2b(v[q * 4 + 0] * scale * w.x);
    o.y = f2b(v[q * 4 + 1] * scale * w.y);
    o.z = f2b(v[q * 4 + 2] * scale * w.z);
    o.w = f2b(v[q * 4 + 3] * scale * w.w);
    *(ushort4*)(yp + col) = o;
  }
}

// ---------------------------------------------------------------------------
extern "C" void kernel_launch(void* const* d_in, const int* in_sizes, int n_in,
                              void* d_out, int out_size, void* d_ws, size_t ws_size,
                              hipStream_t stream) {
  const float* hs   = (const float*)d_in[0];
  const float* w1   = (const float*)d_in[1];
  const float* cw   = (const float*)d_in[2];
  const float* cb   = (const float*)d_in[3];
  const float* dtb  = (const float*)d_in[4];
  const float* alog = (const float*)d_in[5];
  const float* Dp   = (const float*)d_in[6];
  const float* nw   = (const float*)d_in[7];
  const float* w2   = (const float*)d_in[8];
  float* out = (float*)d_out;

  // ws layout
  char* base = (char*)d_ws;
  size_t off = 0;
  ushort* proj = (ushort*)(base + off); off += (size_t)BS * PROJ * 2;          // 69.7 MB
  ushort* side = (ushort*)(base + off); off += (size_t)BB * NCH * 3 * CONV_DIM * 2;
  off = (off + 255) & ~(size_t)255;
  float* dtbuf = (float*)(base + off); off += (size_t)BS * 64 * 4;             // 1.05 MB
  off = (off + 255) & ~(size_t)255;
  char* rC = base + off;
  // phase 1 tenants:
  ushort* hs16 = (ushort*)rC;                                 // 16.78 MB
  ushort* w1p  = (ushort*)(rC + 16777216);                    // 35.65 MB (8704x2048)
  // phase 2 tenants (after GEMM1; hs16/w1p dead):
  ushort* states = (ushort*)rC;                               // 33.55 MB
  float*  cumbuf = (float*)(rC + 33554432);                   // 1.05 MB
  float*  dtvbuf = (float*)(rC + 33554432 + 1048576);         // 1.05 MB
  // phase 3 tenants (after K3; states/cum dead):
  ushort* w216 = (ushort*)rC;                                 // 16.78 MB

  // 0) fp32 -> bf16 conversions for GEMM1
  {
    long n4 = (long)BS * HID / 4;
    to_bf16<<<(n4 + 255) / 256, 256, 0, stream>>>(hs, hs16, n4);
  }
  {
    long n4 = (long)PROJ_PAD * HID / 4;
    to_bf16_pad<<<(n4 + 255) / 256, 256, 0, stream>>>(w1, w1p, n4);
  }

  // 1) in_proj GEMM (8-phase 256^2): proj(bf16) = hs @ w1^T ; dt fp32 sidecar
  gemm256_8ph<<<(BS / 256) * (PROJ_PAD / 256), 512, 0, stream>>>(hs16, w1p, proj, dtbuf);

  // 2) causal depthwise conv + SiLU (in place, bf16)
  conv_capture<<<(BB * CONV_DIM * NCH * 3 + 255) / 256, 256, 0, stream>>>(proj, side);
  conv_silu<<<(BB * CONV_DIM * NCH + 255) / 256, 256, 0, stream>>>(proj, side, cw, cb);

  // 3) SSD chunked scan
  ssd_chunk_state<<<BB * NH * NCHK, 256, 0, stream>>>(proj, dtbuf, dtb, alog, states, cumbuf, dtvbuf);
  ssd_state_scan<<<BB * NH, 256, 0, stream>>>(states, cumbuf);
  ssd_chunk_out<<<BB * NH * NCHK, 256, 0, stream>>>(proj, states, cumbuf, dtvbuf, Dp);

  // 4) w2 conversion (after SSD so it can reuse region C)
  {
    long n4 = (long)HID * INTER / 4;
    to_bf16<<<(n4 + 255) / 256, 256, 0, stream>>>(w2, w216, n4);
  }

  // 5) gated RMSNorm (in place over proj hs columns)
  rmsnorm_kernel<<<BS, 256, 0, stream>>>(proj, nw);

  // 6) out_proj GEMM (256x128 pipelined, 256 blocks = exact 1 round)
  gemm2_256x128<<<256, 512, 0, stream>>>(
      (const ushort*)(proj + COL_HS), w216, out);
}

// Round 9
// 440.105 us; speedup vs baseline: 10.4682x; 1.0028x over previous
//
#include <hip/hip_runtime.h>
#include <hip/hip_bf16.h>
#include <cstddef>
#include <cstdint>

// Problem constants
#define HID   2048
#define INTER 4096
#define NH    64
#define HD    64
#define NST   128
#define CONV_DIM 4352           // INTER + 2*NST
#define PROJ  8512              // INTER + CONV_DIM + NH
#define PROJ_PAD 8704           // 68 * 128
#define SS    2048
#define BB    2
#define BS    (BB*SS)           // 4096 rows
#define EPS   1e-5f

// proj column layout: [0,4096)=gate [4096,8192)=hs [8192,8320)=B [8320,8448)=C [8448,8512)=dt
#define COL_HS 4096
#define COL_B  8192
#define COL_C  8320
#define COL_DT 8448

// conv chunking (finer than SSD for occupancy)
#define NCHC  64
#define CHUNKC 32               // SS / NCHC
#define CV8   (CONV_DIM / 8)    // 544

// SSD chunking
#define CL    128               // chunk length
#define NCHK  16                // SS / CL

typedef short s16x8 __attribute__((ext_vector_type(8)));
typedef float f32x4 __attribute__((ext_vector_type(4)));

__device__ inline ushort f2b(float x) {
  __hip_bfloat16 h = __float2bfloat16(x);
  return *(ushort*)&h;
}
__device__ inline float b2f(ushort u) {
  unsigned int v = ((unsigned int)u) << 16;
  return __uint_as_float(v);
}
// LDS tile: 256B rows (128 bf16), XOR-swizzled in 8-elem slots (T2)
__device__ inline int swz(int row, int e) { return row * 128 + (e ^ ((row & 7) << 3)); }

__device__ inline void gload16(const void* g, void* l) {
  __builtin_amdgcn_global_load_lds((const __attribute__((address_space(1))) void*)g,
                                   (__attribute__((address_space(3))) void*)l, 16, 0, 0);
}

// ---------------------------------------------------------------------------
// Merged fp32 -> bf16 conversion: hs | w1 (padded to 8704 rows) | w2
// ---------------------------------------------------------------------------
#define N4A  ((long)BS * HID / 4)
#define N4W1 ((long)PROJ_PAD * HID / 4)
#define N4W2 ((long)HID * INTER / 4)

__global__ __launch_bounds__(256) void convert_all(
    const float* __restrict__ hs, const float* __restrict__ w1,
    const float* __restrict__ w2, ushort* __restrict__ hs16,
    ushort* __restrict__ w1p, ushort* __restrict__ w216) {
  long i = (long)blockIdx.x * 256 + threadIdx.x;
  const float* src;
  ushort* dst;
  long e0;
  if (i < N4A) {
    src = hs; dst = hs16; e0 = i * 4;
  } else if (i < N4A + N4W1) {
    long k = i - N4A;
    e0 = k * 4;
    long row = e0 >> 11;  // / 2048
    if (row >= PROJ) {
      ushort4 z = {0, 0, 0, 0};
      *(ushort4*)(w1p + e0) = z;
      return;
    }
    src = w1; dst = w1p;
  } else if (i < N4A + N4W1 + N4W2) {
    long k = i - N4A - N4W1;
    src = w2; dst = w216; e0 = k * 4;
  } else {
    return;
  }
  float4 v = *(const float4*)(src + e0);
  ushort4 o;
  o.x = f2b(v.x); o.y = f2b(v.y); o.z = f2b(v.z); o.w = f2b(v.w);
  *(ushort4*)(dst + e0) = o;
}

// ---------------------------------------------------------------------------
// GEMM1: 256x128-tile pipelined bf16 MFMA GEMM (r8-proven gemm2 structure).
// A = hs16 [4096][2048], Bw = w1p [8704][2048] -> proj bf16 [4096][8512]
// (+ fp32 dt sidecar). Grid 1088 blocks (16 rows x 68 cols), 85% packing.
// Remap: row-groups of 4 (4 row-tiles x 68 cols per group, bijective).
// ---------------------------------------------------------------------------
__global__ __launch_bounds__(512, 2) void gemm1_256x128(
    const ushort* __restrict__ A, const ushort* __restrict__ Bw,
    ushort* __restrict__ C, float* __restrict__ dtbuf) {
  __shared__ ushort smem[49152];   // A: 2x16384, B (at 32768): 2x8192
  const int tid = threadIdx.x;
  const int lane = tid & 63;
  const int wid = tid >> 6;
  const int wm = wid >> 1;         // 0..3
  const int wn = wid & 1;          // 0..1
  const int r = lane & 15;
  const int kx = lane >> 4;        // 0..3

  // remap: group = 4 row-tiles x 68 cols = 272 blocks
  const int fid = blockIdx.x;      // 0..1087
  const int rg = fid / 272;        // 0..3
  const int ix = fid % 272;
  const int brow = rg * 4 + (ix & 3);   // 0..15
  const int bcol = ix >> 2;             // 0..67

  const ushort* Ag = A + (size_t)(brow * 256) * HID;
  const ushort* Bg = Bw + (size_t)(bcol * 128) * HID;

  // contiguous staging map: thread -> (row srow in 64-row batch, 16B slot tid&7)
  const int srow = tid >> 3;                 // 0..63
  const int scole = (((tid & 7) * 16) ^ ((srow & 7) << 4)) >> 1;

  auto stageA1 = [&](int buf, int kt) {
#pragma unroll
    for (int i = 0; i < 4; i++) {
      gload16(Ag + (size_t)(i * 64 + srow) * HID + kt * 64 + scole,
              smem + buf * 16384 + i * 4096 + tid * 8);
    }
  };
  auto stageB1 = [&](int buf, int kt) {
#pragma unroll
    for (int i = 0; i < 2; i++) {
      gload16(Bg + (size_t)(i * 64 + srow) * HID + kt * 64 + scole,
              smem + 32768 + buf * 8192 + i * 4096 + tid * 8);
    }
  };
  auto ldA1 = [&](int buf, int mf, int ks) -> s16x8 {
    int row = wm * 64 + mf * 16 + r;
    int cb = (ks * 64 + kx * 16) ^ ((row & 7) << 4);
    return *(const s16x8*)(smem + buf * 16384 + row * 64 + (cb >> 1));
  };
  auto ldB1 = [&](int buf, int nf, int ks) -> s16x8 {
    int row = wn * 64 + nf * 16 + r;
    int cb = (ks * 64 + kx * 16) ^ ((row & 7) << 4);
    return *(const s16x8*)(smem + 32768 + buf * 8192 + row * 64 + (cb >> 1));
  };

  f32x4 acc[4][4];
#pragma unroll
  for (int i = 0; i < 4; i++)
#pragma unroll
    for (int j = 0; j < 4; j++) acc[i][j] = (f32x4)0.f;

  constexpr int NT = HID / 64;   // 32 K-tiles

  // prologue: tile0 -> buf0, tile1 -> buf1 (6 loads each); wait tile0
  stageA1(0, 0); stageB1(0, 0);
  stageA1(1, 1); stageB1(1, 1);
  asm volatile("s_waitcnt vmcnt(6)" ::: "memory");
  __builtin_amdgcn_s_barrier();

  int cur = 0;
  for (int t = 0; t < NT; t++) {
    s16x8 a[4][2], b[4][2];
    // ---------- phase 1: read ALL frags; MFMA nf0-1
#pragma unroll
    for (int mf = 0; mf < 4; mf++)
#pragma unroll
      for (int ks = 0; ks < 2; ks++) a[mf][ks] = ldA1(cur, mf, ks);
#pragma unroll
    for (int nf = 0; nf < 4; nf++)
#pragma unroll
      for (int ks = 0; ks < 2; ks++) b[nf][ks] = ldB1(cur, nf, ks);
    __builtin_amdgcn_s_barrier();
    asm volatile("s_waitcnt lgkmcnt(0)" ::: "memory");
    __builtin_amdgcn_sched_barrier(0);
    __builtin_amdgcn_s_setprio(1);
#pragma unroll
    for (int mf = 0; mf < 4; mf++)
#pragma unroll
      for (int nf = 0; nf < 2; nf++)
#pragma unroll
        for (int ks = 0; ks < 2; ks++)
          acc[mf][nf] = __builtin_amdgcn_mfma_f32_16x16x32_bf16(a[mf][ks], b[nf][ks], acc[mf][nf], 0, 0, 0);
    __builtin_amdgcn_s_setprio(0);
    __builtin_amdgcn_s_barrier();
    // ---------- phase 2: stage t+2 into cur (all reads drained); MFMA nf2-3
    if (t + 2 < NT) { stageA1(cur, t + 2); stageB1(cur, t + 2); }
    __builtin_amdgcn_s_setprio(1);
#pragma unroll
    for (int mf = 0; mf < 4; mf++)
#pragma unroll
      for (int nf = 2; nf < 4; nf++)
#pragma unroll
        for (int ks = 0; ks < 2; ks++)
          acc[mf][nf] = __builtin_amdgcn_mfma_f32_16x16x32_bf16(a[mf][ks], b[nf][ks], acc[mf][nf], 0, 0, 0);
    __builtin_amdgcn_s_setprio(0);
    if (t + 2 < NT) {
      asm volatile("s_waitcnt vmcnt(6)" ::: "memory");
    } else {
      asm volatile("s_waitcnt vmcnt(0)" ::: "memory");
    }
    __builtin_amdgcn_s_barrier();
    cur ^= 1;
  }

  // epilogue: bf16 proj store + fp32 dt sidecar (guard n < PROJ)
  const int m0 = brow * 256 + wm * 64 + (lane >> 4) * 4;
  const int n0 = bcol * 128 + wn * 64 + r;
#pragma unroll
  for (int mf = 0; mf < 4; mf++) {
#pragma unroll
    for (int nf = 0; nf < 4; nf++) {
      int n = n0 + nf * 16;
      if (n >= PROJ) continue;
#pragma unroll
      for (int q = 0; q < 4; q++) {
        float v = acc[mf][nf][q];
        int m = m0 + mf * 16 + q;
        C[(size_t)m * PROJ + n] = f2b(v);
        if (n >= COL_DT) dtbuf[(size_t)m * 64 + (n - COL_DT)] = v;
      }
    }
  }
}

// ---------------------------------------------------------------------------
// GEMM2: 256x128-tile pipelined bf16 MFMA GEMM (unchanged from r8, proven).
// A = proj+COL_HS (lda=PROJ), Bw = w216 [2048][4096], C fp32 [4096][2048].
// ---------------------------------------------------------------------------
__global__ __launch_bounds__(512, 2) void gemm2_256x128(
    const ushort* __restrict__ A, const ushort* __restrict__ Bw,
    float* __restrict__ C) {
  __shared__ ushort smem[49152];
  const int tid = threadIdx.x;
  const int lane = tid & 63;
  const int wid = tid >> 6;
  const int wm = wid >> 1;
  const int wn = wid & 1;
  const int r = lane & 15;
  const int kx = lane >> 4;

  const int fid = blockIdx.x;      // 256 blocks
  const int bcol = fid >> 4;
  const int brow = fid & 15;

  const ushort* Ag = A + (size_t)(brow * 256) * PROJ;
  const ushort* Bg = Bw + (size_t)(bcol * 128) * INTER;

  const int srow = tid >> 3;
  const int scole = (((tid & 7) * 16) ^ ((srow & 7) << 4)) >> 1;

  auto stageA2 = [&](int buf, int kt) {
#pragma unroll
    for (int i = 0; i < 4; i++) {
      gload16(Ag + (size_t)(i * 64 + srow) * PROJ + kt * 64 + scole,
              smem + buf * 16384 + i * 4096 + tid * 8);
    }
  };
  auto stageB2 = [&](int buf, int kt) {
#pragma unroll
    for (int i = 0; i < 2; i++) {
      gload16(Bg + (size_t)(i * 64 + srow) * INTER + kt * 64 + scole,
              smem + 32768 + buf * 8192 + i * 4096 + tid * 8);
    }
  };
  auto ldA2 = [&](int buf, int mf, int ks) -> s16x8 {
    int row = wm * 64 + mf * 16 + r;
    int cb = (ks * 64 + kx * 16) ^ ((row & 7) << 4);
    return *(const s16x8*)(smem + buf * 16384 + row * 64 + (cb >> 1));
  };
  auto ldB2 = [&](int buf, int nf, int ks) -> s16x8 {
    int row = wn * 64 + nf * 16 + r;
    int cb = (ks * 64 + kx * 16) ^ ((row & 7) << 4);
    return *(const s16x8*)(smem + 32768 + buf * 8192 + row * 64 + (cb >> 1));
  };

  f32x4 acc[4][4];
#pragma unroll
  for (int i = 0; i < 4; i++)
#pragma unroll
    for (int j = 0; j < 4; j++) acc[i][j] = (f32x4)0.f;

  constexpr int NT = INTER / 64;   // 64 K-tiles

  stageA2(0, 0); stageB2(0, 0);
  stageA2(1, 1); stageB2(1, 1);
  asm volatile("s_waitcnt vmcnt(6)" ::: "memory");
  __builtin_amdgcn_s_barrier();

  int cur = 0;
  for (int t = 0; t < NT; t++) {
    s16x8 a[4][2], b[4][2];
#pragma unroll
    for (int mf = 0; mf < 4; mf++)
#pragma unroll
      for (int ks = 0; ks < 2; ks++) a[mf][ks] = ldA2(cur, mf, ks);
#pragma unroll
    for (int nf = 0; nf < 4; nf++)
#pragma unroll
      for (int ks = 0; ks < 2; ks++) b[nf][ks] = ldB2(cur, nf, ks);
    __builtin_amdgcn_s_barrier();
    asm volatile("s_waitcnt lgkmcnt(0)" ::: "memory");
    __builtin_amdgcn_sched_barrier(0);
    __builtin_amdgcn_s_setprio(1);
#pragma unroll
    for (int mf = 0; mf < 4; mf++)
#pragma unroll
      for (int nf = 0; nf < 2; nf++)
#pragma unroll
        for (int ks = 0; ks < 2; ks++)
          acc[mf][nf] = __builtin_amdgcn_mfma_f32_16x16x32_bf16(a[mf][ks], b[nf][ks], acc[mf][nf], 0, 0, 0);
    __builtin_amdgcn_s_setprio(0);
    __builtin_amdgcn_s_barrier();
    if (t + 2 < NT) { stageA2(cur, t + 2); stageB2(cur, t + 2); }
    __builtin_amdgcn_s_setprio(1);
#pragma unroll
    for (int mf = 0; mf < 4; mf++)
#pragma unroll
      for (int nf = 2; nf < 4; nf++)
#pragma unroll
        for (int ks = 0; ks < 2; ks++)
          acc[mf][nf] = __builtin_amdgcn_mfma_f32_16x16x32_bf16(a[mf][ks], b[nf][ks], acc[mf][nf], 0, 0, 0);
    __builtin_amdgcn_s_setprio(0);
    if (t + 2 < NT) {
      asm volatile("s_waitcnt vmcnt(6)" ::: "memory");
    } else {
      asm volatile("s_waitcnt vmcnt(0)" ::: "memory");
    }
    __builtin_amdgcn_s_barrier();
    cur ^= 1;
  }

  const int m0 = brow * 256 + wm * 64 + (lane >> 4) * 4;
  const int n0 = bcol * 128 + wn * 64 + r;
#pragma unroll
  for (int mf = 0; mf < 4; mf++) {
#pragma unroll
    for (int nf = 0; nf < 4; nf++) {
      int n = n0 + nf * 16;
#pragma unroll
      for (int q = 0; q < 4; q++)
        C[(size_t)(m0 + mf * 16 + q) * HID + n] = acc[mf][nf][q];
    }
  }
}

// ---------------------------------------------------------------------------
// Conv boundary capture (bf16, 8-wide, fine chunks)
// ---------------------------------------------------------------------------
__global__ __launch_bounds__(256) void conv_capture(
    const ushort* __restrict__ proj, ushort* __restrict__ side) {
  int idx = blockIdx.x * 256 + threadIdx.x;
  const int total = BB * NCHC * 3 * CV8;
  if (idx >= total) return;
  int c8 = idx % CV8;
  int t = idx / CV8;
  int j = t % 3; t /= 3;
  int chunk = t % NCHC;
  int b = t / NCHC;
  int s = chunk * CHUNKC - 1 - j;
  s16x8 v = {0, 0, 0, 0, 0, 0, 0, 0};
  if (s >= 0) v = *(const s16x8*)(proj + ((size_t)b * SS + s) * PROJ + COL_HS + c8 * 8);
  *(s16x8*)(side + ((size_t)(b * NCHC + chunk) * 3 + j) * CONV_DIM + c8 * 8) = v;
}

// ---------------------------------------------------------------------------
// Causal depthwise conv1d (K=4) + bias + SiLU, in place, 8 channels/thread
// ---------------------------------------------------------------------------
__global__ __launch_bounds__(256) void conv_silu(
    ushort* __restrict__ proj, const ushort* __restrict__ side,
    const float* __restrict__ cw, const float* __restrict__ cb) {
  int idx = blockIdx.x * 256 + threadIdx.x;
  const int total = BB * NCHC * CV8;
  if (idx >= total) return;
  int c8 = idx % CV8;
  int t = idx / CV8;
  int chunk = t % NCHC;
  int b = t / NCHC;
  const int c0 = c8 * 8;
  float w0[8], w1[8], w2[8], w3[8], bias[8], h1[8], h2[8], h3[8];
#pragma unroll
  for (int e = 0; e < 8; e++) {
    float4 wv = *(const float4*)(cw + (c0 + e) * 4);
    w0[e] = wv.x; w1[e] = wv.y; w2[e] = wv.z; w3[e] = wv.w;
    bias[e] = cb[c0 + e];
  }
  const ushort* sd = side + (size_t)(b * NCHC + chunk) * 3 * CONV_DIM;
  {
    s16x8 v1 = *(const s16x8*)(sd + c0);
    s16x8 v2 = *(const s16x8*)(sd + CONV_DIM + c0);
    s16x8 v3 = *(const s16x8*)(sd + 2 * CONV_DIM + c0);
#pragma unroll
    for (int e = 0; e < 8; e++) {
      h1[e] = b2f((ushort)v1[e]);
      h2[e] = b2f((ushort)v2[e]);
      h3[e] = b2f((ushort)v3[e]);
    }
  }
  size_t p = ((size_t)b * SS + (size_t)chunk * CHUNKC) * PROJ + COL_HS + c0;
  for (int s = 0; s < CHUNKC; s++) {
    s16x8 xv = *(const s16x8*)(proj + p);
    s16x8 ov;
#pragma unroll
    for (int e = 0; e < 8; e++) {
      float x = b2f((ushort)xv[e]);
      float o = w3[e] * x + w2[e] * h1[e] + w1[e] * h2[e] + w0[e] * h3[e] + bias[e];
      o = o / (1.f + __expf(-o));    // SiLU
      ov[e] = (short)f2b(o);
      h3[e] = h2[e]; h2[e] = h1[e]; h1[e] = x;
    }
    *(s16x8*)(proj + p) = ov;
    p += PROJ;
  }
}

// ---------------------------------------------------------------------------
// SSD K1: per (b,h,chunk): softplus(dt) [fp32 sidecar], cumsum, chunk state.
// states written TRANSPOSED: [d=64][n=128]
// ---------------------------------------------------------------------------
__global__ __launch_bounds__(256) void ssd_chunk_state(
    const ushort* __restrict__ proj, const float* __restrict__ dtf,
    const float* __restrict__ dt_bias, const float* __restrict__ A_log,
    ushort* __restrict__ states, float* __restrict__ cumbuf,
    float* __restrict__ dtvbuf) {
  const int bid = blockIdx.x;
  const int c = bid & 15;
  const int h = (bid >> 4) & 63;
  const int b = bid >> 10;
  const int tid = threadIdx.x;
  const int lane = tid & 63;
  const int wv = tid >> 6;
  __shared__ float sdtv[CL], scum[CL], sw[CL];
  __shared__ ushort sBt[128 * 128];   // [n][t]
  __shared__ ushort sXw[64 * 128];    // [d][t] scaled
  const size_t row0 = (size_t)b * SS + (size_t)c * CL;
  const size_t bh = (size_t)(b * NH + h);

  const float Ah = -__expf(A_log[h]);
  if (tid < CL) {
    float z = dtf[(row0 + tid) * 64 + h] + dt_bias[h];
    float dtv = (z > 20.f) ? z : log1pf(__expf(z));
    sdtv[tid] = dtv;
    sw[tid] = dtv * Ah;
  }
  __syncthreads();
  for (int off = 1; off < CL; off <<= 1) {
    float v = 0.f;
    if (tid < CL) { v = sw[tid]; if (tid >= off) v += sw[tid - off]; }
    __syncthreads();
    if (tid < CL) sw[tid] = v;
    __syncthreads();
  }
  if (tid < CL) {
    scum[tid] = sw[tid];
    cumbuf[bh * SS + c * CL + tid] = sw[tid];
    dtvbuf[bh * SS + c * CL + tid] = sdtv[tid];
  }
  __syncthreads();
  const float cumL = scum[CL - 1];
  if (tid < CL) sw[tid] = __expf(cumL - scum[tid]) * sdtv[tid];
  __syncthreads();

  // stage B^T [n][t]
  {
    const int t = tid >> 1, n0 = (tid & 1) * 64;
    const ushort* src = proj + (row0 + t) * PROJ + COL_B + n0;
#pragma unroll
    for (int j = 0; j < 64; j += 8) {
      s16x8 v = *(const s16x8*)(src + j);
#pragma unroll
      for (int e = 0; e < 8; e++) sBt[swz(n0 + j + e, t)] = (ushort)v[e];
    }
  }
  // stage Xw^T [d][t] scaled by sw[t]
  {
    const int d = tid & 63;
    const int t0 = (tid >> 6) * 32;
    for (int t = t0; t < t0 + 32; t++) {
      float x = b2f(proj[(row0 + t) * PROJ + COL_HS + h * 64 + d]);
      sXw[swz(d, t)] = f2b(x * sw[t]);
    }
  }
  __syncthreads();

  const int r = lane & 15, kx = lane >> 4;
  f32x4 acc[2][4];
#pragma unroll
  for (int i = 0; i < 2; i++)
#pragma unroll
    for (int j = 0; j < 4; j++) acc[i][j] = (f32x4)0.f;
#pragma unroll
  for (int kk = 0; kk < 4; kk++) {
    s16x8 a[2], bo[4];
#pragma unroll
    for (int i = 0; i < 2; i++)
      a[i] = *(const s16x8*)&sBt[swz(wv * 32 + i * 16 + r, kk * 32 + kx * 8)];
#pragma unroll
    for (int j = 0; j < 4; j++)
      bo[j] = *(const s16x8*)&sXw[swz(j * 16 + r, kk * 32 + kx * 8)];
#pragma unroll
    for (int i = 0; i < 2; i++)
#pragma unroll
      for (int j = 0; j < 4; j++)
        acc[i][j] = __builtin_amdgcn_mfma_f32_16x16x32_bf16(a[i], bo[j], acc[i][j], 0, 0, 0);
  }
  ushort* dst = states + (size_t)bid * (128 * 64);
#pragma unroll
  for (int i = 0; i < 2; i++) {
#pragma unroll
    for (int j = 0; j < 4; j++) {
      int n = wv * 32 + i * 16 + (lane >> 4) * 4;
      int d = (lane & 15) + j * 16;
      ushort4 o;
      o.x = f2b(acc[i][j][0]);
      o.y = f2b(acc[i][j][1]);
      o.z = f2b(acc[i][j][2]);
      o.w = f2b(acc[i][j][3]);
      *(ushort4*)(dst + (size_t)d * 128 + n) = o;
    }
  }
}

// ---------------------------------------------------------------------------
// SSD K2: inter-chunk recurrence
// ---------------------------------------------------------------------------
__global__ __launch_bounds__(256) void ssd_state_scan(
    ushort* __restrict__ states, const float* __restrict__ cumbuf) {
  const int bh = blockIdx.x;
  const int tid = threadIdx.x;
  float run[32];
#pragma unroll
  for (int i = 0; i < 32; i++) run[i] = 0.f;
  for (int c = 0; c < NCHK; c++) {
    float dec = __expf(cumbuf[(size_t)bh * SS + c * CL + (CL - 1)]);
    ushort* p = states + ((size_t)bh * NCHK + c) * 8192 + tid * 32;
    s16x8 in[4];
#pragma unroll
    for (int v = 0; v < 4; v++) in[v] = *(const s16x8*)(p + v * 8);
    s16x8 out[4];
#pragma unroll
    for (int v = 0; v < 4; v++) {
#pragma unroll
      for (int e = 0; e < 8; e++) {
        int i = v * 8 + e;
        out[v][e] = (short)f2b(run[i]);
        run[i] = dec * run[i] + b2f((ushort)in[v][e]);
      }
    }
#pragma unroll
    for (int v = 0; v < 4; v++) *(s16x8*)(p + v * 8) = out[v];
  }
}

// ---------------------------------------------------------------------------
// SSD K3: per (b,h,chunk) fused output. LDS = 80KB -> 2 blocks/CU.
// ---------------------------------------------------------------------------
__global__ __launch_bounds__(256, 2) void ssd_chunk_out(
    ushort* __restrict__ proj, const ushort* __restrict__ states,
    const float* __restrict__ cumbuf, const float* __restrict__ dtvbuf,
    const float* __restrict__ Dp) {
  const int bid = blockIdx.x;
  const int c = bid & 15;
  const int h = (bid >> 4) & 63;
  const int b = bid >> 10;
  const int tid = threadIdx.x;
  const int lane = tid & 63;
  const int wv = tid >> 6;
  __shared__ ushort sC[128 * 128];
  __shared__ ushort sB[128 * 128];
  __shared__ ushort sX[64 * 128];
  const size_t row0 = (size_t)b * SS + (size_t)c * CL;
  const size_t bh = (size_t)(b * NH + h);
  const float* cumb = cumbuf + bh * SS + c * CL;
  const float* dtvb = dtvbuf + bh * SS + c * CL;
  const int r = lane & 15, kx = lane >> 4;

  float ct[2][4];
#pragma unroll
  for (int i = 0; i < 2; i++)
#pragma unroll
    for (int q = 0; q < 4; q++)
      ct[i][q] = cumb[wv * 32 + i * 16 + ((lane >> 4) << 2) + q];
  float cumt[8], dvt[8];
#pragma unroll
  for (int j = 0; j < 8; j++) {
    int tau = j * 16 + (lane & 15);
    cumt[j] = cumb[tau];
    dvt[j] = dtvb[tau];
  }
  const float eC = __expf(cumb[wv * 32 + (lane >> 1)]);

  // stage C and B natural [t][n]  (pure bf16 copies)
  {
    const int t = tid >> 1, n0 = (tid & 1) * 64;
    const ushort* srcC = proj + (row0 + t) * PROJ + COL_C + n0;
    const ushort* srcB = proj + (row0 + t) * PROJ + COL_B + n0;
#pragma unroll
    for (int j = 0; j < 64; j += 8) {
      *(s16x8*)&sC[swz(t, n0 + j)] = *(const s16x8*)(srcC + j);
      *(s16x8*)&sB[swz(t, n0 + j)] = *(const s16x8*)(srcB + j);
    }
  }
  // stage X^T [d][t]
  {
    const int d = tid & 63;
    const int t0 = (tid >> 6) * 32;
    for (int t = t0; t < t0 + 32; t++)
      sX[swz(d, t)] = proj[(row0 + t) * PROJ + COL_HS + h * 64 + d];
  }
  __syncthreads();

  f32x4 g[2][8];
#pragma unroll
  for (int i = 0; i < 2; i++)
#pragma unroll
    for (int j = 0; j < 8; j++) g[i][j] = (f32x4)0.f;
#pragma unroll
  for (int kk = 0; kk < 4; kk++) {
    s16x8 a[2], bo[8];
#pragma unroll
    for (int i = 0; i < 2; i++)
      a[i] = *(const s16x8*)&sC[swz(wv * 32 + i * 16 + r, kk * 32 + kx * 8)];
#pragma unroll
    for (int j = 0; j < 8; j++)
      bo[j] = *(const s16x8*)&sB[swz(j * 16 + r, kk * 32 + kx * 8)];
#pragma unroll
    for (int i = 0; i < 2; i++)
#pragma unroll
      for (int j = 0; j < 8; j++)
        g[i][j] = __builtin_amdgcn_mfma_f32_16x16x32_bf16(a[i], bo[j], g[i][j], 0, 0, 0);
  }

  s16x8 spf[4][4];
  {
    const ushort* sp = states + (size_t)bid * 8192;
#pragma unroll
    for (int kk = 0; kk < 4; kk++)
#pragma unroll
      for (int j = 0; j < 4; j++)
        spf[kk][j] = *(const s16x8*)(sp + (size_t)(j * 16 + r) * 128 + kk * 32 + kx * 8);
  }
  __syncthreads();

#pragma unroll
  for (int j = 0; j < 8; j++) {
    float cu = cumt[j], dv = dvt[j];
    int tau = j * 16 + (lane & 15);
#pragma unroll
    for (int i = 0; i < 2; i++) {
#pragma unroll
      for (int q = 0; q < 4; q++) {
        int t = wv * 32 + i * 16 + ((lane >> 4) << 2) + q;
        float val = (tau <= t) ? g[i][j][q] * __expf(ct[i][q] - cu) * dv : 0.f;
        sB[swz(t, tau)] = f2b(val);
      }
    }
  }
  {
    int t = wv * 32 + (lane >> 1);
    int n0 = (lane & 1) * 64;
#pragma unroll
    for (int j = 0; j < 64; j += 8) {
      s16x8 u = *(const s16x8*)&sC[swz(t, n0 + j)];
#pragma unroll
      for (int k = 0; k < 8; k++) u[k] = (short)f2b(b2f((ushort)u[k]) * eC);
      *(s16x8*)&sC[swz(t, n0 + j)] = u;
    }
  }
  __syncthreads();

  f32x4 y[2][4];
#pragma unroll
  for (int i = 0; i < 2; i++)
#pragma unroll
    for (int j = 0; j < 4; j++) y[i][j] = (f32x4)0.f;
#pragma unroll
  for (int kk = 0; kk < 4; kk++) {
    s16x8 a[2], bo[4];
#pragma unroll
    for (int i = 0; i < 2; i++)
      a[i] = *(const s16x8*)&sB[swz(wv * 32 + i * 16 + r, kk * 32 + kx * 8)];
#pragma unroll
    for (int j = 0; j < 4; j++)
      bo[j] = *(const s16x8*)&sX[swz(j * 16 + r, kk * 32 + kx * 8)];
#pragma unroll
    for (int i = 0; i < 2; i++)
#pragma unroll
      for (int j = 0; j < 4; j++)
        y[i][j] = __builtin_amdgcn_mfma_f32_16x16x32_bf16(a[i], bo[j], y[i][j], 0, 0, 0);
  }
#pragma unroll
  for (int kk = 0; kk < 4; kk++) {
    s16x8 a[2];
#pragma unroll
    for (int i = 0; i < 2; i++)
      a[i] = *(const s16x8*)&sC[swz(wv * 32 + i * 16 + r, kk * 32 + kx * 8)];
#pragma unroll
    for (int i = 0; i < 2; i++)
#pragma unroll
      for (int j = 0; j < 4; j++)
        y[i][j] = __builtin_amdgcn_mfma_f32_16x16x32_bf16(a[i], spf[kk][j], y[i][j], 0, 0, 0);
  }

  const float Dh = Dp[h];
#pragma unroll
  for (int i = 0; i < 2; i++) {
#pragma unroll
    for (int j = 0; j < 4; j++) {
      int t0 = wv * 32 + i * 16 + (lane >> 4) * 4;
      int d = (lane & 15) + j * 16;
#pragma unroll
      for (int q = 0; q < 4; q++) {
        float x = b2f(sX[swz(d, t0 + q)]);
        proj[(row0 + t0 + q) * PROJ + COL_HS + h * 64 + d] = f2b(y[i][j][q] + Dh * x);
      }
    }
  }
}

// ---------------------------------------------------------------------------
// Gated RMSNorm, bf16 in / bf16 in-place out over proj hs columns
// ---------------------------------------------------------------------------
__global__ __launch_bounds__(256) void rmsnorm_kernel(
    ushort* __restrict__ proj, const float* __restrict__ nw) {
  const int row = blockIdx.x;
  const int tid = threadIdx.x;
  ushort* yp = proj + (size_t)row * PROJ + COL_HS;
  const ushort* gp = proj + (size_t)row * PROJ;
  float v[16];
  float ss = 0.f;
#pragma unroll
  for (int q = 0; q < 4; q++) {
    int col = q * 1024 + tid * 4;
    ushort4 yv = *(const ushort4*)(yp + col);
    ushort4 gv = *(const ushort4*)(gp + col);
    float vy[4] = {b2f(yv.x), b2f(yv.y), b2f(yv.z), b2f(yv.w)};
    float vg[4] = {b2f(gv.x), b2f(gv.y), b2f(gv.z), b2f(gv.w)};
#pragma unroll
    for (int j = 0; j < 4; j++) {
      float sg = vg[j] / (1.f + __expf(-vg[j]));
      float vv = vy[j] * sg;
      v[q * 4 + j] = vv;
      ss += vv * vv;
    }
  }
#pragma unroll
  for (int o = 1; o < 64; o <<= 1) ss += __shfl_xor(ss, o);
  __shared__ float red[4];
  if ((tid & 63) == 0) red[tid >> 6] = ss;
  __syncthreads();
  float tot = red[0] + red[1] + red[2] + red[3];
  float scale = rsqrtf(tot * (1.f / INTER) + EPS);
#pragma unroll
  for (int q = 0; q < 4; q++) {
    int col = q * 1024 + tid * 4;
    float4 w = *(const float4*)(nw + col);
    ushort4 o;
    o.x = f2b(v[q * 4 + 0] * scale * w.x);
    o.y = f2b(v[q * 4 + 1] * scale * w.y);
    o.z = f2b(v[q * 4 + 2] * scale * w.z);
    o.w = f2b(v[q * 4 + 3] * scale * w.w);
    *(ushort4*)(yp + col) = o;
  }
}

// ---------------------------------------------------------------------------
extern "C" void kernel_launch(void* const* d_in, const int* in_sizes, int n_in,
                              void* d_out, int out_size, void* d_ws, size_t ws_size,
                              hipStream_t stream) {
  const float* hs   = (const float*)d_in[0];
  const float* w1   = (const float*)d_in[1];
  const float* cw   = (const float*)d_in[2];
  const float* cb   = (const float*)d_in[3];
  const float* dtb  = (const float*)d_in[4];
  const float* alog = (const float*)d_in[5];
  const float* Dp   = (const float*)d_in[6];
  const float* nw   = (const float*)d_in[7];
  const float* w2   = (const float*)d_in[8];
  float* out = (float*)d_out;

  // ws layout
  char* base = (char*)d_ws;
  size_t off = 0;
  ushort* proj = (ushort*)(base + off); off += (size_t)BS * PROJ * 2;          // 69.7 MB
  ushort* side = (ushort*)(base + off); off += (size_t)BB * NCHC * 3 * CONV_DIM * 2;  // 3.34 MB
  off = (off + 255) & ~(size_t)255;
  float* dtbuf = (float*)(base + off); off += (size_t)BS * 64 * 4;             // 1.05 MB
  off = (off + 255) & ~(size_t)255;
  ushort* w216 = (ushort*)(base + off); off += (size_t)HID * INTER * 2;        // 16.78 MB
  off = (off + 255) & ~(size_t)255;
  char* rC = base + off;
  // phase 1 tenants:
  ushort* hs16 = (ushort*)rC;                                 // 16.78 MB
  ushort* w1p  = (ushort*)(rC + 16777216);                    // 35.65 MB (8704x2048)
  // phase 2 tenants (after GEMM1; hs16/w1p dead):
  ushort* states = (ushort*)rC;                               // 33.55 MB
  float*  cumbuf = (float*)(rC + 33554432);                   // 1.05 MB
  float*  dtvbuf = (float*)(rC + 33554432 + 1048576);         // 1.05 MB

  // 0) merged fp32 -> bf16 conversions (hs, w1 padded, w2)
  {
    long n4 = N4A + N4W1 + N4W2;
    convert_all<<<(int)((n4 + 255) / 256), 256, 0, stream>>>(hs, w1, w2, hs16, w1p, w216);
  }

  // 1) in_proj GEMM (256x128, 1088 blocks): proj(bf16) = hs @ w1^T ; dt sidecar
  gemm1_256x128<<<1088, 512, 0, stream>>>(hs16, w1p, proj, dtbuf);

  // 2) causal depthwise conv + SiLU (in place, bf16, 8-wide)
  conv_capture<<<(BB * NCHC * 3 * CV8 + 255) / 256, 256, 0, stream>>>(proj, side);
  conv_silu<<<(BB * NCHC * CV8 + 255) / 256, 256, 0, stream>>>(proj, side, cw, cb);

  // 3) SSD chunked scan
  ssd_chunk_state<<<BB * NH * NCHK, 256, 0, stream>>>(proj, dtbuf, dtb, alog, states, cumbuf, dtvbuf);
  ssd_state_scan<<<BB * NH, 256, 0, stream>>>(states, cumbuf);
  ssd_chunk_out<<<BB * NH * NCHK, 256, 0, stream>>>(proj, states, cumbuf, dtvbuf, Dp);

  // 4) gated RMSNorm (in place over proj hs columns)
  rmsnorm_kernel<<<BS, 256, 0, stream>>>(proj, nw);

  // 5) out_proj GEMM (256x128 pipelined, 256 blocks = exact 1 round)
  gemm2_256x128<<<256, 512, 0, stream>>>(
      (const ushort*)(proj + COL_HS), w216, out);
}

// Round 10
// 430.650 us; speedup vs baseline: 10.6980x; 1.0220x over previous
//
#include <hip/hip_runtime.h>
#include <hip/hip_bf16.h>
#include <cstddef>
#include <cstdint>

// Problem constants
#define HID   2048
#define INTER 4096
#define NH    64
#define HD    64
#define NST   128
#define CONV_DIM 4352           // INTER + 2*NST
#define PROJ  8512              // INTER + CONV_DIM + NH
#define PROJ_PAD 8704           // 34 * 256
#define SS    2048
#define BB    2
#define BS    (BB*SS)           // 4096 rows
#define EPS   1e-5f

// proj column layout: [0,4096)=gate [4096,8192)=hs [8192,8320)=B [8320,8448)=C [8448,8512)=dt
#define COL_HS 4096
#define COL_B  8192
#define COL_C  8320
#define COL_DT 8448

// conv chunking
#define NCHC  64
#define CHUNKC 32               // SS / NCHC
#define CV8   (CONV_DIM / 8)    // 544

// SSD chunking
#define CL    128               // chunk length
#define NCHK  16                // SS / CL

typedef short s16x8 __attribute__((ext_vector_type(8)));
typedef float f32x4 __attribute__((ext_vector_type(4)));

__device__ inline ushort f2b(float x) {
  __hip_bfloat16 h = __float2bfloat16(x);
  return *(ushort*)&h;
}
__device__ inline float b2f(ushort u) {
  unsigned int v = ((unsigned int)u) << 16;
  return __uint_as_float(v);
}
// LDS tile: 256B rows (128 bf16), XOR-swizzled in 8-elem slots (T2)
__device__ inline int swz(int row, int e) { return row * 128 + (e ^ ((row & 7) << 3)); }

__device__ inline void gload16(const void* g, void* l) {
  __builtin_amdgcn_global_load_lds((const __attribute__((address_space(1))) void*)g,
                                   (__attribute__((address_space(3))) void*)l, 16, 0, 0);
}

// ---------------------------------------------------------------------------
// Merged fp32 -> bf16 conversion: hs | w1 (padded to 8704 rows) | w2
// ---------------------------------------------------------------------------
#define N4A  ((long)BS * HID / 4)
#define N4W1 ((long)PROJ_PAD * HID / 4)
#define N4W2 ((long)HID * INTER / 4)

__global__ __launch_bounds__(256) void convert_all(
    const float* __restrict__ hs, const float* __restrict__ w1,
    const float* __restrict__ w2, ushort* __restrict__ hs16,
    ushort* __restrict__ w1p, ushort* __restrict__ w216) {
  long i = (long)blockIdx.x * 256 + threadIdx.x;
  const float* src;
  ushort* dst;
  long e0;
  if (i < N4A) {
    src = hs; dst = hs16; e0 = i * 4;
  } else if (i < N4A + N4W1) {
    long k = i - N4A;
    e0 = k * 4;
    long row = e0 >> 11;  // / 2048
    if (row >= PROJ) {
      ushort4 z = {0, 0, 0, 0};
      *(ushort4*)(w1p + e0) = z;
      return;
    }
    src = w1; dst = w1p;
  } else if (i < N4A + N4W1 + N4W2) {
    long k = i - N4A - N4W1;
    src = w2; dst = w216; e0 = k * 4;
  } else {
    return;
  }
  float4 v = *(const float4*)(src + e0);
  ushort4 o;
  o.x = f2b(v.x); o.y = f2b(v.y); o.z = f2b(v.z); o.w = f2b(v.w);
  *(ushort4*)(dst + e0) = o;
}

// ---------------------------------------------------------------------------
// GEMM1: 256x256 4-phase pipelined bf16 MFMA GEMM (r8-proven, 183 us).
// B(t+1) staged halves in ph1/ph2 (other buf), A(t+2) staged in ph4 (same
// buf, reads drained by ph3), vmcnt(4). bf16 epilogue + fp32 dt sidecar.
// ---------------------------------------------------------------------------
__global__ __launch_bounds__(512, 2) void gemm256_8ph(
    const ushort* __restrict__ A, const ushort* __restrict__ Bw,
    ushort* __restrict__ C, float* __restrict__ dtbuf) {
  __shared__ ushort smem[65536];   // [A: buf0 16K, buf1 16K][B: buf0, buf1]
  const int tid = threadIdx.x;
  const int lane = tid & 63;
  const int wid = tid >> 6;
  const int wm = wid >> 2;         // 0..1
  const int wn = wid & 3;          // 0..3
  const int r = lane & 15;
  const int kx = lane >> 4;        // 0..3

  // grid remap: column-groups of 8 (16 row-tiles), bijective over 544 blocks
  const int fid = blockIdx.x;
  const int bcol = ((fid >> 7) << 3) + ((fid & 127) >> 4);   // 0..33
  const int brow = fid & 15;                                  // 0..15

  const ushort* Ag = A + (size_t)(brow * 256) * HID;
  const ushort* Bg = Bw + (size_t)(bcol * 256) * HID;

  const int srow = tid >> 3;                 // 0..63
  const int scole = (((tid & 7) * 16) ^ ((srow & 7) << 4)) >> 1;

  auto stageA = [&](int buf, int kt, int half) {
    const ushort* g = Ag + (size_t)(half * 128 + srow) * HID + kt * 64 + scole;
    ushort* l = smem + buf * 16384 + half * 8192 + tid * 8;
    gload16(g, l);
    gload16(g + (size_t)64 * HID, l + 4096);
  };
  auto stageB = [&](int buf, int kt, int half) {
    const ushort* g = Bg + (size_t)(half * 128 + srow) * HID + kt * 64 + scole;
    ushort* l = smem + 32768 + buf * 16384 + half * 8192 + tid * 8;
    gload16(g, l);
    gload16(g + (size_t)64 * HID, l + 4096);
  };
  auto ldA = [&](int buf, int mf, int ks) -> s16x8 {
    int row = wm * 128 + mf * 16 + r;
    int cb = (ks * 64 + kx * 16) ^ ((row & 7) << 4);
    return *(const s16x8*)(smem + buf * 16384 + row * 64 + (cb >> 1));
  };
  auto ldB = [&](int buf, int nf, int ks) -> s16x8 {
    int row = wn * 64 + nf * 16 + r;
    int cb = (ks * 64 + kx * 16) ^ ((row & 7) << 4);
    return *(const s16x8*)(smem + 32768 + buf * 16384 + row * 64 + (cb >> 1));
  };

  f32x4 acc[8][4];
#pragma unroll
  for (int i = 0; i < 8; i++)
#pragma unroll
    for (int j = 0; j < 4; j++) acc[i][j] = (f32x4)0.f;

  constexpr int NT = HID / 64;   // 32 K-tiles

  stageA(0, 0, 0); stageA(0, 0, 1);
  stageB(0, 0, 0); stageB(0, 0, 1);
  stageA(1, 1, 0); stageA(1, 1, 1);
  asm volatile("s_waitcnt vmcnt(4)" ::: "memory");
  __builtin_amdgcn_s_barrier();

  int cur = 0;
  for (int t = 0; t < NT; t++) {
    s16x8 a[4][2], b[2][2], b2[2][2];
    // phase 1: read a(mf0-3), b(nf0-1); stage B-lo(t+1); Q00
#pragma unroll
    for (int mf = 0; mf < 4; mf++)
#pragma unroll
      for (int ks = 0; ks < 2; ks++) a[mf][ks] = ldA(cur, mf, ks);
#pragma unroll
    for (int nf = 0; nf < 2; nf++)
#pragma unroll
      for (int ks = 0; ks < 2; ks++) b[nf][ks] = ldB(cur, nf, ks);
    if (t + 1 < NT) stageB(cur ^ 1, t + 1, 0);
    __builtin_amdgcn_s_barrier();
    asm volatile("s_waitcnt lgkmcnt(0)" ::: "memory");
    __builtin_amdgcn_sched_barrier(0);
    __builtin_amdgcn_s_setprio(1);
#pragma unroll
    for (int mf = 0; mf < 4; mf++)
#pragma unroll
      for (int nf = 0; nf < 2; nf++)
#pragma unroll
        for (int ks = 0; ks < 2; ks++)
          acc[mf][nf] = __builtin_amdgcn_mfma_f32_16x16x32_bf16(a[mf][ks], b[nf][ks], acc[mf][nf], 0, 0, 0);
    __builtin_amdgcn_s_setprio(0);
    __builtin_amdgcn_s_barrier();
    // phase 2: read b2(nf2-3); stage B-hi(t+1); Q01
#pragma unroll
    for (int nf = 0; nf < 2; nf++)
#pragma unroll
      for (int ks = 0; ks < 2; ks++) b2[nf][ks] = ldB(cur, nf + 2, ks);
    if (t + 1 < NT) stageB(cur ^ 1, t + 1, 1);
    __builtin_amdgcn_s_barrier();
    asm volatile("s_waitcnt lgkmcnt(0)" ::: "memory");
    __builtin_amdgcn_sched_barrier(0);
    __builtin_amdgcn_s_setprio(1);
#pragma unroll
    for (int mf = 0; mf < 4; mf++)
#pragma unroll
      for (int nf = 0; nf < 2; nf++)
#pragma unroll
        for (int ks = 0; ks < 2; ks++)
          acc[mf][nf + 2] = __builtin_amdgcn_mfma_f32_16x16x32_bf16(a[mf][ks], b2[nf][ks], acc[mf][nf + 2], 0, 0, 0);
    __builtin_amdgcn_s_setprio(0);
    __builtin_amdgcn_s_barrier();
    // phase 3: read a(mf4-7); Q10
#pragma unroll
    for (int mf = 0; mf < 4; mf++)
#pragma unroll
      for (int ks = 0; ks < 2; ks++) a[mf][ks] = ldA(cur, mf + 4, ks);
    __builtin_amdgcn_s_barrier();
    asm volatile("s_waitcnt lgkmcnt(0)" ::: "memory");
    __builtin_amdgcn_sched_barrier(0);
    __builtin_amdgcn_s_setprio(1);
#pragma unroll
    for (int mf = 0; mf < 4; mf++)
#pragma unroll
      for (int nf = 0; nf < 2; nf++)
#pragma unroll
        for (int ks = 0; ks < 2; ks++)
          acc[mf + 4][nf] = __builtin_amdgcn_mfma_f32_16x16x32_bf16(a[mf][ks], b[nf][ks], acc[mf + 4][nf], 0, 0, 0);
    __builtin_amdgcn_s_setprio(0);
    __builtin_amdgcn_s_barrier();
    // phase 4: stage A(t+2) into cur; Q11
    if (t + 2 < NT) { stageA(cur, t + 2, 0); stageA(cur, t + 2, 1); }
    __builtin_amdgcn_s_setprio(1);
#pragma unroll
    for (int mf = 0; mf < 4; mf++)
#pragma unroll
      for (int nf = 0; nf < 2; nf++)
#pragma unroll
        for (int ks = 0; ks < 2; ks++)
          acc[mf + 4][nf + 2] = __builtin_amdgcn_mfma_f32_16x16x32_bf16(a[mf][ks], b2[nf][ks], acc[mf + 4][nf + 2], 0, 0, 0);
    __builtin_amdgcn_s_setprio(0);
    if (t + 2 < NT) {
      asm volatile("s_waitcnt vmcnt(4)" ::: "memory");
    } else {
      asm volatile("s_waitcnt vmcnt(0)" ::: "memory");
    }
    __builtin_amdgcn_s_barrier();
    cur ^= 1;
  }

  const int m0 = brow * 256 + wm * 128 + (lane >> 4) * 4;
  const int n0 = bcol * 256 + wn * 64 + r;
#pragma unroll
  for (int mf = 0; mf < 8; mf++) {
#pragma unroll
    for (int nf = 0; nf < 4; nf++) {
      int n = n0 + nf * 16;
      if (n >= PROJ) continue;
#pragma unroll
      for (int q = 0; q < 4; q++) {
        float v = acc[mf][nf][q];
        int m = m0 + mf * 16 + q;
        C[(size_t)m * PROJ + n] = f2b(v);
        if (n >= COL_DT) dtbuf[(size_t)m * 64 + (n - COL_DT)] = v;
      }
    }
  }
}

// ---------------------------------------------------------------------------
// GEMM2: 256x128-tile pipelined bf16 MFMA GEMM (r8-proven).
// ---------------------------------------------------------------------------
__global__ __launch_bounds__(512, 2) void gemm2_256x128(
    const ushort* __restrict__ A, const ushort* __restrict__ Bw,
    float* __restrict__ C) {
  __shared__ ushort smem[49152];
  const int tid = threadIdx.x;
  const int lane = tid & 63;
  const int wid = tid >> 6;
  const int wm = wid >> 1;
  const int wn = wid & 1;
  const int r = lane & 15;
  const int kx = lane >> 4;

  const int fid = blockIdx.x;      // 256 blocks
  const int bcol = fid >> 4;
  const int brow = fid & 15;

  const ushort* Ag = A + (size_t)(brow * 256) * PROJ;
  const ushort* Bg = Bw + (size_t)(bcol * 128) * INTER;

  const int srow = tid >> 3;
  const int scole = (((tid & 7) * 16) ^ ((srow & 7) << 4)) >> 1;

  auto stageA2 = [&](int buf, int kt) {
#pragma unroll
    for (int i = 0; i < 4; i++) {
      gload16(Ag + (size_t)(i * 64 + srow) * PROJ + kt * 64 + scole,
              smem + buf * 16384 + i * 4096 + tid * 8);
    }
  };
  auto stageB2 = [&](int buf, int kt) {
#pragma unroll
    for (int i = 0; i < 2; i++) {
      gload16(Bg + (size_t)(i * 64 + srow) * INTER + kt * 64 + scole,
              smem + 32768 + buf * 8192 + i * 4096 + tid * 8);
    }
  };
  auto ldA2 = [&](int buf, int mf, int ks) -> s16x8 {
    int row = wm * 64 + mf * 16 + r;
    int cb = (ks * 64 + kx * 16) ^ ((row & 7) << 4);
    return *(const s16x8*)(smem + buf * 16384 + row * 64 + (cb >> 1));
  };
  auto ldB2 = [&](int buf, int nf, int ks) -> s16x8 {
    int row = wn * 64 + nf * 16 + r;
    int cb = (ks * 64 + kx * 16) ^ ((row & 7) << 4);
    return *(const s16x8*)(smem + 32768 + buf * 8192 + row * 64 + (cb >> 1));
  };

  f32x4 acc[4][4];
#pragma unroll
  for (int i = 0; i < 4; i++)
#pragma unroll
    for (int j = 0; j < 4; j++) acc[i][j] = (f32x4)0.f;

  constexpr int NT = INTER / 64;   // 64 K-tiles

  stageA2(0, 0); stageB2(0, 0);
  stageA2(1, 1); stageB2(1, 1);
  asm volatile("s_waitcnt vmcnt(6)" ::: "memory");
  __builtin_amdgcn_s_barrier();

  int cur = 0;
  for (int t = 0; t < NT; t++) {
    s16x8 a[4][2], b[4][2];
#pragma unroll
    for (int mf = 0; mf < 4; mf++)
#pragma unroll
      for (int ks = 0; ks < 2; ks++) a[mf][ks] = ldA2(cur, mf, ks);
#pragma unroll
    for (int nf = 0; nf < 4; nf++)
#pragma unroll
      for (int ks = 0; ks < 2; ks++) b[nf][ks] = ldB2(cur, nf, ks);
    __builtin_amdgcn_s_barrier();
    asm volatile("s_waitcnt lgkmcnt(0)" ::: "memory");
    __builtin_amdgcn_sched_barrier(0);
    __builtin_amdgcn_s_setprio(1);
#pragma unroll
    for (int mf = 0; mf < 4; mf++)
#pragma unroll
      for (int nf = 0; nf < 2; nf++)
#pragma unroll
        for (int ks = 0; ks < 2; ks++)
          acc[mf][nf] = __builtin_amdgcn_mfma_f32_16x16x32_bf16(a[mf][ks], b[nf][ks], acc[mf][nf], 0, 0, 0);
    __builtin_amdgcn_s_setprio(0);
    __builtin_amdgcn_s_barrier();
    if (t + 2 < NT) { stageA2(cur, t + 2); stageB2(cur, t + 2); }
    __builtin_amdgcn_s_setprio(1);
#pragma unroll
    for (int mf = 0; mf < 4; mf++)
#pragma unroll
      for (int nf = 2; nf < 4; nf++)
#pragma unroll
        for (int ks = 0; ks < 2; ks++)
          acc[mf][nf] = __builtin_amdgcn_mfma_f32_16x16x32_bf16(a[mf][ks], b[nf][ks], acc[mf][nf], 0, 0, 0);
    __builtin_amdgcn_s_setprio(0);
    if (t + 2 < NT) {
      asm volatile("s_waitcnt vmcnt(6)" ::: "memory");
    } else {
      asm volatile("s_waitcnt vmcnt(0)" ::: "memory");
    }
    __builtin_amdgcn_s_barrier();
    cur ^= 1;
  }

  const int m0 = brow * 256 + wm * 64 + (lane >> 4) * 4;
  const int n0 = bcol * 128 + wn * 64 + r;
#pragma unroll
  for (int mf = 0; mf < 4; mf++) {
#pragma unroll
    for (int nf = 0; nf < 4; nf++) {
      int n = n0 + nf * 16;
#pragma unroll
      for (int q = 0; q < 4; q++)
        C[(size_t)(m0 + mf * 16 + q) * HID + n] = acc[mf][nf][q];
    }
  }
}

// ---------------------------------------------------------------------------
// Conv boundary capture (bf16, 8-wide, fine chunks)
// ---------------------------------------------------------------------------
__global__ __launch_bounds__(256) void conv_capture(
    const ushort* __restrict__ proj, ushort* __restrict__ side) {
  int idx = blockIdx.x * 256 + threadIdx.x;
  const int total = BB * NCHC * 3 * CV8;
  if (idx >= total) return;
  int c8 = idx % CV8;
  int t = idx / CV8;
  int j = t % 3; t /= 3;
  int chunk = t % NCHC;
  int b = t / NCHC;
  int s = chunk * CHUNKC - 1 - j;
  s16x8 v = {0, 0, 0, 0, 0, 0, 0, 0};
  if (s >= 0) v = *(const s16x8*)(proj + ((size_t)b * SS + s) * PROJ + COL_HS + c8 * 8);
  *(s16x8*)(side + ((size_t)(b * NCHC + chunk) * 3 + j) * CONV_DIM + c8 * 8) = v;
}

// ---------------------------------------------------------------------------
// Causal depthwise conv1d (K=4) + bias + SiLU, in place, 8 channels/thread
// ---------------------------------------------------------------------------
__global__ __launch_bounds__(256) void conv_silu(
    ushort* __restrict__ proj, const ushort* __restrict__ side,
    const float* __restrict__ cw, const float* __restrict__ cb) {
  int idx = blockIdx.x * 256 + threadIdx.x;
  const int total = BB * NCHC * CV8;
  if (idx >= total) return;
  int c8 = idx % CV8;
  int t = idx / CV8;
  int chunk = t % NCHC;
  int b = t / NCHC;
  const int c0 = c8 * 8;
  float w0[8], w1[8], w2[8], w3[8], bias[8], h1[8], h2[8], h3[8];
#pragma unroll
  for (int e = 0; e < 8; e++) {
    float4 wv = *(const float4*)(cw + (c0 + e) * 4);
    w0[e] = wv.x; w1[e] = wv.y; w2[e] = wv.z; w3[e] = wv.w;
    bias[e] = cb[c0 + e];
  }
  const ushort* sd = side + (size_t)(b * NCHC + chunk) * 3 * CONV_DIM;
  {
    s16x8 v1 = *(const s16x8*)(sd + c0);
    s16x8 v2 = *(const s16x8*)(sd + CONV_DIM + c0);
    s16x8 v3 = *(const s16x8*)(sd + 2 * CONV_DIM + c0);
#pragma unroll
    for (int e = 0; e < 8; e++) {
      h1[e] = b2f((ushort)v1[e]);
      h2[e] = b2f((ushort)v2[e]);
      h3[e] = b2f((ushort)v3[e]);
    }
  }
  size_t p = ((size_t)b * SS + (size_t)chunk * CHUNKC) * PROJ + COL_HS + c0;
  for (int s = 0; s < CHUNKC; s++) {
    s16x8 xv = *(const s16x8*)(proj + p);
    s16x8 ov;
#pragma unroll
    for (int e = 0; e < 8; e++) {
      float x = b2f((ushort)xv[e]);
      float o = w3[e] * x + w2[e] * h1[e] + w1[e] * h2[e] + w0[e] * h3[e] + bias[e];
      o = o / (1.f + __expf(-o));    // SiLU
      ov[e] = (short)f2b(o);
      h3[e] = h2[e]; h2[e] = h1[e]; h1[e] = x;
    }
    *(s16x8*)(proj + p) = ov;
    p += PROJ;
  }
}

// ---------------------------------------------------------------------------
// SSD K1: per (b,h,chunk): softplus(dt), shuffle cumsum, chunk state (MFMA).
// states written TRANSPOSED: [d=64][n=128]
// ---------------------------------------------------------------------------
__global__ __launch_bounds__(256) void ssd_chunk_state(
    const ushort* __restrict__ proj, const float* __restrict__ dtf,
    const float* __restrict__ dt_bias, const float* __restrict__ A_log,
    ushort* __restrict__ states, float* __restrict__ cumbuf,
    float* __restrict__ dtvbuf) {
  const int bid = blockIdx.x;
  const int c = bid & 15;
  const int h = (bid >> 4) & 63;
  const int b = bid >> 10;
  const int tid = threadIdx.x;
  const int lane = tid & 63;
  const int wv = tid >> 6;
  __shared__ float sdtv[CL], scum[CL], sw[CL];
  __shared__ float wtot[2];
  __shared__ ushort sBt[128 * 128];   // [n][t]
  __shared__ ushort sXw[64 * 128];    // [d][t] scaled
  const size_t row0 = (size_t)b * SS + (size_t)c * CL;
  const size_t bh = (size_t)(b * NH + h);

  const float Ah = -__expf(A_log[h]);
  // softplus + wave-shuffle inclusive cumsum (waves 0,1 carry the 128 values)
  float dtvv = 0.f, v = 0.f;
  if (tid < CL) {
    float z = dtf[(row0 + tid) * 64 + h] + dt_bias[h];
    dtvv = (z > 20.f) ? z : log1pf(__expf(z));
    v = dtvv * Ah;
  }
#pragma unroll
  for (int off = 1; off < 64; off <<= 1) {
    float u = __shfl_up(v, off);
    if (lane >= off) v += u;
  }
  if (tid < CL && lane == 63) wtot[wv] = v;
  __syncthreads();
  if (wv == 1) v += wtot[0];
  if (tid < CL) {
    sdtv[tid] = dtvv;
    scum[tid] = v;
    cumbuf[bh * SS + c * CL + tid] = v;
    dtvbuf[bh * SS + c * CL + tid] = dtvv;
  }
  __syncthreads();
  const float cumL = scum[CL - 1];
  if (tid < CL) sw[tid] = __expf(cumL - v) * dtvv;
  __syncthreads();

  // stage B^T [n][t]
  {
    const int t = tid >> 1, n0 = (tid & 1) * 64;
    const ushort* src = proj + (row0 + t) * PROJ + COL_B + n0;
#pragma unroll
    for (int j = 0; j < 64; j += 8) {
      s16x8 vv = *(const s16x8*)(src + j);
#pragma unroll
      for (int e = 0; e < 8; e++) sBt[swz(n0 + j + e, t)] = (ushort)vv[e];
    }
  }
  // stage Xw^T [d][t] scaled by sw[t]
  {
    const int d = tid & 63;
    const int t0 = (tid >> 6) * 32;
    for (int t = t0; t < t0 + 32; t++) {
      float x = b2f(proj[(row0 + t) * PROJ + COL_HS + h * 64 + d]);
      sXw[swz(d, t)] = f2b(x * sw[t]);
    }
  }
  __syncthreads();

  const int r = lane & 15, kx = lane >> 4;
  f32x4 acc[2][4];
#pragma unroll
  for (int i = 0; i < 2; i++)
#pragma unroll
    for (int j = 0; j < 4; j++) acc[i][j] = (f32x4)0.f;
#pragma unroll
  for (int kk = 0; kk < 4; kk++) {
    s16x8 a[2], bo[4];
#pragma unroll
    for (int i = 0; i < 2; i++)
      a[i] = *(const s16x8*)&sBt[swz(wv * 32 + i * 16 + r, kk * 32 + kx * 8)];
#pragma unroll
    for (int j = 0; j < 4; j++)
      bo[j] = *(const s16x8*)&sXw[swz(j * 16 + r, kk * 32 + kx * 8)];
#pragma unroll
    for (int i = 0; i < 2; i++)
#pragma unroll
      for (int j = 0; j < 4; j++)
        acc[i][j] = __builtin_amdgcn_mfma_f32_16x16x32_bf16(a[i], bo[j], acc[i][j], 0, 0, 0);
  }
  ushort* dst = states + (size_t)bid * (128 * 64);
#pragma unroll
  for (int i = 0; i < 2; i++) {
#pragma unroll
    for (int j = 0; j < 4; j++) {
      int n = wv * 32 + i * 16 + (lane >> 4) * 4;
      int d = (lane & 15) + j * 16;
      ushort4 o;
      o.x = f2b(acc[i][j][0]);
      o.y = f2b(acc[i][j][1]);
      o.z = f2b(acc[i][j][2]);
      o.w = f2b(acc[i][j][3]);
      *(ushort4*)(dst + (size_t)d * 128 + n) = o;
    }
  }
}

// ---------------------------------------------------------------------------
// SSD K2: inter-chunk recurrence
// ---------------------------------------------------------------------------
__global__ __launch_bounds__(256) void ssd_state_scan(
    ushort* __restrict__ states, const float* __restrict__ cumbuf) {
  const int bh = blockIdx.x;
  const int tid = threadIdx.x;
  float run[32];
#pragma unroll
  for (int i = 0; i < 32; i++) run[i] = 0.f;
  for (int c = 0; c < NCHK; c++) {
    float dec = __expf(cumbuf[(size_t)bh * SS + c * CL + (CL - 1)]);
    ushort* p = states + ((size_t)bh * NCHK + c) * 8192 + tid * 32;
    s16x8 in[4];
#pragma unroll
    for (int v = 0; v < 4; v++) in[v] = *(const s16x8*)(p + v * 8);
    s16x8 out[4];
#pragma unroll
    for (int v = 0; v < 4; v++) {
#pragma unroll
      for (int e = 0; e < 8; e++) {
        int i = v * 8 + e;
        out[v][e] = (short)f2b(run[i]);
        run[i] = dec * run[i] + b2f((ushort)in[v][e]);
      }
    }
#pragma unroll
    for (int v = 0; v < 4; v++) *(s16x8*)(p + v * 8) = out[v];
  }
}

// ---------------------------------------------------------------------------
// SSD K3 (slim): LDS = sB + sX = 48KB. C fragments read ONCE from global
// (L2-hot), reused for G-phase and Yi-phase. Cs row-scale exp(cum[t]) folded
// into the epilogue: out = y + exp(ct)*yi + D*x.
// ---------------------------------------------------------------------------
__global__ __launch_bounds__(256, 2) void ssd_chunk_out(
    ushort* __restrict__ proj, const ushort* __restrict__ states,
    const float* __restrict__ cumbuf, const float* __restrict__ dtvbuf,
    const float* __restrict__ Dp) {
  const int bid = blockIdx.x;
  const int c = bid & 15;
  const int h = (bid >> 4) & 63;
  const int b = bid >> 10;
  const int tid = threadIdx.x;
  const int lane = tid & 63;
  const int wv = tid >> 6;
  __shared__ ushort sB[128 * 128];   // B [tau][n] -> later P [t][tau]
  __shared__ ushort sX[64 * 128];    // X^T [d][t]
  const size_t row0 = (size_t)b * SS + (size_t)c * CL;
  const size_t bh = (size_t)(b * NH + h);
  const float* cumb = cumbuf + bh * SS + c * CL;
  const float* dtvb = dtvbuf + bh * SS + c * CL;
  const int r = lane & 15, kx = lane >> 4;

  float ct[2][4];
#pragma unroll
  for (int i = 0; i < 2; i++)
#pragma unroll
    for (int q = 0; q < 4; q++)
      ct[i][q] = cumb[wv * 32 + i * 16 + ((lane >> 4) << 2) + q];
  float cumt[8], dvt[8];
#pragma unroll
  for (int j = 0; j < 8; j++) {
    int tau = j * 16 + (lane & 15);
    cumt[j] = cumb[tau];
    dvt[j] = dtvb[tau];
  }

  // stage B [t][n]
  {
    const int t = tid >> 1, n0 = (tid & 1) * 64;
    const ushort* srcB = proj + (row0 + t) * PROJ + COL_B + n0;
#pragma unroll
    for (int j = 0; j < 64; j += 8)
      *(s16x8*)&sB[swz(t, n0 + j)] = *(const s16x8*)(srcB + j);
  }
  // stage X^T [d][t]
  {
    const int d = tid & 63;
    const int t0 = (tid >> 6) * 32;
    for (int t = t0; t < t0 + 32; t++)
      sX[swz(d, t)] = proj[(row0 + t) * PROJ + COL_HS + h * 64 + d];
  }
  // prefetch C fragments from global (16B aligned, L2-hot)
  s16x8 cf[4][2];
#pragma unroll
  for (int kk = 0; kk < 4; kk++)
#pragma unroll
    for (int i = 0; i < 2; i++)
      cf[kk][i] = *(const s16x8*)(proj + (row0 + wv * 32 + i * 16 + r) * PROJ
                                  + COL_C + kk * 32 + kx * 8);
  __syncthreads();

  // Phase G: G = C @ B^T
  f32x4 g[2][8];
#pragma unroll
  for (int i = 0; i < 2; i++)
#pragma unroll
    for (int j = 0; j < 8; j++) g[i][j] = (f32x4)0.f;
#pragma unroll
  for (int kk = 0; kk < 4; kk++) {
    s16x8 bo[8];
#pragma unroll
    for (int j = 0; j < 8; j++)
      bo[j] = *(const s16x8*)&sB[swz(j * 16 + r, kk * 32 + kx * 8)];
#pragma unroll
    for (int i = 0; i < 2; i++)
#pragma unroll
      for (int j = 0; j < 8; j++)
        g[i][j] = __builtin_amdgcn_mfma_f32_16x16x32_bf16(cf[kk][i], bo[j], g[i][j], 0, 0, 0);
  }

  // Phase Yi: yi = C @ Sp^T (unscaled; exp(ct) applied in epilogue)
  f32x4 yi[2][4];
#pragma unroll
  for (int i = 0; i < 2; i++)
#pragma unroll
    for (int j = 0; j < 4; j++) yi[i][j] = (f32x4)0.f;
  {
    const ushort* sp = states + (size_t)bid * 8192;
#pragma unroll
    for (int kk = 0; kk < 4; kk++) {
      s16x8 spk[4];
#pragma unroll
      for (int j = 0; j < 4; j++)
        spk[j] = *(const s16x8*)(sp + (size_t)(j * 16 + r) * 128 + kk * 32 + kx * 8);
#pragma unroll
      for (int i = 0; i < 2; i++)
#pragma unroll
        for (int j = 0; j < 4; j++)
          yi[i][j] = __builtin_amdgcn_mfma_f32_16x16x32_bf16(cf[kk][i], spk[j], yi[i][j], 0, 0, 0);
    }
  }
  __syncthreads();   // all waves done reading sB as B

  // Phase P: write P[t][tau] over sB
#pragma unroll
  for (int j = 0; j < 8; j++) {
    float cu = cumt[j], dv = dvt[j];
    int tau = j * 16 + (lane & 15);
#pragma unroll
    for (int i = 0; i < 2; i++) {
#pragma unroll
      for (int q = 0; q < 4; q++) {
        int t = wv * 32 + i * 16 + ((lane >> 4) << 2) + q;
        float val = (tau <= t) ? g[i][j][q] * __expf(ct[i][q] - cu) * dv : 0.f;
        sB[swz(t, tau)] = f2b(val);
      }
    }
  }
  __syncthreads();

  // Phase Y: y = P @ X^T
  f32x4 y[2][4];
#pragma unroll
  for (int i = 0; i < 2; i++)
#pragma unroll
    for (int j = 0; j < 4; j++) y[i][j] = (f32x4)0.f;
#pragma unroll
  for (int kk = 0; kk < 4; kk++) {
    s16x8 a[2], bo[4];
#pragma unroll
    for (int i = 0; i < 2; i++)
      a[i] = *(const s16x8*)&sB[swz(wv * 32 + i * 16 + r, kk * 32 + kx * 8)];
#pragma unroll
    for (int j = 0; j < 4; j++)
      bo[j] = *(const s16x8*)&sX[swz(j * 16 + r, kk * 32 + kx * 8)];
#pragma unroll
    for (int i = 0; i < 2; i++)
#pragma unroll
      for (int j = 0; j < 4; j++)
        y[i][j] = __builtin_amdgcn_mfma_f32_16x16x32_bf16(a[i], bo[j], y[i][j], 0, 0, 0);
  }

  // Epilogue: out = y + exp(ct)*yi + D*x
  const float Dh = Dp[h];
  float eP[2][4];
#pragma unroll
  for (int i = 0; i < 2; i++)
#pragma unroll
    for (int q = 0; q < 4; q++) eP[i][q] = __expf(ct[i][q]);
#pragma unroll
  for (int i = 0; i < 2; i++) {
#pragma unroll
    for (int j = 0; j < 4; j++) {
      int t0 = wv * 32 + i * 16 + (lane >> 4) * 4;
      int d = (lane & 15) + j * 16;
#pragma unroll
      for (int q = 0; q < 4; q++) {
        float x = b2f(sX[swz(d, t0 + q)]);
        proj[(row0 + t0 + q) * PROJ + COL_HS + h * 64 + d] =
            f2b(y[i][j][q] + eP[i][q] * yi[i][j][q] + Dh * x);
      }
    }
  }
}

// ---------------------------------------------------------------------------
// Gated RMSNorm, bf16 in / bf16 in-place out over proj hs columns
// ---------------------------------------------------------------------------
__global__ __launch_bounds__(256) void rmsnorm_kernel(
    ushort* __restrict__ proj, const float* __restrict__ nw) {
  const int row = blockIdx.x;
  const int tid = threadIdx.x;
  ushort* yp = proj + (size_t)row * PROJ + COL_HS;
  const ushort* gp = proj + (size_t)row * PROJ;
  float v[16];
  float ss = 0.f;
#pragma unroll
  for (int q = 0; q < 4; q++) {
    int col = q * 1024 + tid * 4;
    ushort4 yv = *(const ushort4*)(yp + col);
    ushort4 gv = *(const ushort4*)(gp + col);
    float vy[4] = {b2f(yv.x), b2f(yv.y), b2f(yv.z), b2f(yv.w)};
    float vg[4] = {b2f(gv.x), b2f(gv.y), b2f(gv.z), b2f(gv.w)};
#pragma unroll
    for (int j = 0; j < 4; j++) {
      float sg = vg[j] / (1.f + __expf(-vg[j]));
      float vv = vy[j] * sg;
      v[q * 4 + j] = vv;
      ss += vv * vv;
    }
  }
#pragma unroll
  for (int o = 1; o < 64; o <<= 1) ss += __shfl_xor(ss, o);
  __shared__ float red[4];
  if ((tid & 63) == 0) red[tid >> 6] = ss;
  __syncthreads();
  float tot = red[0] + red[1] + red[2] + red[3];
  float scale = rsqrtf(tot * (1.f / INTER) + EPS);
#pragma unroll
  for (int q = 0; q < 4; q++) {
    int col = q * 1024 + tid * 4;
    float4 w = *(const float4*)(nw + col);
    ushort4 o;
    o.x = f2b(v[q * 4 + 0] * scale * w.x);
    o.y = f2b(v[q * 4 + 1] * scale * w.y);
    o.z = f2b(v[q * 4 + 2] * scale * w.z);
    o.w = f2b(v[q * 4 + 3] * scale * w.w);
    *(ushort4*)(yp + col) = o;
  }
}

// ---------------------------------------------------------------------------
extern "C" void kernel_launch(void* const* d_in, const int* in_sizes, int n_in,
                              void* d_out, int out_size, void* d_ws, size_t ws_size,
                              hipStream_t stream) {
  const float* hs   = (const float*)d_in[0];
  const float* w1   = (const float*)d_in[1];
  const float* cw   = (const float*)d_in[2];
  const float* cb   = (const float*)d_in[3];
  const float* dtb  = (const float*)d_in[4];
  const float* alog = (const float*)d_in[5];
  const float* Dp   = (const float*)d_in[6];
  const float* nw   = (const float*)d_in[7];
  const float* w2   = (const float*)d_in[8];
  float* out = (float*)d_out;

  // ws layout
  char* base = (char*)d_ws;
  size_t off = 0;
  ushort* proj = (ushort*)(base + off); off += (size_t)BS * PROJ * 2;          // 69.7 MB
  ushort* side = (ushort*)(base + off); off += (size_t)BB * NCHC * 3 * CONV_DIM * 2;
  off = (off + 255) & ~(size_t)255;
  float* dtbuf = (float*)(base + off); off += (size_t)BS * 64 * 4;             // 1.05 MB
  off = (off + 255) & ~(size_t)255;
  ushort* w216 = (ushort*)(base + off); off += (size_t)HID * INTER * 2;        // 16.78 MB
  off = (off + 255) & ~(size_t)255;
  char* rC = base + off;
  // phase 1 tenants:
  ushort* hs16 = (ushort*)rC;                                 // 16.78 MB
  ushort* w1p  = (ushort*)(rC + 16777216);                    // 35.65 MB (8704x2048)
  // phase 2 tenants (after GEMM1; hs16/w1p dead):
  ushort* states = (ushort*)rC;                               // 33.55 MB
  float*  cumbuf = (float*)(rC + 33554432);                   // 1.05 MB
  float*  dtvbuf = (float*)(rC + 33554432 + 1048576);         // 1.05 MB

  // 0) merged fp32 -> bf16 conversions (hs, w1 padded, w2)
  {
    long n4 = N4A + N4W1 + N4W2;
    convert_all<<<(int)((n4 + 255) / 256), 256, 0, stream>>>(hs, w1, w2, hs16, w1p, w216);
  }

  // 1) in_proj GEMM (256^2, 544 blocks): proj(bf16) = hs @ w1^T ; dt sidecar
  gemm256_8ph<<<(BS / 256) * (PROJ_PAD / 256), 512, 0, stream>>>(hs16, w1p, proj, dtbuf);

  // 2) causal depthwise conv + SiLU (in place, bf16, 8-wide)
  conv_capture<<<(BB * NCHC * 3 * CV8 + 255) / 256, 256, 0, stream>>>(proj, side);
  conv_silu<<<(BB * NCHC * CV8 + 255) / 256, 256, 0, stream>>>(proj, side, cw, cb);

  // 3) SSD chunked scan
  ssd_chunk_state<<<BB * NH * NCHK, 256, 0, stream>>>(proj, dtbuf, dtb, alog, states, cumbuf, dtvbuf);
  ssd_state_scan<<<BB * NH, 256, 0, stream>>>(states, cumbuf);
  ssd_chunk_out<<<BB * NH * NCHK, 256, 0, stream>>>(proj, states, cumbuf, dtvbuf, Dp);

  // 4) gated RMSNorm (in place over proj hs columns)
  rmsnorm_kernel<<<BS, 256, 0, stream>>>(proj, nw);

  // 5) out_proj GEMM (256x128 pipelined, 256 blocks = exact 1 round)
  gemm2_256x128<<<256, 512, 0, stream>>>(
      (const ushort*)(proj + COL_HS), w216, out);
}

// Round 11
// 405.070 us; speedup vs baseline: 11.3736x; 1.0631x over previous
//
#include <hip/hip_runtime.h>
#include <hip/hip_bf16.h>
#include <cstddef>
#include <cstdint>

// Problem constants
#define HID   2048
#define INTER 4096
#define NH    64
#define HD    64
#define NST   128
#define CONV_DIM 4352           // INTER + 2*NST
#define PROJ  8512              // INTER + CONV_DIM + NH
#define PROJ_PAD 8704           // 34 * 256
#define SS    2048
#define BB    2
#define BS    (BB*SS)           // 4096 rows
#define EPS   1e-5f

// proj column layout: [0,4096)=gate [4096,8192)=hs [8192,8320)=B [8320,8448)=C [8448,8512)=dt
#define COL_HS 4096
#define COL_B  8192
#define COL_C  8320
#define COL_DT 8448

// xbc column layout: [0,4096)=x [4096,4224)=B [4224,4352)=C
#define XBC_B  4096
#define XBC_C  4224

#define CV8   (CONV_DIM / 8)    // 544

// SSD chunking
#define CL    128               // chunk length
#define NCHK  16                // SS / CL

typedef short s16x8 __attribute__((ext_vector_type(8)));
typedef float f32x4 __attribute__((ext_vector_type(4)));

__device__ inline ushort f2b(float x) {
  __hip_bfloat16 h = __float2bfloat16(x);
  return *(ushort*)&h;
}
__device__ inline float b2f(ushort u) {
  unsigned int v = ((unsigned int)u) << 16;
  return __uint_as_float(v);
}
// LDS tile: 256B rows (128 bf16), XOR-swizzled in 8-elem slots (T2)
__device__ inline int swz(int row, int e) { return row * 128 + (e ^ ((row & 7) << 3)); }

__device__ inline void gload16(const void* g, void* l) {
  __builtin_amdgcn_global_load_lds((const __attribute__((address_space(1))) void*)g,
                                   (__attribute__((address_space(3))) void*)l, 16, 0, 0);
}

// ---------------------------------------------------------------------------
// Merged fp32 -> bf16 conversion: hs | w1 (padded to 8704 rows) | w2
// ---------------------------------------------------------------------------
#define N4A  ((long)BS * HID / 4)
#define N4W1 ((long)PROJ_PAD * HID / 4)
#define N4W2 ((long)HID * INTER / 4)

__global__ __launch_bounds__(256) void convert_all(
    const float* __restrict__ hs, const float* __restrict__ w1,
    const float* __restrict__ w2, ushort* __restrict__ hs16,
    ushort* __restrict__ w1p, ushort* __restrict__ w216) {
  long i = (long)blockIdx.x * 256 + threadIdx.x;
  const float* src;
  ushort* dst;
  long e0;
  if (i < N4A) {
    src = hs; dst = hs16; e0 = i * 4;
  } else if (i < N4A + N4W1) {
    long k = i - N4A;
    e0 = k * 4;
    long row = e0 >> 11;  // / 2048
    if (row >= PROJ) {
      ushort4 z = {0, 0, 0, 0};
      *(ushort4*)(w1p + e0) = z;
      return;
    }
    src = w1; dst = w1p;
  } else if (i < N4A + N4W1 + N4W2) {
    long k = i - N4A - N4W1;
    src = w2; dst = w216; e0 = k * 4;
  } else {
    return;
  }
  float4 v = *(const float4*)(src + e0);
  ushort4 o;
  o.x = f2b(v.x); o.y = f2b(v.y); o.z = f2b(v.z); o.w = f2b(v.w);
  *(ushort4*)(dst + e0) = o;
}

// ---------------------------------------------------------------------------
// GEMM1: 256x256 4-phase pipelined bf16 MFMA GEMM (r8-proven, frozen).
// ---------------------------------------------------------------------------
__global__ __launch_bounds__(512, 2) void gemm256_8ph(
    const ushort* __restrict__ A, const ushort* __restrict__ Bw,
    ushort* __restrict__ C, float* __restrict__ dtbuf) {
  __shared__ ushort smem[65536];
  const int tid = threadIdx.x;
  const int lane = tid & 63;
  const int wid = tid >> 6;
  const int wm = wid >> 2;
  const int wn = wid & 3;
  const int r = lane & 15;
  const int kx = lane >> 4;

  const int fid = blockIdx.x;
  const int bcol = ((fid >> 7) << 3) + ((fid & 127) >> 4);   // 0..33
  const int brow = fid & 15;                                  // 0..15

  const ushort* Ag = A + (size_t)(brow * 256) * HID;
  const ushort* Bg = Bw + (size_t)(bcol * 256) * HID;

  const int srow = tid >> 3;
  const int scole = (((tid & 7) * 16) ^ ((srow & 7) << 4)) >> 1;

  auto stageA = [&](int buf, int kt, int half) {
    const ushort* g = Ag + (size_t)(half * 128 + srow) * HID + kt * 64 + scole;
    ushort* l = smem + buf * 16384 + half * 8192 + tid * 8;
    gload16(g, l);
    gload16(g + (size_t)64 * HID, l + 4096);
  };
  auto stageB = [&](int buf, int kt, int half) {
    const ushort* g = Bg + (size_t)(half * 128 + srow) * HID + kt * 64 + scole;
    ushort* l = smem + 32768 + buf * 16384 + half * 8192 + tid * 8;
    gload16(g, l);
    gload16(g + (size_t)64 * HID, l + 4096);
  };
  auto ldA = [&](int buf, int mf, int ks) -> s16x8 {
    int row = wm * 128 + mf * 16 + r;
    int cb = (ks * 64 + kx * 16) ^ ((row & 7) << 4);
    return *(const s16x8*)(smem + buf * 16384 + row * 64 + (cb >> 1));
  };
  auto ldB = [&](int buf, int nf, int ks) -> s16x8 {
    int row = wn * 64 + nf * 16 + r;
    int cb = (ks * 64 + kx * 16) ^ ((row & 7) << 4);
    return *(const s16x8*)(smem + 32768 + buf * 16384 + row * 64 + (cb >> 1));
  };

  f32x4 acc[8][4];
#pragma unroll
  for (int i = 0; i < 8; i++)
#pragma unroll
    for (int j = 0; j < 4; j++) acc[i][j] = (f32x4)0.f;

  constexpr int NT = HID / 64;   // 32 K-tiles

  stageA(0, 0, 0); stageA(0, 0, 1);
  stageB(0, 0, 0); stageB(0, 0, 1);
  stageA(1, 1, 0); stageA(1, 1, 1);
  asm volatile("s_waitcnt vmcnt(4)" ::: "memory");
  __builtin_amdgcn_s_barrier();

  int cur = 0;
  for (int t = 0; t < NT; t++) {
    s16x8 a[4][2], b[2][2], b2[2][2];
    // phase 1
#pragma unroll
    for (int mf = 0; mf < 4; mf++)
#pragma unroll
      for (int ks = 0; ks < 2; ks++) a[mf][ks] = ldA(cur, mf, ks);
#pragma unroll
    for (int nf = 0; nf < 2; nf++)
#pragma unroll
      for (int ks = 0; ks < 2; ks++) b[nf][ks] = ldB(cur, nf, ks);
    if (t + 1 < NT) stageB(cur ^ 1, t + 1, 0);
    __builtin_amdgcn_s_barrier();
    asm volatile("s_waitcnt lgkmcnt(0)" ::: "memory");
    __builtin_amdgcn_sched_barrier(0);
    __builtin_amdgcn_s_setprio(1);
#pragma unroll
    for (int mf = 0; mf < 4; mf++)
#pragma unroll
      for (int nf = 0; nf < 2; nf++)
#pragma unroll
        for (int ks = 0; ks < 2; ks++)
          acc[mf][nf] = __builtin_amdgcn_mfma_f32_16x16x32_bf16(a[mf][ks], b[nf][ks], acc[mf][nf], 0, 0, 0);
    __builtin_amdgcn_s_setprio(0);
    __builtin_amdgcn_s_barrier();
    // phase 2
#pragma unroll
    for (int nf = 0; nf < 2; nf++)
#pragma unroll
      for (int ks = 0; ks < 2; ks++) b2[nf][ks] = ldB(cur, nf + 2, ks);
    if (t + 1 < NT) stageB(cur ^ 1, t + 1, 1);
    __builtin_amdgcn_s_barrier();
    asm volatile("s_waitcnt lgkmcnt(0)" ::: "memory");
    __builtin_amdgcn_sched_barrier(0);
    __builtin_amdgcn_s_setprio(1);
#pragma unroll
    for (int mf = 0; mf < 4; mf++)
#pragma unroll
      for (int nf = 0; nf < 2; nf++)
#pragma unroll
        for (int ks = 0; ks < 2; ks++)
          acc[mf][nf + 2] = __builtin_amdgcn_mfma_f32_16x16x32_bf16(a[mf][ks], b2[nf][ks], acc[mf][nf + 2], 0, 0, 0);
    __builtin_amdgcn_s_setprio(0);
    __builtin_amdgcn_s_barrier();
    // phase 3
#pragma unroll
    for (int mf = 0; mf < 4; mf++)
#pragma unroll
      for (int ks = 0; ks < 2; ks++) a[mf][ks] = ldA(cur, mf + 4, ks);
    __builtin_amdgcn_s_barrier();
    asm volatile("s_waitcnt lgkmcnt(0)" ::: "memory");
    __builtin_amdgcn_sched_barrier(0);
    __builtin_amdgcn_s_setprio(1);
#pragma unroll
    for (int mf = 0; mf < 4; mf++)
#pragma unroll
      for (int nf = 0; nf < 2; nf++)
#pragma unroll
        for (int ks = 0; ks < 2; ks++)
          acc[mf + 4][nf] = __builtin_amdgcn_mfma_f32_16x16x32_bf16(a[mf][ks], b[nf][ks], acc[mf + 4][nf], 0, 0, 0);
    __builtin_amdgcn_s_setprio(0);
    __builtin_amdgcn_s_barrier();
    // phase 4
    if (t + 2 < NT) { stageA(cur, t + 2, 0); stageA(cur, t + 2, 1); }
    __builtin_amdgcn_s_setprio(1);
#pragma unroll
    for (int mf = 0; mf < 4; mf++)
#pragma unroll
      for (int nf = 0; nf < 2; nf++)
#pragma unroll
        for (int ks = 0; ks < 2; ks++)
          acc[mf + 4][nf + 2] = __builtin_amdgcn_mfma_f32_16x16x32_bf16(a[mf][ks], b2[nf][ks], acc[mf + 4][nf + 2], 0, 0, 0);
    __builtin_amdgcn_s_setprio(0);
    if (t + 2 < NT) {
      asm volatile("s_waitcnt vmcnt(4)" ::: "memory");
    } else {
      asm volatile("s_waitcnt vmcnt(0)" ::: "memory");
    }
    __builtin_amdgcn_s_barrier();
    cur ^= 1;
  }

  const int m0 = brow * 256 + wm * 128 + (lane >> 4) * 4;
  const int n0 = bcol * 256 + wn * 64 + r;
#pragma unroll
  for (int mf = 0; mf < 8; mf++) {
#pragma unroll
    for (int nf = 0; nf < 4; nf++) {
      int n = n0 + nf * 16;
      if (n >= PROJ) continue;
#pragma unroll
      for (int q = 0; q < 4; q++) {
        float v = acc[mf][nf][q];
        int m = m0 + mf * 16 + q;
        C[(size_t)m * PROJ + n] = f2b(v);
        if (n >= COL_DT) dtbuf[(size_t)m * 64 + (n - COL_DT)] = v;
      }
    }
  }
}

// ---------------------------------------------------------------------------
// GEMM2: 256x128-tile pipelined bf16 MFMA GEMM (r8-proven, frozen).
// ---------------------------------------------------------------------------
__global__ __launch_bounds__(512, 2) void gemm2_256x128(
    const ushort* __restrict__ A, const ushort* __restrict__ Bw,
    float* __restrict__ C) {
  __shared__ ushort smem[49152];
  const int tid = threadIdx.x;
  const int lane = tid & 63;
  const int wid = tid >> 6;
  const int wm = wid >> 1;
  const int wn = wid & 1;
  const int r = lane & 15;
  const int kx = lane >> 4;

  const int fid = blockIdx.x;      // 256 blocks
  const int bcol = fid >> 4;
  const int brow = fid & 15;

  const ushort* Ag = A + (size_t)(brow * 256) * PROJ;
  const ushort* Bg = Bw + (size_t)(bcol * 128) * INTER;

  const int srow = tid >> 3;
  const int scole = (((tid & 7) * 16) ^ ((srow & 7) << 4)) >> 1;

  auto stageA2 = [&](int buf, int kt) {
#pragma unroll
    for (int i = 0; i < 4; i++) {
      gload16(Ag + (size_t)(i * 64 + srow) * PROJ + kt * 64 + scole,
              smem + buf * 16384 + i * 4096 + tid * 8);
    }
  };
  auto stageB2 = [&](int buf, int kt) {
#pragma unroll
    for (int i = 0; i < 2; i++) {
      gload16(Bg + (size_t)(i * 64 + srow) * INTER + kt * 64 + scole,
              smem + 32768 + buf * 8192 + i * 4096 + tid * 8);
    }
  };
  auto ldA2 = [&](int buf, int mf, int ks) -> s16x8 {
    int row = wm * 64 + mf * 16 + r;
    int cb = (ks * 64 + kx * 16) ^ ((row & 7) << 4);
    return *(const s16x8*)(smem + buf * 16384 + row * 64 + (cb >> 1));
  };
  auto ldB2 = [&](int buf, int nf, int ks) -> s16x8 {
    int row = wn * 64 + nf * 16 + r;
    int cb = (ks * 64 + kx * 16) ^ ((row & 7) << 4);
    return *(const s16x8*)(smem + 32768 + buf * 8192 + row * 64 + (cb >> 1));
  };

  f32x4 acc[4][4];
#pragma unroll
  for (int i = 0; i < 4; i++)
#pragma unroll
    for (int j = 0; j < 4; j++) acc[i][j] = (f32x4)0.f;

  constexpr int NT = INTER / 64;   // 64 K-tiles

  stageA2(0, 0); stageB2(0, 0);
  stageA2(1, 1); stageB2(1, 1);
  asm volatile("s_waitcnt vmcnt(6)" ::: "memory");
  __builtin_amdgcn_s_barrier();

  int cur = 0;
  for (int t = 0; t < NT; t++) {
    s16x8 a[4][2], b[4][2];
#pragma unroll
    for (int mf = 0; mf < 4; mf++)
#pragma unroll
      for (int ks = 0; ks < 2; ks++) a[mf][ks] = ldA2(cur, mf, ks);
#pragma unroll
    for (int nf = 0; nf < 4; nf++)
#pragma unroll
      for (int ks = 0; ks < 2; ks++) b[nf][ks] = ldB2(cur, nf, ks);
    __builtin_amdgcn_s_barrier();
    asm volatile("s_waitcnt lgkmcnt(0)" ::: "memory");
    __builtin_amdgcn_sched_barrier(0);
    __builtin_amdgcn_s_setprio(1);
#pragma unroll
    for (int mf = 0; mf < 4; mf++)
#pragma unroll
      for (int nf = 0; nf < 2; nf++)
#pragma unroll
        for (int ks = 0; ks < 2; ks++)
          acc[mf][nf] = __builtin_amdgcn_mfma_f32_16x16x32_bf16(a[mf][ks], b[nf][ks], acc[mf][nf], 0, 0, 0);
    __builtin_amdgcn_s_setprio(0);
    __builtin_amdgcn_s_barrier();
    if (t + 2 < NT) { stageA2(cur, t + 2); stageB2(cur, t + 2); }
    __builtin_amdgcn_s_setprio(1);
#pragma unroll
    for (int mf = 0; mf < 4; mf++)
#pragma unroll
      for (int nf = 2; nf < 4; nf++)
#pragma unroll
        for (int ks = 0; ks < 2; ks++)
          acc[mf][nf] = __builtin_amdgcn_mfma_f32_16x16x32_bf16(a[mf][ks], b[nf][ks], acc[mf][nf], 0, 0, 0);
    __builtin_amdgcn_s_setprio(0);
    if (t + 2 < NT) {
      asm volatile("s_waitcnt vmcnt(6)" ::: "memory");
    } else {
      asm volatile("s_waitcnt vmcnt(0)" ::: "memory");
    }
    __builtin_amdgcn_s_barrier();
    cur ^= 1;
  }

  const int m0 = brow * 256 + wm * 64 + (lane >> 4) * 4;
  const int n0 = bcol * 128 + wn * 64 + r;
#pragma unroll
  for (int mf = 0; mf < 4; mf++) {
#pragma unroll
    for (int nf = 0; nf < 4; nf++) {
      int n = n0 + nf * 16;
#pragma unroll
      for (int q = 0; q < 4; q++)
        C[(size_t)(m0 + mf * 16 + q) * HID + n] = acc[mf][nf][q];
    }
  }
}

// ---------------------------------------------------------------------------
// Fused causal depthwise conv1d (K=4) + bias + SiLU, OUT-OF-PLACE to xbc.
// Thread = (b, s-block of 8, channel-group of 8). Reads raw proj, writes xbc.
// ---------------------------------------------------------------------------
__global__ __launch_bounds__(256) void conv_fused(
    const ushort* __restrict__ proj, ushort* __restrict__ xbc,
    const float* __restrict__ cw, const float* __restrict__ cb) {
  int idx = blockIdx.x * 256 + threadIdx.x;
  const int total = BB * (SS / 8) * CV8;
  if (idx >= total) return;
  int c8 = idx % CV8;
  int t = idx / CV8;
  int s8 = t % (SS / 8);
  int b = t / (SS / 8);
  const int c0 = c8 * 8;
  const int s0 = s8 * 8;
  float w0[8], w1[8], w2[8], w3[8], bias[8], h1[8], h2[8], h3[8];
#pragma unroll
  for (int e = 0; e < 8; e++) {
    float4 wv = *(const float4*)(cw + (c0 + e) * 4);
    w0[e] = wv.x; w1[e] = wv.y; w2[e] = wv.z; w3[e] = wv.w;
    bias[e] = cb[c0 + e];
  }
  const ushort* src = proj + ((size_t)b * SS + s0) * PROJ + COL_HS + c0;
  // history rows s0-1, s0-2, s0-3 (raw proj values; zero before s=0)
  {
    s16x8 v1 = {0,0,0,0,0,0,0,0}, v2 = v1, v3 = v1;
    if (s0 >= 1) v1 = *(const s16x8*)(src - (size_t)1 * PROJ);
    if (s0 >= 2) v2 = *(const s16x8*)(src - (size_t)2 * PROJ);
    if (s0 >= 3) v3 = *(const s16x8*)(src - (size_t)3 * PROJ);
#pragma unroll
    for (int e = 0; e < 8; e++) {
      h1[e] = b2f((ushort)v1[e]);
      h2[e] = b2f((ushort)v2[e]);
      h3[e] = b2f((ushort)v3[e]);
    }
  }
  ushort* dst = xbc + ((size_t)b * SS + s0) * CONV_DIM + c0;
#pragma unroll
  for (int s = 0; s < 8; s++) {
    s16x8 xv = *(const s16x8*)(src + (size_t)s * PROJ);
    s16x8 ov;
#pragma unroll
    for (int e = 0; e < 8; e++) {
      float x = b2f((ushort)xv[e]);
      float o = w3[e] * x + w2[e] * h1[e] + w1[e] * h2[e] + w0[e] * h3[e] + bias[e];
      o = o / (1.f + __expf(-o));    // SiLU
      ov[e] = (short)f2b(o);
      h3[e] = h2[e]; h2[e] = h1[e]; h1[e] = x;
    }
    *(s16x8*)(dst + (size_t)s * CONV_DIM) = ov;
  }
}

// ---------------------------------------------------------------------------
// SSD K1: per (b,h,chunk): softplus(dt), shuffle cumsum, chunk state (MFMA).
// Reads X/B from xbc. states written TRANSPOSED: [d=64][n=128]
// ---------------------------------------------------------------------------
__global__ __launch_bounds__(256) void ssd_chunk_state(
    const ushort* __restrict__ xbc, const float* __restrict__ dtf,
    const float* __restrict__ dt_bias, const float* __restrict__ A_log,
    ushort* __restrict__ states, float* __restrict__ cumbuf,
    float* __restrict__ dtvbuf) {
  const int bid = blockIdx.x;
  const int c = bid & 15;
  const int h = (bid >> 4) & 63;
  const int b = bid >> 10;
  const int tid = threadIdx.x;
  const int lane = tid & 63;
  const int wv = tid >> 6;
  __shared__ float sdtv[CL], scum[CL], sw[CL];
  __shared__ float wtot[2];
  __shared__ ushort sBt[128 * 128];   // [n][t]
  __shared__ ushort sXw[64 * 128];    // [d][t] scaled
  const size_t row0 = (size_t)b * SS + (size_t)c * CL;
  const size_t bh = (size_t)(b * NH + h);

  const float Ah = -__expf(A_log[h]);
  float dtvv = 0.f, v = 0.f;
  if (tid < CL) {
    float z = dtf[(row0 + tid) * 64 + h] + dt_bias[h];
    dtvv = (z > 20.f) ? z : log1pf(__expf(z));
    v = dtvv * Ah;
  }
#pragma unroll
  for (int off = 1; off < 64; off <<= 1) {
    float u = __shfl_up(v, off);
    if (lane >= off) v += u;
  }
  if (tid < CL && lane == 63) wtot[wv] = v;
  __syncthreads();
  if (wv == 1) v += wtot[0];
  if (tid < CL) {
    sdtv[tid] = dtvv;
    scum[tid] = v;
    cumbuf[bh * SS + c * CL + tid] = v;
    dtvbuf[bh * SS + c * CL + tid] = dtvv;
  }
  __syncthreads();
  const float cumL = scum[CL - 1];
  if (tid < CL) sw[tid] = __expf(cumL - v) * dtvv;
  __syncthreads();

  // stage B^T [n][t]
  {
    const int t = tid >> 1, n0 = (tid & 1) * 64;
    const ushort* src = xbc + (row0 + t) * CONV_DIM + XBC_B + n0;
#pragma unroll
    for (int j = 0; j < 64; j += 8) {
      s16x8 vv = *(const s16x8*)(src + j);
#pragma unroll
      for (int e = 0; e < 8; e++) sBt[swz(n0 + j + e, t)] = (ushort)vv[e];
    }
  }
  // stage Xw^T [d][t] scaled by sw[t]
  {
    const int d = tid & 63;
    const int t0 = (tid >> 6) * 32;
    for (int t = t0; t < t0 + 32; t++) {
      float x = b2f(xbc[(row0 + t) * CONV_DIM + h * 64 + d]);
      sXw[swz(d, t)] = f2b(x * sw[t]);
    }
  }
  __syncthreads();

  const int r = lane & 15, kx = lane >> 4;
  f32x4 acc[2][4];
#pragma unroll
  for (int i = 0; i < 2; i++)
#pragma unroll
    for (int j = 0; j < 4; j++) acc[i][j] = (f32x4)0.f;
#pragma unroll
  for (int kk = 0; kk < 4; kk++) {
    s16x8 a[2], bo[4];
#pragma unroll
    for (int i = 0; i < 2; i++)
      a[i] = *(const s16x8*)&sBt[swz(wv * 32 + i * 16 + r, kk * 32 + kx * 8)];
#pragma unroll
    for (int j = 0; j < 4; j++)
      bo[j] = *(const s16x8*)&sXw[swz(j * 16 + r, kk * 32 + kx * 8)];
#pragma unroll
    for (int i = 0; i < 2; i++)
#pragma unroll
      for (int j = 0; j < 4; j++)
        acc[i][j] = __builtin_amdgcn_mfma_f32_16x16x32_bf16(a[i], bo[j], acc[i][j], 0, 0, 0);
  }
  ushort* dst = states + (size_t)bid * (128 * 64);
#pragma unroll
  for (int i = 0; i < 2; i++) {
#pragma unroll
    for (int j = 0; j < 4; j++) {
      int n = wv * 32 + i * 16 + (lane >> 4) * 4;
      int d = (lane & 15) + j * 16;
      ushort4 o;
      o.x = f2b(acc[i][j][0]);
      o.y = f2b(acc[i][j][1]);
      o.z = f2b(acc[i][j][2]);
      o.w = f2b(acc[i][j][3]);
      *(ushort4*)(dst + (size_t)d * 128 + n) = o;
    }
  }
}

// ---------------------------------------------------------------------------
// SSD K2: inter-chunk recurrence. Block = (bh, d-half): 256 blocks.
// ---------------------------------------------------------------------------
__global__ __launch_bounds__(256) void ssd_state_scan(
    ushort* __restrict__ states, const float* __restrict__ cumbuf) {
  const int bh = blockIdx.x >> 1;
  const int half = blockIdx.x & 1;
  const int tid = threadIdx.x;
  float run[16];
#pragma unroll
  for (int i = 0; i < 16; i++) run[i] = 0.f;
  for (int c = 0; c < NCHK; c++) {
    float dec = __expf(cumbuf[(size_t)bh * SS + c * CL + (CL - 1)]);
    ushort* p = states + ((size_t)bh * NCHK + c) * 8192 + half * 4096 + tid * 16;
    s16x8 in[2];
#pragma unroll
    for (int v = 0; v < 2; v++) in[v] = *(const s16x8*)(p + v * 8);
    s16x8 out[2];
#pragma unroll
    for (int v = 0; v < 2; v++) {
#pragma unroll
      for (int e = 0; e < 8; e++) {
        int i = v * 8 + e;
        out[v][e] = (short)f2b(run[i]);
        run[i] = dec * run[i] + b2f((ushort)in[v][e]);
      }
    }
#pragma unroll
    for (int v = 0; v < 2; v++) *(s16x8*)(p + v * 8) = out[v];
  }
}

// ---------------------------------------------------------------------------
// SSD K3 (slim): LDS = sB + sX = 48KB. B/X/C read from xbc; C fragments read
// once from global, reused for G and Yi. y written in-place to proj hs cols.
// ---------------------------------------------------------------------------
__global__ __launch_bounds__(256, 2) void ssd_chunk_out(
    ushort* __restrict__ proj, const ushort* __restrict__ xbc,
    const ushort* __restrict__ states, const float* __restrict__ cumbuf,
    const float* __restrict__ dtvbuf, const float* __restrict__ Dp) {
  const int bid = blockIdx.x;
  const int c = bid & 15;
  const int h = (bid >> 4) & 63;
  const int b = bid >> 10;
  const int tid = threadIdx.x;
  const int lane = tid & 63;
  const int wv = tid >> 6;
  __shared__ ushort sB[128 * 128];   // B [tau][n] -> later P [t][tau]
  __shared__ ushort sX[64 * 128];    // X^T [d][t]
  const size_t row0 = (size_t)b * SS + (size_t)c * CL;
  const size_t bh = (size_t)(b * NH + h);
  const float* cumb = cumbuf + bh * SS + c * CL;
  const float* dtvb = dtvbuf + bh * SS + c * CL;
  const int r = lane & 15, kx = lane >> 4;

  float ct[2][4];
#pragma unroll
  for (int i = 0; i < 2; i++)
#pragma unroll
    for (int q = 0; q < 4; q++)
      ct[i][q] = cumb[wv * 32 + i * 16 + ((lane >> 4) << 2) + q];
  float cumt[8], dvt[8];
#pragma unroll
  for (int j = 0; j < 8; j++) {
    int tau = j * 16 + (lane & 15);
    cumt[j] = cumb[tau];
    dvt[j] = dtvb[tau];
  }

  // stage B [t][n] from xbc
  {
    const int t = tid >> 1, n0 = (tid & 1) * 64;
    const ushort* srcB = xbc + (row0 + t) * CONV_DIM + XBC_B + n0;
#pragma unroll
    for (int j = 0; j < 64; j += 8)
      *(s16x8*)&sB[swz(t, n0 + j)] = *(const s16x8*)(srcB + j);
  }
  // stage X^T [d][t] from xbc
  {
    const int d = tid & 63;
    const int t0 = (tid >> 6) * 32;
    for (int t = t0; t < t0 + 32; t++)
      sX[swz(d, t)] = xbc[(row0 + t) * CONV_DIM + h * 64 + d];
  }
  // prefetch C fragments from xbc (16B aligned, L2-hot)
  s16x8 cf[4][2];
#pragma unroll
  for (int kk = 0; kk < 4; kk++)
#pragma unroll
    for (int i = 0; i < 2; i++)
      cf[kk][i] = *(const s16x8*)(xbc + (row0 + wv * 32 + i * 16 + r) * CONV_DIM
                                  + XBC_C + kk * 32 + kx * 8);
  __syncthreads();

  // Phase G: G = C @ B^T
  f32x4 g[2][8];
#pragma unroll
  for (int i = 0; i < 2; i++)
#pragma unroll
    for (int j = 0; j < 8; j++) g[i][j] = (f32x4)0.f;
#pragma unroll
  for (int kk = 0; kk < 4; kk++) {
    s16x8 bo[8];
#pragma unroll
    for (int j = 0; j < 8; j++)
      bo[j] = *(const s16x8*)&sB[swz(j * 16 + r, kk * 32 + kx * 8)];
#pragma unroll
    for (int i = 0; i < 2; i++)
#pragma unroll
      for (int j = 0; j < 8; j++)
        g[i][j] = __builtin_amdgcn_mfma_f32_16x16x32_bf16(cf[kk][i], bo[j], g[i][j], 0, 0, 0);
  }

  // Phase Yi: yi = C @ Sp^T (unscaled; exp(ct) applied in epilogue)
  f32x4 yi[2][4];
#pragma unroll
  for (int i = 0; i < 2; i++)
#pragma unroll
    for (int j = 0; j < 4; j++) yi[i][j] = (f32x4)0.f;
  {
    const ushort* sp = states + (size_t)bid * 8192;
#pragma unroll
    for (int kk = 0; kk < 4; kk++) {
      s16x8 spk[4];
#pragma unroll
      for (int j = 0; j < 4; j++)
        spk[j] = *(const s16x8*)(sp + (size_t)(j * 16 + r) * 128 + kk * 32 + kx * 8);
#pragma unroll
      for (int i = 0; i < 2; i++)
#pragma unroll
        for (int j = 0; j < 4; j++)
          yi[i][j] = __builtin_amdgcn_mfma_f32_16x16x32_bf16(cf[kk][i], spk[j], yi[i][j], 0, 0, 0);
    }
  }
  __syncthreads();   // all waves done reading sB as B

  // Phase P: write P[t][tau] over sB
#pragma unroll
  for (int j = 0; j < 8; j++) {
    float cu = cumt[j], dv = dvt[j];
    int tau = j * 16 + (lane & 15);
#pragma unroll
    for (int i = 0; i < 2; i++) {
#pragma unroll
      for (int q = 0; q < 4; q++) {
        int t = wv * 32 + i * 16 + ((lane >> 4) << 2) + q;
        float val = (tau <= t) ? g[i][j][q] * __expf(ct[i][q] - cu) * dv : 0.f;
        sB[swz(t, tau)] = f2b(val);
      }
    }
  }
  __syncthreads();

  // Phase Y: y = P @ X^T
  f32x4 y[2][4];
#pragma unroll
  for (int i = 0; i < 2; i++)
#pragma unroll
    for (int j = 0; j < 4; j++) y[i][j] = (f32x4)0.f;
#pragma unroll
  for (int kk = 0; kk < 4; kk++) {
    s16x8 a[2], bo[4];
#pragma unroll
    for (int i = 0; i < 2; i++)
      a[i] = *(const s16x8*)&sB[swz(wv * 32 + i * 16 + r, kk * 32 + kx * 8)];
#pragma unroll
    for (int j = 0; j < 4; j++)
      bo[j] = *(const s16x8*)&sX[swz(j * 16 + r, kk * 32 + kx * 8)];
#pragma unroll
    for (int i = 0; i < 2; i++)
#pragma unroll
      for (int j = 0; j < 4; j++)
        y[i][j] = __builtin_amdgcn_mfma_f32_16x16x32_bf16(a[i], bo[j], y[i][j], 0, 0, 0);
  }

  // Epilogue: out = y + exp(ct)*yi + D*x  -> proj hs cols
  const float Dh = Dp[h];
  float eP[2][4];
#pragma unroll
  for (int i = 0; i < 2; i++)
#pragma unroll
    for (int q = 0; q < 4; q++) eP[i][q] = __expf(ct[i][q]);
#pragma unroll
  for (int i = 0; i < 2; i++) {
#pragma unroll
    for (int j = 0; j < 4; j++) {
      int t0 = wv * 32 + i * 16 + (lane >> 4) * 4;
      int d = (lane & 15) + j * 16;
#pragma unroll
      for (int q = 0; q < 4; q++) {
        float x = b2f(sX[swz(d, t0 + q)]);
        proj[(row0 + t0 + q) * PROJ + COL_HS + h * 64 + d] =
            f2b(y[i][j][q] + eP[i][q] * yi[i][j][q] + Dh * x);
      }
    }
  }
}

// ---------------------------------------------------------------------------
// Gated RMSNorm, bf16 in / bf16 in-place out over proj hs columns
// ---------------------------------------------------------------------------
__global__ __launch_bounds__(256) void rmsnorm_kernel(
    ushort* __restrict__ proj, const float* __restrict__ nw) {
  const int row = blockIdx.x;
  const int tid = threadIdx.x;
  ushort* yp = proj + (size_t)row * PROJ + COL_HS;
  const ushort* gp = proj + (size_t)row * PROJ;
  float v[16];
  float ss = 0.f;
#pragma unroll
  for (int q = 0; q < 4; q++) {
    int col = q * 1024 + tid * 4;
    ushort4 yv = *(const ushort4*)(yp + col);
    ushort4 gv = *(const ushort4*)(gp + col);
    float vy[4] = {b2f(yv.x), b2f(yv.y), b2f(yv.z), b2f(yv.w)};
    float vg[4] = {b2f(gv.x), b2f(gv.y), b2f(gv.z), b2f(gv.w)};
#pragma unroll
    for (int j = 0; j < 4; j++) {
      float sg = vg[j] / (1.f + __expf(-vg[j]));
      float vv = vy[j] * sg;
      v[q * 4 + j] = vv;
      ss += vv * vv;
    }
  }
#pragma unroll
  for (int o = 1; o < 64; o <<= 1) ss += __shfl_xor(ss, o);
  __shared__ float red[4];
  if ((tid & 63) == 0) red[tid >> 6] = ss;
  __syncthreads();
  float tot = red[0] + red[1] + red[2] + red[3];
  float scale = rsqrtf(tot * (1.f / INTER) + EPS);
#pragma unroll
  for (int q = 0; q < 4; q++) {
    int col = q * 1024 + tid * 4;
    float4 w = *(const float4*)(nw + col);
    ushort4 o;
    o.x = f2b(v[q * 4 + 0] * scale * w.x);
    o.y = f2b(v[q * 4 + 1] * scale * w.y);
    o.z = f2b(v[q * 4 + 2] * scale * w.z);
    o.w = f2b(v[q * 4 + 3] * scale * w.w);
    *(ushort4*)(yp + col) = o;
  }
}

// ---------------------------------------------------------------------------
extern "C" void kernel_launch(void* const* d_in, const int* in_sizes, int n_in,
                              void* d_out, int out_size, void* d_ws, size_t ws_size,
                              hipStream_t stream) {
  const float* hs   = (const float*)d_in[0];
  const float* w1   = (const float*)d_in[1];
  const float* cw   = (const float*)d_in[2];
  const float* cb   = (const float*)d_in[3];
  const float* dtb  = (const float*)d_in[4];
  const float* alog = (const float*)d_in[5];
  const float* Dp   = (const float*)d_in[6];
  const float* nw   = (const float*)d_in[7];
  const float* w2   = (const float*)d_in[8];
  float* out = (float*)d_out;

  // ws layout
  char* base = (char*)d_ws;
  size_t off = 0;
  ushort* proj = (ushort*)(base + off); off += (size_t)BS * PROJ * 2;          // 69.7 MB
  off = (off + 255) & ~(size_t)255;
  ushort* xbc = (ushort*)(base + off); off += (size_t)BS * CONV_DIM * 2;       // 35.7 MB
  off = (off + 255) & ~(size_t)255;
  float* dtbuf = (float*)(base + off); off += (size_t)BS * 64 * 4;             // 1.05 MB
  off = (off + 255) & ~(size_t)255;
  ushort* w216 = (ushort*)(base + off); off += (size_t)HID * INTER * 2;        // 16.78 MB
  off = (off + 255) & ~(size_t)255;
  char* rC = base + off;
  // phase 1 tenants:
  ushort* hs16 = (ushort*)rC;                                 // 16.78 MB
  ushort* w1p  = (ushort*)(rC + 16777216);                    // 35.65 MB (8704x2048)
  // phase 2 tenants (after GEMM1; hs16/w1p dead):
  ushort* states = (ushort*)rC;                               // 33.55 MB
  float*  cumbuf = (float*)(rC + 33554432);                   // 1.05 MB
  float*  dtvbuf = (float*)(rC + 33554432 + 1048576);         // 1.05 MB

  // 0) merged fp32 -> bf16 conversions (hs, w1 padded, w2)
  {
    long n4 = N4A + N4W1 + N4W2;
    convert_all<<<(int)((n4 + 255) / 256), 256, 0, stream>>>(hs, w1, w2, hs16, w1p, w216);
  }

  // 1) in_proj GEMM (256^2, 544 blocks): proj(bf16) = hs @ w1^T ; dt sidecar
  gemm256_8ph<<<(BS / 256) * (PROJ_PAD / 256), 512, 0, stream>>>(hs16, w1p, proj, dtbuf);

  // 2) fused causal depthwise conv + SiLU (out-of-place -> xbc)
  conv_fused<<<(BB * (SS / 8) * CV8 + 255) / 256, 256, 0, stream>>>(proj, xbc, cw, cb);

  // 3) SSD chunked scan
  ssd_chunk_state<<<BB * NH * NCHK, 256, 0, stream>>>(xbc, dtbuf, dtb, alog, states, cumbuf, dtvbuf);
  ssd_state_scan<<<BB * NH * 2, 256, 0, stream>>>(states, cumbuf);
  ssd_chunk_out<<<BB * NH * NCHK, 256, 0, stream>>>(proj, xbc, states, cumbuf, dtvbuf, Dp);

  // 4) gated RMSNorm (in place over proj hs columns)
  rmsnorm_kernel<<<BS, 256, 0, stream>>>(proj, nw);

  // 5) out_proj GEMM (256x128 pipelined, 256 blocks = exact 1 round)
  gemm2_256x128<<<256, 512, 0, stream>>>(
      (const ushort*)(proj + COL_HS), w216, out);
}

// Round 12
// 403.123 us; speedup vs baseline: 11.4285x; 1.0048x over previous
//
#include <hip/hip_runtime.h>
#include <hip/hip_bf16.h>
#include <cstddef>
#include <cstdint>

// Problem constants
#define HID   2048
#define INTER 4096
#define NH    64
#define HD    64
#define NST   128
#define CONV_DIM 4352           // INTER + 2*NST
#define PROJ  8512              // INTER + CONV_DIM + NH
#define PROJ_PAD 8704           // 34 * 256
#define SS    2048
#define BB    2
#define BS    (BB*SS)           // 4096 rows
#define EPS   1e-5f

// proj column layout: [0,4096)=gate [4096,8192)=hs [8192,8320)=B [8320,8448)=C [8448,8512)=dt
#define COL_HS 4096
#define COL_B  8192
#define COL_C  8320
#define COL_DT 8448

// xbc column layout: [0,4096)=x [4096,4224)=B [4224,4352)=C
#define XBC_B  4096
#define XBC_C  4224

#define CV8   (CONV_DIM / 8)    // 544

// SSD chunking
#define CL    128               // chunk length
#define NCHK  16                // SS / CL

typedef short s16x8 __attribute__((ext_vector_type(8)));
typedef float f32x4 __attribute__((ext_vector_type(4)));

__device__ inline ushort f2b(float x) {
  __hip_bfloat16 h = __float2bfloat16(x);
  return *(ushort*)&h;
}
__device__ inline float b2f(ushort u) {
  unsigned int v = ((unsigned int)u) << 16;
  return __uint_as_float(v);
}
// LDS tile: 256B rows (128 bf16), XOR-swizzled in 8-elem slots (T2)
__device__ inline int swz(int row, int e) { return row * 128 + (e ^ ((row & 7) << 3)); }

__device__ inline void gload16(const void* g, void* l) {
  __builtin_amdgcn_global_load_lds((const __attribute__((address_space(1))) void*)g,
                                   (__attribute__((address_space(3))) void*)l, 16, 0, 0);
}

// ---------------------------------------------------------------------------
// Merged fp32 -> bf16 conversion: hs | w1 (padded to 8704 rows) | w2
// ---------------------------------------------------------------------------
#define N4A  ((long)BS * HID / 4)
#define N4W1 ((long)PROJ_PAD * HID / 4)
#define N4W2 ((long)HID * INTER / 4)

__global__ __launch_bounds__(256) void convert_all(
    const float* __restrict__ hs, const float* __restrict__ w1,
    const float* __restrict__ w2, ushort* __restrict__ hs16,
    ushort* __restrict__ w1p, ushort* __restrict__ w216) {
  long i = (long)blockIdx.x * 256 + threadIdx.x;
  const float* src;
  ushort* dst;
  long e0;
  if (i < N4A) {
    src = hs; dst = hs16; e0 = i * 4;
  } else if (i < N4A + N4W1) {
    long k = i - N4A;
    e0 = k * 4;
    long row = e0 >> 11;  // / 2048
    if (row >= PROJ) {
      ushort4 z = {0, 0, 0, 0};
      *(ushort4*)(w1p + e0) = z;
      return;
    }
    src = w1; dst = w1p;
  } else if (i < N4A + N4W1 + N4W2) {
    long k = i - N4A - N4W1;
    src = w2; dst = w216; e0 = k * 4;
  } else {
    return;
  }
  float4 v = *(const float4*)(src + e0);
  ushort4 o;
  o.x = f2b(v.x); o.y = f2b(v.y); o.z = f2b(v.z); o.w = f2b(v.w);
  *(ushort4*)(dst + e0) = o;
}

// ---------------------------------------------------------------------------
// GEMM1: 256x256 4-phase pipelined bf16 MFMA GEMM (r8-proven, frozen).
// ---------------------------------------------------------------------------
__global__ __launch_bounds__(512, 2) void gemm256_8ph(
    const ushort* __restrict__ A, const ushort* __restrict__ Bw,
    ushort* __restrict__ C, float* __restrict__ dtbuf) {
  __shared__ ushort smem[65536];
  const int tid = threadIdx.x;
  const int lane = tid & 63;
  const int wid = tid >> 6;
  const int wm = wid >> 2;
  const int wn = wid & 3;
  const int r = lane & 15;
  const int kx = lane >> 4;

  const int fid = blockIdx.x;
  const int bcol = ((fid >> 7) << 3) + ((fid & 127) >> 4);   // 0..33
  const int brow = fid & 15;                                  // 0..15

  const ushort* Ag = A + (size_t)(brow * 256) * HID;
  const ushort* Bg = Bw + (size_t)(bcol * 256) * HID;

  const int srow = tid >> 3;
  const int scole = (((tid & 7) * 16) ^ ((srow & 7) << 4)) >> 1;

  auto stageA = [&](int buf, int kt, int half) {
    const ushort* g = Ag + (size_t)(half * 128 + srow) * HID + kt * 64 + scole;
    ushort* l = smem + buf * 16384 + half * 8192 + tid * 8;
    gload16(g, l);
    gload16(g + (size_t)64 * HID, l + 4096);
  };
  auto stageB = [&](int buf, int kt, int half) {
    const ushort* g = Bg + (size_t)(half * 128 + srow) * HID + kt * 64 + scole;
    ushort* l = smem + 32768 + buf * 16384 + half * 8192 + tid * 8;
    gload16(g, l);
    gload16(g + (size_t)64 * HID, l + 4096);
  };
  auto ldA = [&](int buf, int mf, int ks) -> s16x8 {
    int row = wm * 128 + mf * 16 + r;
    int cb = (ks * 64 + kx * 16) ^ ((row & 7) << 4);
    return *(const s16x8*)(smem + buf * 16384 + row * 64 + (cb >> 1));
  };
  auto ldB = [&](int buf, int nf, int ks) -> s16x8 {
    int row = wn * 64 + nf * 16 + r;
    int cb = (ks * 64 + kx * 16) ^ ((row & 7) << 4);
    return *(const s16x8*)(smem + 32768 + buf * 16384 + row * 64 + (cb >> 1));
  };

  f32x4 acc[8][4];
#pragma unroll
  for (int i = 0; i < 8; i++)
#pragma unroll
    for (int j = 0; j < 4; j++) acc[i][j] = (f32x4)0.f;

  constexpr int NT = HID / 64;   // 32 K-tiles

  stageA(0, 0, 0); stageA(0, 0, 1);
  stageB(0, 0, 0); stageB(0, 0, 1);
  stageA(1, 1, 0); stageA(1, 1, 1);
  asm volatile("s_waitcnt vmcnt(4)" ::: "memory");
  __builtin_amdgcn_s_barrier();

  int cur = 0;
  for (int t = 0; t < NT; t++) {
    s16x8 a[4][2], b[2][2], b2[2][2];
    // phase 1
#pragma unroll
    for (int mf = 0; mf < 4; mf++)
#pragma unroll
      for (int ks = 0; ks < 2; ks++) a[mf][ks] = ldA(cur, mf, ks);
#pragma unroll
    for (int nf = 0; nf < 2; nf++)
#pragma unroll
      for (int ks = 0; ks < 2; ks++) b[nf][ks] = ldB(cur, nf, ks);
    if (t + 1 < NT) stageB(cur ^ 1, t + 1, 0);
    __builtin_amdgcn_s_barrier();
    asm volatile("s_waitcnt lgkmcnt(0)" ::: "memory");
    __builtin_amdgcn_sched_barrier(0);
    __builtin_amdgcn_s_setprio(1);
#pragma unroll
    for (int mf = 0; mf < 4; mf++)
#pragma unroll
      for (int nf = 0; nf < 2; nf++)
#pragma unroll
        for (int ks = 0; ks < 2; ks++)
          acc[mf][nf] = __builtin_amdgcn_mfma_f32_16x16x32_bf16(a[mf][ks], b[nf][ks], acc[mf][nf], 0, 0, 0);
    __builtin_amdgcn_s_setprio(0);
    __builtin_amdgcn_s_barrier();
    // phase 2
#pragma unroll
    for (int nf = 0; nf < 2; nf++)
#pragma unroll
      for (int ks = 0; ks < 2; ks++) b2[nf][ks] = ldB(cur, nf + 2, ks);
    if (t + 1 < NT) stageB(cur ^ 1, t + 1, 1);
    __builtin_amdgcn_s_barrier();
    asm volatile("s_waitcnt lgkmcnt(0)" ::: "memory");
    __builtin_amdgcn_sched_barrier(0);
    __builtin_amdgcn_s_setprio(1);
#pragma unroll
    for (int mf = 0; mf < 4; mf++)
#pragma unroll
      for (int nf = 0; nf < 2; nf++)
#pragma unroll
        for (int ks = 0; ks < 2; ks++)
          acc[mf][nf + 2] = __builtin_amdgcn_mfma_f32_16x16x32_bf16(a[mf][ks], b2[nf][ks], acc[mf][nf + 2], 0, 0, 0);
    __builtin_amdgcn_s_setprio(0);
    __builtin_amdgcn_s_barrier();
    // phase 3
#pragma unroll
    for (int mf = 0; mf < 4; mf++)
#pragma unroll
      for (int ks = 0; ks < 2; ks++) a[mf][ks] = ldA(cur, mf + 4, ks);
    __builtin_amdgcn_s_barrier();
    asm volatile("s_waitcnt lgkmcnt(0)" ::: "memory");
    __builtin_amdgcn_sched_barrier(0);
    __builtin_amdgcn_s_setprio(1);
#pragma unroll
    for (int mf = 0; mf < 4; mf++)
#pragma unroll
      for (int nf = 0; nf < 2; nf++)
#pragma unroll
        for (int ks = 0; ks < 2; ks++)
          acc[mf + 4][nf] = __builtin_amdgcn_mfma_f32_16x16x32_bf16(a[mf][ks], b[nf][ks], acc[mf + 4][nf], 0, 0, 0);
    __builtin_amdgcn_s_setprio(0);
    __builtin_amdgcn_s_barrier();
    // phase 4
    if (t + 2 < NT) { stageA(cur, t + 2, 0); stageA(cur, t + 2, 1); }
    __builtin_amdgcn_s_setprio(1);
#pragma unroll
    for (int mf = 0; mf < 4; mf++)
#pragma unroll
      for (int nf = 0; nf < 2; nf++)
#pragma unroll
        for (int ks = 0; ks < 2; ks++)
          acc[mf + 4][nf + 2] = __builtin_amdgcn_mfma_f32_16x16x32_bf16(a[mf][ks], b2[nf][ks], acc[mf + 4][nf + 2], 0, 0, 0);
    __builtin_amdgcn_s_setprio(0);
    if (t + 2 < NT) {
      asm volatile("s_waitcnt vmcnt(4)" ::: "memory");
    } else {
      asm volatile("s_waitcnt vmcnt(0)" ::: "memory");
    }
    __builtin_amdgcn_s_barrier();
    cur ^= 1;
  }

  const int m0 = brow * 256 + wm * 128 + (lane >> 4) * 4;
  const int n0 = bcol * 256 + wn * 64 + r;
#pragma unroll
  for (int mf = 0; mf < 8; mf++) {
#pragma unroll
    for (int nf = 0; nf < 4; nf++) {
      int n = n0 + nf * 16;
      if (n >= PROJ) continue;
#pragma unroll
      for (int q = 0; q < 4; q++) {
        float v = acc[mf][nf][q];
        int m = m0 + mf * 16 + q;
        C[(size_t)m * PROJ + n] = f2b(v);
        if (n >= COL_DT) dtbuf[(size_t)m * 64 + (n - COL_DT)] = v;
      }
    }
  }
}

// ---------------------------------------------------------------------------
// GEMM2: 256x128-tile pipelined bf16 MFMA GEMM (r8-proven). A dense lda=4096.
// ---------------------------------------------------------------------------
__global__ __launch_bounds__(512, 2) void gemm2_256x128(
    const ushort* __restrict__ A, const ushort* __restrict__ Bw,
    float* __restrict__ C) {
  __shared__ ushort smem[49152];
  const int tid = threadIdx.x;
  const int lane = tid & 63;
  const int wid = tid >> 6;
  const int wm = wid >> 1;
  const int wn = wid & 1;
  const int r = lane & 15;
  const int kx = lane >> 4;

  const int fid = blockIdx.x;      // 256 blocks
  const int bcol = fid >> 4;
  const int brow = fid & 15;

  const ushort* Ag = A + (size_t)(brow * 256) * INTER;
  const ushort* Bg = Bw + (size_t)(bcol * 128) * INTER;

  const int srow = tid >> 3;
  const int scole = (((tid & 7) * 16) ^ ((srow & 7) << 4)) >> 1;

  auto stageA2 = [&](int buf, int kt) {
#pragma unroll
    for (int i = 0; i < 4; i++) {
      gload16(Ag + (size_t)(i * 64 + srow) * INTER + kt * 64 + scole,
              smem + buf * 16384 + i * 4096 + tid * 8);
    }
  };
  auto stageB2 = [&](int buf, int kt) {
#pragma unroll
    for (int i = 0; i < 2; i++) {
      gload16(Bg + (size_t)(i * 64 + srow) * INTER + kt * 64 + scole,
              smem + 32768 + buf * 8192 + i * 4096 + tid * 8);
    }
  };
  auto ldA2 = [&](int buf, int mf, int ks) -> s16x8 {
    int row = wm * 64 + mf * 16 + r;
    int cb = (ks * 64 + kx * 16) ^ ((row & 7) << 4);
    return *(const s16x8*)(smem + buf * 16384 + row * 64 + (cb >> 1));
  };
  auto ldB2 = [&](int buf, int nf, int ks) -> s16x8 {
    int row = wn * 64 + nf * 16 + r;
    int cb = (ks * 64 + kx * 16) ^ ((row & 7) << 4);
    return *(const s16x8*)(smem + 32768 + buf * 8192 + row * 64 + (cb >> 1));
  };

  f32x4 acc[4][4];
#pragma unroll
  for (int i = 0; i < 4; i++)
#pragma unroll
    for (int j = 0; j < 4; j++) acc[i][j] = (f32x4)0.f;

  constexpr int NT = INTER / 64;   // 64 K-tiles

  stageA2(0, 0); stageB2(0, 0);
  stageA2(1, 1); stageB2(1, 1);
  asm volatile("s_waitcnt vmcnt(6)" ::: "memory");
  __builtin_amdgcn_s_barrier();

  int cur = 0;
  for (int t = 0; t < NT; t++) {
    s16x8 a[4][2], b[4][2];
#pragma unroll
    for (int mf = 0; mf < 4; mf++)
#pragma unroll
      for (int ks = 0; ks < 2; ks++) a[mf][ks] = ldA2(cur, mf, ks);
#pragma unroll
    for (int nf = 0; nf < 4; nf++)
#pragma unroll
      for (int ks = 0; ks < 2; ks++) b[nf][ks] = ldB2(cur, nf, ks);
    __builtin_amdgcn_s_barrier();
    asm volatile("s_waitcnt lgkmcnt(0)" ::: "memory");
    __builtin_amdgcn_sched_barrier(0);
    __builtin_amdgcn_s_setprio(1);
#pragma unroll
    for (int mf = 0; mf < 4; mf++)
#pragma unroll
      for (int nf = 0; nf < 2; nf++)
#pragma unroll
        for (int ks = 0; ks < 2; ks++)
          acc[mf][nf] = __builtin_amdgcn_mfma_f32_16x16x32_bf16(a[mf][ks], b[nf][ks], acc[mf][nf], 0, 0, 0);
    __builtin_amdgcn_s_setprio(0);
    __builtin_amdgcn_s_barrier();
    if (t + 2 < NT) { stageA2(cur, t + 2); stageB2(cur, t + 2); }
    __builtin_amdgcn_s_setprio(1);
#pragma unroll
    for (int mf = 0; mf < 4; mf++)
#pragma unroll
      for (int nf = 2; nf < 4; nf++)
#pragma unroll
        for (int ks = 0; ks < 2; ks++)
          acc[mf][nf] = __builtin_amdgcn_mfma_f32_16x16x32_bf16(a[mf][ks], b[nf][ks], acc[mf][nf], 0, 0, 0);
    __builtin_amdgcn_s_setprio(0);
    if (t + 2 < NT) {
      asm volatile("s_waitcnt vmcnt(6)" ::: "memory");
    } else {
      asm volatile("s_waitcnt vmcnt(0)" ::: "memory");
    }
    __builtin_amdgcn_s_barrier();
    cur ^= 1;
  }

  const int m0 = brow * 256 + wm * 64 + (lane >> 4) * 4;
  const int n0 = bcol * 128 + wn * 64 + r;
#pragma unroll
  for (int mf = 0; mf < 4; mf++) {
#pragma unroll
    for (int nf = 0; nf < 4; nf++) {
      int n = n0 + nf * 16;
#pragma unroll
      for (int q = 0; q < 4; q++)
        C[(size_t)(m0 + mf * 16 + q) * HID + n] = acc[mf][nf][q];
    }
  }
}

// ---------------------------------------------------------------------------
// Fused causal depthwise conv1d (K=4) + bias + SiLU, OUT-OF-PLACE to xbc.
// ---------------------------------------------------------------------------
__global__ __launch_bounds__(256) void conv_fused(
    const ushort* __restrict__ proj, ushort* __restrict__ xbc,
    const float* __restrict__ cw, const float* __restrict__ cb) {
  int idx = blockIdx.x * 256 + threadIdx.x;
  const int total = BB * (SS / 8) * CV8;
  if (idx >= total) return;
  int c8 = idx % CV8;
  int t = idx / CV8;
  int s8 = t % (SS / 8);
  int b = t / (SS / 8);
  const int c0 = c8 * 8;
  const int s0 = s8 * 8;
  float w0[8], w1[8], w2[8], w3[8], bias[8], h1[8], h2[8], h3[8];
#pragma unroll
  for (int e = 0; e < 8; e++) {
    float4 wv = *(const float4*)(cw + (c0 + e) * 4);
    w0[e] = wv.x; w1[e] = wv.y; w2[e] = wv.z; w3[e] = wv.w;
    bias[e] = cb[c0 + e];
  }
  const ushort* src = proj + ((size_t)b * SS + s0) * PROJ + COL_HS + c0;
  {
    s16x8 v1 = {0,0,0,0,0,0,0,0}, v2 = v1, v3 = v1;
    if (s0 >= 1) v1 = *(const s16x8*)(src - (size_t)1 * PROJ);
    if (s0 >= 2) v2 = *(const s16x8*)(src - (size_t)2 * PROJ);
    if (s0 >= 3) v3 = *(const s16x8*)(src - (size_t)3 * PROJ);
#pragma unroll
    for (int e = 0; e < 8; e++) {
      h1[e] = b2f((ushort)v1[e]);
      h2[e] = b2f((ushort)v2[e]);
      h3[e] = b2f((ushort)v3[e]);
    }
  }
  ushort* dst = xbc + ((size_t)b * SS + s0) * CONV_DIM + c0;
#pragma unroll
  for (int s = 0; s < 8; s++) {
    s16x8 xv = *(const s16x8*)(src + (size_t)s * PROJ);
    s16x8 ov;
#pragma unroll
    for (int e = 0; e < 8; e++) {
      float x = b2f((ushort)xv[e]);
      float o = w3[e] * x + w2[e] * h1[e] + w1[e] * h2[e] + w0[e] * h3[e] + bias[e];
      o = o / (1.f + __expf(-o));    // SiLU
      ov[e] = (short)f2b(o);
      h3[e] = h2[e]; h2[e] = h1[e]; h1[e] = x;
    }
    *(s16x8*)(dst + (size_t)s * CONV_DIM) = ov;
  }
}

// ---------------------------------------------------------------------------
// SSD K1: per (b,h,chunk): softplus(dt), shuffle cumsum, chunk state (MFMA).
// X staging: vectorized global reads (t_local=tid&31, dg=tid>>5).
// ---------------------------------------------------------------------------
__global__ __launch_bounds__(256) void ssd_chunk_state(
    const ushort* __restrict__ xbc, const float* __restrict__ dtf,
    const float* __restrict__ dt_bias, const float* __restrict__ A_log,
    ushort* __restrict__ states, float* __restrict__ cumbuf,
    float* __restrict__ dtvbuf) {
  const int bid = blockIdx.x;
  const int c = bid & 15;
  const int h = (bid >> 4) & 63;
  const int b = bid >> 10;
  const int tid = threadIdx.x;
  const int lane = tid & 63;
  const int wv = tid >> 6;
  __shared__ float sdtv[CL], scum[CL], sw[CL];
  __shared__ float wtot[2];
  __shared__ ushort sBt[128 * 128];   // [n][t]
  __shared__ ushort sXw[64 * 128];    // [d][t] scaled
  const size_t row0 = (size_t)b * SS + (size_t)c * CL;
  const size_t bh = (size_t)(b * NH + h);

  const float Ah = -__expf(A_log[h]);
  float dtvv = 0.f, v = 0.f;
  if (tid < CL) {
    float z = dtf[(row0 + tid) * 64 + h] + dt_bias[h];
    dtvv = (z > 20.f) ? z : log1pf(__expf(z));
    v = dtvv * Ah;
  }
#pragma unroll
  for (int off = 1; off < 64; off <<= 1) {
    float u = __shfl_up(v, off);
    if (lane >= off) v += u;
  }
  if (tid < CL && lane == 63) wtot[wv] = v;
  __syncthreads();
  if (wv == 1) v += wtot[0];
  if (tid < CL) {
    sdtv[tid] = dtvv;
    scum[tid] = v;
    cumbuf[bh * SS + c * CL + tid] = v;
    dtvbuf[bh * SS + c * CL + tid] = dtvv;
  }
  __syncthreads();
  const float cumL = scum[CL - 1];
  if (tid < CL) sw[tid] = __expf(cumL - v) * dtvv;
  __syncthreads();

  // stage B^T [n][t]
  {
    const int t = tid >> 1, n0 = (tid & 1) * 64;
    const ushort* src = xbc + (row0 + t) * CONV_DIM + XBC_B + n0;
#pragma unroll
    for (int j = 0; j < 64; j += 8) {
      s16x8 vv = *(const s16x8*)(src + j);
#pragma unroll
      for (int e = 0; e < 8; e++) sBt[swz(n0 + j + e, t)] = (ushort)vv[e];
    }
  }
  // stage Xw^T [d][t] scaled by sw[t]: vector global reads, scatter LDS
  {
    const int tl = tid & 31;
    const int dg = tid >> 5;     // 0..7
#pragma unroll
    for (int it = 0; it < 4; it++) {
      int t = tl + it * 32;
      float swt = sw[t];
      s16x8 xv = *(const s16x8*)(xbc + (row0 + t) * CONV_DIM + h * 64 + dg * 8);
#pragma unroll
      for (int e = 0; e < 8; e++)
        sXw[swz(dg * 8 + e, t)] = f2b(b2f((ushort)xv[e]) * swt);
    }
  }
  __syncthreads();

  const int r = lane & 15, kx = lane >> 4;
  f32x4 acc[2][4];
#pragma unroll
  for (int i = 0; i < 2; i++)
#pragma unroll
    for (int j = 0; j < 4; j++) acc[i][j] = (f32x4)0.f;
#pragma unroll
  for (int kk = 0; kk < 4; kk++) {
    s16x8 a[2], bo[4];
#pragma unroll
    for (int i = 0; i < 2; i++)
      a[i] = *(const s16x8*)&sBt[swz(wv * 32 + i * 16 + r, kk * 32 + kx * 8)];
#pragma unroll
    for (int j = 0; j < 4; j++)
      bo[j] = *(const s16x8*)&sXw[swz(j * 16 + r, kk * 32 + kx * 8)];
#pragma unroll
    for (int i = 0; i < 2; i++)
#pragma unroll
      for (int j = 0; j < 4; j++)
        acc[i][j] = __builtin_amdgcn_mfma_f32_16x16x32_bf16(a[i], bo[j], acc[i][j], 0, 0, 0);
  }
  ushort* dst = states + (size_t)bid * (128 * 64);
#pragma unroll
  for (int i = 0; i < 2; i++) {
#pragma unroll
    for (int j = 0; j < 4; j++) {
      int n = wv * 32 + i * 16 + (lane >> 4) * 4;
      int d = (lane & 15) + j * 16;
      ushort4 o;
      o.x = f2b(acc[i][j][0]);
      o.y = f2b(acc[i][j][1]);
      o.z = f2b(acc[i][j][2]);
      o.w = f2b(acc[i][j][3]);
      *(ushort4*)(dst + (size_t)d * 128 + n) = o;
    }
  }
}

// ---------------------------------------------------------------------------
// SSD K2: inter-chunk recurrence. Block = (bh, d-half): 256 blocks.
// ---------------------------------------------------------------------------
__global__ __launch_bounds__(256) void ssd_state_scan(
    ushort* __restrict__ states, const float* __restrict__ cumbuf) {
  const int bh = blockIdx.x >> 1;
  const int half = blockIdx.x & 1;
  const int tid = threadIdx.x;
  float run[16];
#pragma unroll
  for (int i = 0; i < 16; i++) run[i] = 0.f;
  for (int c = 0; c < NCHK; c++) {
    float dec = __expf(cumbuf[(size_t)bh * SS + c * CL + (CL - 1)]);
    ushort* p = states + ((size_t)bh * NCHK + c) * 8192 + half * 4096 + tid * 16;
    s16x8 in[2];
#pragma unroll
    for (int v = 0; v < 2; v++) in[v] = *(const s16x8*)(p + v * 8);
    s16x8 out[2];
#pragma unroll
    for (int v = 0; v < 2; v++) {
#pragma unroll
      for (int e = 0; e < 8; e++) {
        int i = v * 8 + e;
        out[v][e] = (short)f2b(run[i]);
        run[i] = dec * run[i] + b2f((ushort)in[v][e]);
      }
    }
#pragma unroll
    for (int v = 0; v < 2; v++) *(s16x8*)(p + v * 8) = out[v];
  }
}

// ---------------------------------------------------------------------------
// SSD K3 (slim): LDS = sB + sX = 48KB. X staging vectorized like K1.
// ---------------------------------------------------------------------------
__global__ __launch_bounds__(256, 2) void ssd_chunk_out(
    ushort* __restrict__ proj, const ushort* __restrict__ xbc,
    const ushort* __restrict__ states, const float* __restrict__ cumbuf,
    const float* __restrict__ dtvbuf, const float* __restrict__ Dp) {
  const int bid = blockIdx.x;
  const int c = bid & 15;
  const int h = (bid >> 4) & 63;
  const int b = bid >> 10;
  const int tid = threadIdx.x;
  const int lane = tid & 63;
  const int wv = tid >> 6;
  __shared__ ushort sB[128 * 128];   // B [tau][n] -> later P [t][tau]
  __shared__ ushort sX[64 * 128];    // X^T [d][t]
  const size_t row0 = (size_t)b * SS + (size_t)c * CL;
  const size_t bh = (size_t)(b * NH + h);
  const float* cumb = cumbuf + bh * SS + c * CL;
  const float* dtvb = dtvbuf + bh * SS + c * CL;
  const int r = lane & 15, kx = lane >> 4;

  float ct[2][4];
#pragma unroll
  for (int i = 0; i < 2; i++)
#pragma unroll
    for (int q = 0; q < 4; q++)
      ct[i][q] = cumb[wv * 32 + i * 16 + ((lane >> 4) << 2) + q];
  float cumt[8], dvt[8];
#pragma unroll
  for (int j = 0; j < 8; j++) {
    int tau = j * 16 + (lane & 15);
    cumt[j] = cumb[tau];
    dvt[j] = dtvb[tau];
  }

  // stage B [t][n] from xbc
  {
    const int t = tid >> 1, n0 = (tid & 1) * 64;
    const ushort* srcB = xbc + (row0 + t) * CONV_DIM + XBC_B + n0;
#pragma unroll
    for (int j = 0; j < 64; j += 8)
      *(s16x8*)&sB[swz(t, n0 + j)] = *(const s16x8*)(srcB + j);
  }
  // stage X^T [d][t]: vector global reads, scatter LDS
  {
    const int tl = tid & 31;
    const int dg = tid >> 5;
#pragma unroll
    for (int it = 0; it < 4; it++) {
      int t = tl + it * 32;
      s16x8 xv = *(const s16x8*)(xbc + (row0 + t) * CONV_DIM + h * 64 + dg * 8);
#pragma unroll
      for (int e = 0; e < 8; e++)
        sX[swz(dg * 8 + e, t)] = (ushort)xv[e];
    }
  }
  // prefetch C fragments from xbc (16B aligned, L2-hot)
  s16x8 cf[4][2];
#pragma unroll
  for (int kk = 0; kk < 4; kk++)
#pragma unroll
    for (int i = 0; i < 2; i++)
      cf[kk][i] = *(const s16x8*)(xbc + (row0 + wv * 32 + i * 16 + r) * CONV_DIM
                                  + XBC_C + kk * 32 + kx * 8);
  __syncthreads();

  // Phase G: G = C @ B^T
  f32x4 g[2][8];
#pragma unroll
  for (int i = 0; i < 2; i++)
#pragma unroll
    for (int j = 0; j < 8; j++) g[i][j] = (f32x4)0.f;
#pragma unroll
  for (int kk = 0; kk < 4; kk++) {
    s16x8 bo[8];
#pragma unroll
    for (int j = 0; j < 8; j++)
      bo[j] = *(const s16x8*)&sB[swz(j * 16 + r, kk * 32 + kx * 8)];
#pragma unroll
    for (int i = 0; i < 2; i++)
#pragma unroll
      for (int j = 0; j < 8; j++)
        g[i][j] = __builtin_amdgcn_mfma_f32_16x16x32_bf16(cf[kk][i], bo[j], g[i][j], 0, 0, 0);
  }

  // Phase Yi: yi = C @ Sp^T (unscaled)
  f32x4 yi[2][4];
#pragma unroll
  for (int i = 0; i < 2; i++)
#pragma unroll
    for (int j = 0; j < 4; j++) yi[i][j] = (f32x4)0.f;
  {
    const ushort* sp = states + (size_t)bid * 8192;
#pragma unroll
    for (int kk = 0; kk < 4; kk++) {
      s16x8 spk[4];
#pragma unroll
      for (int j = 0; j < 4; j++)
        spk[j] = *(const s16x8*)(sp + (size_t)(j * 16 + r) * 128 + kk * 32 + kx * 8);
#pragma unroll
      for (int i = 0; i < 2; i++)
#pragma unroll
        for (int j = 0; j < 4; j++)
          yi[i][j] = __builtin_amdgcn_mfma_f32_16x16x32_bf16(cf[kk][i], spk[j], yi[i][j], 0, 0, 0);
    }
  }
  __syncthreads();   // all waves done reading sB as B

  // Phase P: write P[t][tau] over sB
#pragma unroll
  for (int j = 0; j < 8; j++) {
    float cu = cumt[j], dv = dvt[j];
    int tau = j * 16 + (lane & 15);
#pragma unroll
    for (int i = 0; i < 2; i++) {
#pragma unroll
      for (int q = 0; q < 4; q++) {
        int t = wv * 32 + i * 16 + ((lane >> 4) << 2) + q;
        float val = (tau <= t) ? g[i][j][q] * __expf(ct[i][q] - cu) * dv : 0.f;
        sB[swz(t, tau)] = f2b(val);
      }
    }
  }
  __syncthreads();

  // Phase Y: y = P @ X^T
  f32x4 y[2][4];
#pragma unroll
  for (int i = 0; i < 2; i++)
#pragma unroll
    for (int j = 0; j < 4; j++) y[i][j] = (f32x4)0.f;
#pragma unroll
  for (int kk = 0; kk < 4; kk++) {
    s16x8 a[2], bo[4];
#pragma unroll
    for (int i = 0; i < 2; i++)
      a[i] = *(const s16x8*)&sB[swz(wv * 32 + i * 16 + r, kk * 32 + kx * 8)];
#pragma unroll
    for (int j = 0; j < 4; j++)
      bo[j] = *(const s16x8*)&sX[swz(j * 16 + r, kk * 32 + kx * 8)];
#pragma unroll
    for (int i = 0; i < 2; i++)
#pragma unroll
      for (int j = 0; j < 4; j++)
        y[i][j] = __builtin_amdgcn_mfma_f32_16x16x32_bf16(a[i], bo[j], y[i][j], 0, 0, 0);
  }

  // Epilogue: out = y + exp(ct)*yi + D*x  -> proj hs cols
  const float Dh = Dp[h];
  float eP[2][4];
#pragma unroll
  for (int i = 0; i < 2; i++)
#pragma unroll
    for (int q = 0; q < 4; q++) eP[i][q] = __expf(ct[i][q]);
#pragma unroll
  for (int i = 0; i < 2; i++) {
#pragma unroll
    for (int j = 0; j < 4; j++) {
      int t0 = wv * 32 + i * 16 + (lane >> 4) * 4;
      int d = (lane & 15) + j * 16;
#pragma unroll
      for (int q = 0; q < 4; q++) {
        float x = b2f(sX[swz(d, t0 + q)]);
        proj[(row0 + t0 + q) * PROJ + COL_HS + h * 64 + d] =
            f2b(y[i][j][q] + eP[i][q] * yi[i][j][q] + Dh * x);
      }
    }
  }
}

// ---------------------------------------------------------------------------
// Gated RMSNorm: reads proj (gate+y), writes DENSE bf16 ybuf [4096][4096].
// ---------------------------------------------------------------------------
__global__ __launch_bounds__(256) void rmsnorm_kernel(
    const ushort* __restrict__ proj, const float* __restrict__ nw,
    ushort* __restrict__ ybuf) {
  const int row = blockIdx.x;
  const int tid = threadIdx.x;
  const ushort* yp = proj + (size_t)row * PROJ + COL_HS;
  const ushort* gp = proj + (size_t)row * PROJ;
  float v[16];
  float ss = 0.f;
#pragma unroll
  for (int q = 0; q < 4; q++) {
    int col = q * 1024 + tid * 4;
    ushort4 yv = *(const ushort4*)(yp + col);
    ushort4 gv = *(const ushort4*)(gp + col);
    float vy[4] = {b2f(yv.x), b2f(yv.y), b2f(yv.z), b2f(yv.w)};
    float vg[4] = {b2f(gv.x), b2f(gv.y), b2f(gv.z), b2f(gv.w)};
#pragma unroll
    for (int j = 0; j < 4; j++) {
      float sg = vg[j] / (1.f + __expf(-vg[j]));
      float vv = vy[j] * sg;
      v[q * 4 + j] = vv;
      ss += vv * vv;
    }
  }
#pragma unroll
  for (int o = 1; o < 64; o <<= 1) ss += __shfl_xor(ss, o);
  __shared__ float red[4];
  if ((tid & 63) == 0) red[tid >> 6] = ss;
  __syncthreads();
  float tot = red[0] + red[1] + red[2] + red[3];
  float scale = rsqrtf(tot * (1.f / INTER) + EPS);
#pragma unroll
  for (int q = 0; q < 4; q++) {
    int col = q * 1024 + tid * 4;
    float4 w = *(const float4*)(nw + col);
    ushort4 o;
    o.x = f2b(v[q * 4 + 0] * scale * w.x);
    o.y = f2b(v[q * 4 + 1] * scale * w.y);
    o.z = f2b(v[q * 4 + 2] * scale * w.z);
    o.w = f2b(v[q * 4 + 3] * scale * w.w);
    *(ushort4*)(ybuf + (size_t)row * INTER + col) = o;
  }
}

// ---------------------------------------------------------------------------
extern "C" void kernel_launch(void* const* d_in, const int* in_sizes, int n_in,
                              void* d_out, int out_size, void* d_ws, size_t ws_size,
                              hipStream_t stream) {
  const float* hs   = (const float*)d_in[0];
  const float* w1   = (const float*)d_in[1];
  const float* cw   = (const float*)d_in[2];
  const float* cb   = (const float*)d_in[3];
  const float* dtb  = (const float*)d_in[4];
  const float* alog = (const float*)d_in[5];
  const float* Dp   = (const float*)d_in[6];
  const float* nw   = (const float*)d_in[7];
  const float* w2   = (const float*)d_in[8];
  float* out = (float*)d_out;

  // ws layout
  char* base = (char*)d_ws;
  size_t off = 0;
  ushort* proj = (ushort*)(base + off); off += (size_t)BS * PROJ * 2;          // 69.7 MB
  off = (off + 255) & ~(size_t)255;
  ushort* xbc = (ushort*)(base + off); off += (size_t)BS * CONV_DIM * 2;       // 35.7 MB
  off = (off + 255) & ~(size_t)255;
  float* dtbuf = (float*)(base + off); off += (size_t)BS * 64 * 4;             // 1.05 MB
  off = (off + 255) & ~(size_t)255;
  ushort* w216 = (ushort*)(base + off); off += (size_t)HID * INTER * 2;        // 16.78 MB
  off = (off + 255) & ~(size_t)255;
  char* rC = base + off;
  // phase 1 tenants:
  ushort* hs16 = (ushort*)rC;                                 // 16.78 MB
  ushort* w1p  = (ushort*)(rC + 16777216);                    // 35.65 MB (8704x2048)
  // phase 2 tenants (after GEMM1; hs16/w1p dead):
  ushort* states = (ushort*)rC;                               // 33.55 MB
  float*  cumbuf = (float*)(rC + 33554432);                   // 1.05 MB
  float*  dtvbuf = (float*)(rC + 33554432 + 1048576);         // 1.05 MB
  // phase 3 tenant (after K3; states dead):
  ushort* ybuf = (ushort*)rC;                                 // 33.55 MB dense y

  // 0) merged fp32 -> bf16 conversions (hs, w1 padded, w2)
  {
    long n4 = N4A + N4W1 + N4W2;
    convert_all<<<(int)((n4 + 255) / 256), 256, 0, stream>>>(hs, w1, w2, hs16, w1p, w216);
  }

  // 1) in_proj GEMM (256^2, 544 blocks): proj(bf16) = hs @ w1^T ; dt sidecar
  gemm256_8ph<<<(BS / 256) * (PROJ_PAD / 256), 512, 0, stream>>>(hs16, w1p, proj, dtbuf);

  // 2) fused causal depthwise conv + SiLU (out-of-place -> xbc)
  conv_fused<<<(BB * (SS / 8) * CV8 + 255) / 256, 256, 0, stream>>>(proj, xbc, cw, cb);

  // 3) SSD chunked scan
  ssd_chunk_state<<<BB * NH * NCHK, 256, 0, stream>>>(xbc, dtbuf, dtb, alog, states, cumbuf, dtvbuf);
  ssd_state_scan<<<BB * NH * 2, 256, 0, stream>>>(states, cumbuf);
  ssd_chunk_out<<<BB * NH * NCHK, 256, 0, stream>>>(proj, xbc, states, cumbuf, dtvbuf, Dp);

  // 4) gated RMSNorm -> dense ybuf (states region dead after K3)
  rmsnorm_kernel<<<BS, 256, 0, stream>>>(proj, nw, ybuf);

  // 5) out_proj GEMM (256x128 pipelined, 256 blocks = exact 1 round)
  gemm2_256x128<<<256, 512, 0, stream>>>(ybuf, w216, out);
}